// Round 1
// baseline (2571.872 us; speedup 1.0000x reference)
//
#include <hip/hip_runtime.h>
#include <hip/hip_bf16.h>
#include <math.h>

// Problem dims
#define Bb 8
#define Tt 256
#define DM 256       // d_model
#define DI 512       // d_inner
#define NL 6
#define DS 16        // d_state
#define DTR 16       // dt_rank

// ---------------- workspace layout (floats) ----------------
#define OFF_H     0u
#define SZ_H      (Bb*Tt*DM)            // 524288
#define OFF_XN    (OFF_H + SZ_H)
#define SZ_XN     (Bb*Tt*DM)
#define OFF_XZ    (OFF_XN + SZ_XN)
#define SZ_XZ     (Bb*Tt*2*DI)          // 2097152
#define OFF_U     (OFF_XZ + SZ_XZ)
#define SZ_U      (Bb*Tt*DI)
#define OFF_DBC   (OFF_U + SZ_U)
#define SZ_DBC    (Bb*Tt*48)
#define OFF_DELTA (OFF_DBC + SZ_DBC)
#define SZ_DELTA  (Bb*Tt*DI)
#define OFF_Y     (OFF_DELTA + SZ_DELTA)
#define SZ_Y      (Bb*Tt*DI)
#define OFF_HH    (OFF_Y + SZ_Y)
#define SZ_HH     (Bb*Tt*64)
#define OFF_LOGIT (OFF_HH + SZ_HH)
#define SZ_LOGIT  (Bb*Tt)
// total ~6.66M floats = ~26.6 MB

__device__ __forceinline__ float siluf(float x) { return x / (1.f + __expf(-x)); }

// ======================= CNN + fc, one block per frame =======================
__global__ __launch_bounds__(256) void cnn_fc_kernel(
    const float* __restrict__ x,
    const float* __restrict__ w1, const float* __restrict__ b1,
    const float* __restrict__ w2, const float* __restrict__ b2,
    const float* __restrict__ w3, const float* __restrict__ b3,
    const float* __restrict__ fcw, const float* __restrict__ fcb,
    float* __restrict__ hout) {
  // smem: [0,4096) input frame; [4096,8192) c1 chunk (4 ch); reused as c2 [32][256]
  __shared__ float smem[8192];
  __shared__ float s_c3[2048];   // [32][64]
  __shared__ float s_z[32];
  const int f = blockIdx.x;
  const int tid = threadIdx.x;
  const float* xin = x + (size_t)f * 4096;

  for (int i = tid; i < 1024; i += 256)
    ((float4*)smem)[i] = ((const float4*)xin)[i];

  float acc2[32];
#pragma unroll
  for (int i = 0; i < 32; ++i) acc2[i] = 0.f;
  const int oy2 = tid >> 4, ox2 = tid & 15;
  __syncthreads();

  for (int cc = 0; cc < 4; ++cc) {
    // conv1 for output channels cc*4..cc*4+3 (stride 2, SAME: pad_lo=0, pad_hi=1)
    for (int i = 0; i < 16; ++i) {
      int idx = i * 256 + tid;           // 0..4095
      int cl = idx >> 10;                // uniform per i
      int rem = idx & 1023;
      int oy = rem >> 5, ox = rem & 31;
      int oc = cc * 4 + cl;
      float s = b1[oc];
#pragma unroll
      for (int ky = 0; ky < 3; ++ky) {
        int iy = 2 * oy + ky;
        if (iy < 64) {
#pragma unroll
          for (int kx = 0; kx < 3; ++kx) {
            int ix = 2 * ox + kx;
            if (ix < 64) s += w1[oc * 9 + ky * 3 + kx] * smem[iy * 64 + ix];
          }
        }
      }
      smem[4096 + cl * 1024 + rem] = fmaxf(s, 0.f);
    }
    __syncthreads();
    // conv2 partial accumulation over these 4 input channels
#pragma unroll
    for (int icl = 0; icl < 4; ++icl) {
      int ic = cc * 4 + icl;
      float in9[9];
#pragma unroll
      for (int ky = 0; ky < 3; ++ky) {
        int iy = 2 * oy2 + ky;
#pragma unroll
        for (int kx = 0; kx < 3; ++kx) {
          int ix = 2 * ox2 + kx;
          in9[ky * 3 + kx] = (iy < 32 && ix < 32) ? smem[4096 + icl * 1024 + iy * 32 + ix] : 0.f;
        }
      }
#pragma unroll
      for (int oc = 0; oc < 32; ++oc) {
        const float* wp = w2 + oc * 144 + ic * 9;
        float s = acc2[oc];
#pragma unroll
        for (int k = 0; k < 9; ++k) s += wp[k] * in9[k];
        acc2[oc] = s;
      }
    }
    __syncthreads();
  }
  // c2 = relu(acc2 + b2) -> smem [oc][256]
#pragma unroll
  for (int oc = 0; oc < 32; ++oc)
    smem[oc * 256 + tid] = fmaxf(acc2[oc] + b2[oc], 0.f);
  __syncthreads();

  // conv3: thread -> (ocg = tid>>6, pos = tid&63)
  const int ocg = tid >> 6, pos = tid & 63;
  const int oy3 = pos >> 3, ox3 = pos & 7;
  float acc3[8];
#pragma unroll
  for (int j = 0; j < 8; ++j) acc3[j] = 0.f;
  for (int ic = 0; ic < 32; ++ic) {
    float in9[9];
#pragma unroll
    for (int ky = 0; ky < 3; ++ky) {
      int iy = 2 * oy3 + ky;
#pragma unroll
      for (int kx = 0; kx < 3; ++kx) {
        int ix = 2 * ox3 + kx;
        in9[ky * 3 + kx] = (iy < 16 && ix < 16) ? smem[ic * 256 + iy * 16 + ix] : 0.f;
      }
    }
#pragma unroll
    for (int j = 0; j < 8; ++j) {
      const float* wp = w3 + (ocg * 8 + j) * 288 + ic * 9;
      float s = acc3[j];
#pragma unroll
      for (int k = 0; k < 9; ++k) s += wp[k] * in9[k];
      acc3[j] = s;
    }
  }
#pragma unroll
  for (int j = 0; j < 8; ++j)
    s_c3[(ocg * 8 + j) * 64 + pos] = fmaxf(acc3[j] + b3[ocg * 8 + j], 0.f);
  __syncthreads();

  // global avg pool -> s_z[32]
  {
    int oc = tid >> 3, l8 = tid & 7;
    float s = 0.f;
#pragma unroll
    for (int i = 0; i < 8; ++i) s += s_c3[oc * 64 + l8 * 8 + i];
    s += __shfl_xor(s, 1);
    s += __shfl_xor(s, 2);
    s += __shfl_xor(s, 4);
    if (l8 == 0) s_z[oc] = s * (1.f / 64.f);
  }
  __syncthreads();

  // fc: 32 -> 256
  float acc = fcb[tid];
#pragma unroll
  for (int k = 0; k < 32; ++k) acc += fcw[tid * 32 + k] * s_z[k];
  hout[(size_t)f * 256 + tid] = acc;
}

// ======================= RMSNorm =======================
__global__ __launch_bounds__(256) void rmsnorm_kernel(const float* __restrict__ x,
                                                      const float* __restrict__ w,
                                                      float* __restrict__ o) {
  __shared__ float red[4];
  int t = blockIdx.x, j = threadIdx.x;
  float v = x[(size_t)t * 256 + j];
  float s = v * v;
#pragma unroll
  for (int m = 32; m; m >>= 1) s += __shfl_xor(s, m);
  if ((j & 63) == 0) red[j >> 6] = s;
  __syncthreads();
  float tot = red[0] + red[1] + red[2] + red[3];
  float r = rsqrtf(tot * (1.f / 256.f) + 1e-5f);
  o[(size_t)t * 256 + j] = v * r * w[j];
}

// ======================= GEMM NT: C[m][n] = sum_k A[m*lda+k] * W[n*K+k] ===========
// ACT: 0 none, 1 bias+softplus, 2 accumulate into C, 3 bias+gelu(tanh)
template <int ACT>
__global__ __launch_bounds__(256) void gemm_nt(const float* __restrict__ A, int lda,
                                               const float* __restrict__ W,
                                               const float* __restrict__ bias,
                                               float* __restrict__ C,
                                               int M, int N, int K) {
  __shared__ __align__(16) float sA[16][68];
  __shared__ __align__(16) float sW[16][68];
  const int m0 = blockIdx.x * 64;
  const int n0 = blockIdx.y * 64;
  const int tid = threadIdx.x;
  const int lk = tid & 15, lm = tid >> 4;
  const int tx = tid & 15, ty = tid >> 4;
  float acc[4][4] = {};

  for (int k0 = 0; k0 < K; k0 += 16) {
#pragma unroll
    for (int p = 0; p < 4; ++p) {
      int m = p * 16 + lm;
      sA[lk][m] = A[(size_t)(m0 + m) * lda + k0 + lk];
    }
#pragma unroll
    for (int p = 0; p < 4; ++p) {
      int n = p * 16 + lm;
      sW[lk][n] = (n0 + n < N) ? W[(size_t)(n0 + n) * K + k0 + lk] : 0.f;
    }
    __syncthreads();
#pragma unroll
    for (int k = 0; k < 16; ++k) {
      float4 a = *(const float4*)&sA[k][ty * 4];
      float4 b = *(const float4*)&sW[k][tx * 4];
      acc[0][0] += a.x * b.x; acc[0][1] += a.x * b.y; acc[0][2] += a.x * b.z; acc[0][3] += a.x * b.w;
      acc[1][0] += a.y * b.x; acc[1][1] += a.y * b.y; acc[1][2] += a.y * b.z; acc[1][3] += a.y * b.w;
      acc[2][0] += a.z * b.x; acc[2][1] += a.z * b.y; acc[2][2] += a.z * b.z; acc[2][3] += a.z * b.w;
      acc[3][0] += a.w * b.x; acc[3][1] += a.w * b.y; acc[3][2] += a.w * b.z; acc[3][3] += a.w * b.w;
    }
    __syncthreads();
  }
#pragma unroll
  for (int i = 0; i < 4; ++i) {
    int m = m0 + ty * 4 + i;
#pragma unroll
    for (int j = 0; j < 4; ++j) {
      int n = n0 + tx * 4 + j;
      if (n < N) {
        float v = acc[i][j];
        if (ACT == 1) {
          v += bias[n];
          v = (v > 20.f) ? v : log1pf(__expf(v));
        } else if (ACT == 2) {
          v += C[(size_t)m * N + n];
        } else if (ACT == 3) {
          v += bias[n];
          float t3 = v * v * v;
          v = 0.5f * v * (1.f + tanhf(0.7978845608028654f * (v + 0.044715f * t3)));
        }
        C[(size_t)m * N + n] = v;
      }
    }
  }
}

// ======================= causal depthwise conv1d (k=4) + silu ===================
__global__ __launch_bounds__(256) void conv1d_silu_kernel(const float* __restrict__ xz,
                                                          const float* __restrict__ cw,
                                                          const float* __restrict__ cb,
                                                          float* __restrict__ u) {
  int idx = blockIdx.x * 256 + threadIdx.x;   // over B*T*DI
  int e = idx & (DI - 1);
  int bt = idx >> 9;
  int t = bt & (Tt - 1);
  int b = bt >> 8;
  float s = cb[e];
#pragma unroll
  for (int j = 0; j < 4; ++j) {
    int tt = t - 3 + j;
    if (tt >= 0) s += cw[e * 4 + j] * xz[((size_t)(b * Tt + tt)) * (2 * DI) + e];
  }
  u[idx] = siluf(s);
}

// ======================= selective scan (16 lanes per (b,e)) ====================
__global__ __launch_bounds__(256) void scan_kernel(const float* __restrict__ delta,
                                                   const float* __restrict__ u,
                                                   const float* __restrict__ dbc,
                                                   const float* __restrict__ xz,
                                                   const float* __restrict__ A_log,
                                                   const float* __restrict__ Dp,
                                                   float* __restrict__ y) {
  int gid = blockIdx.x * 256 + threadIdx.x;
  int g = gid >> 4;          // (b,e), 0..4095
  int n = gid & 15;
  int b = g >> 9;
  int e = g & (DI - 1);
  float An = -__expf(A_log[e * 16 + n]);
  float Dv = Dp[e];
  float h = 0.f;
  const float* dptr = delta + (size_t)b * Tt * DI + e;
  const float* uptr = u + (size_t)b * Tt * DI + e;
  const float* bc = dbc + (size_t)b * Tt * 48;
  const float* zptr = xz + (size_t)b * Tt * (2 * DI) + DI + e;
  float* yptr = y + (size_t)b * Tt * DI + e;
  for (int t = 0; t < Tt; ++t) {
    float dv = dptr[(size_t)t * DI];
    float uv = uptr[(size_t)t * DI];
    float Bv = bc[t * 48 + 16 + n];
    float Cv = bc[t * 48 + 32 + n];
    float dA = __expf(dv * An);
    h = dA * h + dv * Bv * uv;
    float p = h * Cv;
    p += __shfl_xor(p, 1);
    p += __shfl_xor(p, 2);
    p += __shfl_xor(p, 4);
    p += __shfl_xor(p, 8);
    if (n == 0) {
      float zv = zptr[(size_t)t * 2 * DI];
      yptr[(size_t)t * DI] = (p + uv * Dv) * siluf(zv);
    }
  }
}

// ======================= head: logits and softmax ==============================
__global__ __launch_bounds__(256) void logits_kernel(const float* __restrict__ hh,
                                                     const float* __restrict__ w2,
                                                     const float* __restrict__ b2,
                                                     float* __restrict__ logit) {
  int t = blockIdx.x * 256 + threadIdx.x;  // 2048 tokens
  float s = b2[0];
#pragma unroll
  for (int k = 0; k < 64; ++k) s += hh[(size_t)t * 64 + k] * w2[k];
  logit[t] = s;
}

__global__ __launch_bounds__(256) void softmax_kernel(const float* __restrict__ logit,
                                                      float* __restrict__ out) {
  __shared__ float redm[4], reds[4];
  int b = blockIdx.x, t = threadIdx.x;
  float v = logit[b * 256 + t];
  float m = v;
#pragma unroll
  for (int k = 32; k; k >>= 1) m = fmaxf(m, __shfl_xor(m, k));
  if ((t & 63) == 0) redm[t >> 6] = m;
  __syncthreads();
  m = fmaxf(fmaxf(redm[0], redm[1]), fmaxf(redm[2], redm[3]));
  float e = __expf(v - m);
  float s = e;
#pragma unroll
  for (int k = 32; k; k >>= 1) s += __shfl_xor(s, k);
  if ((t & 63) == 0) reds[t >> 6] = s;
  __syncthreads();
  s = reds[0] + reds[1] + reds[2] + reds[3];
  out[b * 256 + t] = (t == 0) ? 0.f : e / s;
}

// ======================= launch ===============================================
extern "C" void kernel_launch(void* const* d_in, const int* in_sizes, int n_in,
                              void* d_out, int out_size, void* d_ws, size_t ws_size,
                              hipStream_t stream) {
  const float* x      = (const float*)d_in[0];
  const float* cnn_w1 = (const float*)d_in[1];
  const float* cnn_b1 = (const float*)d_in[2];
  const float* cnn_w2 = (const float*)d_in[3];
  const float* cnn_b2 = (const float*)d_in[4];
  const float* cnn_w3 = (const float*)d_in[5];
  const float* cnn_b3 = (const float*)d_in[6];
  const float* fc_w   = (const float*)d_in[7];
  const float* fc_b   = (const float*)d_in[8];
  const float* norm_w = (const float*)d_in[9];
  const float* ipw    = (const float*)d_in[10];
  const float* cw     = (const float*)d_in[11];
  const float* cb     = (const float*)d_in[12];
  const float* xpw    = (const float*)d_in[13];
  const float* dpw    = (const float*)d_in[14];
  const float* dpb    = (const float*)d_in[15];
  const float* A_log  = (const float*)d_in[16];
  const float* Dp     = (const float*)d_in[17];
  const float* opw    = (const float*)d_in[18];
  const float* nfw    = (const float*)d_in[19];
  const float* hw1    = (const float*)d_in[20];
  const float* hb1    = (const float*)d_in[21];
  const float* hw2    = (const float*)d_in[22];
  const float* hb2    = (const float*)d_in[23];

  float* ws    = (float*)d_ws;
  float* h     = ws + OFF_H;
  float* xn    = ws + OFF_XN;
  float* xz    = ws + OFF_XZ;
  float* u     = ws + OFF_U;
  float* dbc   = ws + OFF_DBC;
  float* delta = ws + OFF_DELTA;
  float* yb    = ws + OFF_Y;
  float* hh    = ws + OFF_HH;
  float* logit = ws + OFF_LOGIT;

  cnn_fc_kernel<<<Bb * Tt, 256, 0, stream>>>(x, cnn_w1, cnn_b1, cnn_w2, cnn_b2,
                                             cnn_w3, cnn_b3, fc_w, fc_b, h);

  for (int l = 0; l < NL; ++l) {
    rmsnorm_kernel<<<Bb * Tt, 256, 0, stream>>>(h, norm_w + l * DM, xn);
    {
      dim3 g(32, 16);
      gemm_nt<0><<<g, 256, 0, stream>>>(xn, DM, ipw + (size_t)l * 2 * DI * DM, nullptr,
                                        xz, Bb * Tt, 2 * DI, DM);
    }
    conv1d_silu_kernel<<<(Bb * Tt * DI) / 256, 256, 0, stream>>>(
        xz, cw + l * DI * 4, cb + l * DI, u);
    {
      dim3 g(32, 1);
      gemm_nt<0><<<g, 256, 0, stream>>>(u, DI, xpw + (size_t)l * 48 * DI, nullptr,
                                        dbc, Bb * Tt, 48, DI);
    }
    {
      dim3 g(32, 8);
      gemm_nt<1><<<g, 256, 0, stream>>>(dbc, 48, dpw + (size_t)l * DI * DTR,
                                        dpb + l * DI, delta, Bb * Tt, DI, DTR);
    }
    scan_kernel<<<(Bb * DI * 16) / 256, 256, 0, stream>>>(
        delta, u, dbc, xz, A_log + (size_t)l * DI * DS, Dp + l * DI, yb);
    {
      dim3 g(32, 4);
      gemm_nt<2><<<g, 256, 0, stream>>>(yb, DI, opw + (size_t)l * DM * DI, nullptr,
                                        h, Bb * Tt, DM, DI);
    }
  }

  rmsnorm_kernel<<<Bb * Tt, 256, 0, stream>>>(h, nfw, xn);
  {
    dim3 g(32, 1);
    gemm_nt<3><<<g, 256, 0, stream>>>(xn, DM, hw1, hb1, hh, Bb * Tt, 64, DM);
  }
  logits_kernel<<<Bb * Tt / 256, 256, 0, stream>>>(hh, hw2, hb2, logit);
  softmax_kernel<<<Bb, 256, 0, stream>>>(logit, (float*)d_out);
}

// Round 2
// 1820.153 us; speedup vs baseline: 1.4130x; 1.4130x over previous
//
#include <hip/hip_runtime.h>
#include <hip/hip_bf16.h>
#include <math.h>

// Problem dims
#define Bb 8
#define Tt 256
#define DM 256       // d_model
#define DI 512       // d_inner
#define NL 6
#define DS 16        // d_state
#define DTR 16       // dt_rank

// ---------------- workspace layout (floats) ----------------
#define OFF_H     0u
#define SZ_H      (Bb*Tt*DM)            // 524288
#define OFF_XN    (OFF_H + SZ_H)
#define SZ_XN     (Bb*Tt*DM)
#define OFF_XZ    (OFF_XN + SZ_XN)
#define SZ_XZ     (Bb*Tt*2*DI)          // 2097152
#define OFF_U     (OFF_XZ + SZ_XZ)
#define SZ_U      (Bb*Tt*DI)
#define OFF_DBC   (OFF_U + SZ_U)
#define SZ_DBC    (Bb*Tt*48)
#define OFF_DELTA (OFF_DBC + SZ_DBC)
#define SZ_DELTA  (Bb*Tt*DI)
#define OFF_Y     (OFF_DELTA + SZ_DELTA)
#define SZ_Y      (Bb*Tt*DI)
#define OFF_HH    (OFF_Y + SZ_Y)
#define SZ_HH     (Bb*Tt*64)
#define OFF_LOGIT (OFF_HH + SZ_HH)
#define SZ_LOGIT  (Bb*Tt)
// total ~6.66M floats = ~26.6 MB

__device__ __forceinline__ float siluf(float x) { return x / (1.f + __expf(-x)); }

// ======================= CNN + fc, one block per frame =======================
__global__ __launch_bounds__(256) void cnn_fc_kernel(
    const float* __restrict__ x,
    const float* __restrict__ w1, const float* __restrict__ b1,
    const float* __restrict__ w2, const float* __restrict__ b2,
    const float* __restrict__ w3, const float* __restrict__ b3,
    const float* __restrict__ fcw, const float* __restrict__ fcb,
    float* __restrict__ hout) {
  // smem: [0,4096) input frame; [4096,8192) c1 chunk (4 ch); reused as c2 [32][256]
  __shared__ float smem[8192];
  __shared__ float s_c3[2048];   // [32][64]
  __shared__ float s_z[32];
  const int f = blockIdx.x;
  const int tid = threadIdx.x;
  const float* xin = x + (size_t)f * 4096;

  for (int i = tid; i < 1024; i += 256)
    ((float4*)smem)[i] = ((const float4*)xin)[i];

  float acc2[32];
#pragma unroll
  for (int i = 0; i < 32; ++i) acc2[i] = 0.f;
  const int oy2 = tid >> 4, ox2 = tid & 15;
  __syncthreads();

  for (int cc = 0; cc < 4; ++cc) {
    // conv1 for output channels cc*4..cc*4+3 (stride 2, SAME: pad_lo=0, pad_hi=1)
    for (int i = 0; i < 16; ++i) {
      int idx = i * 256 + tid;           // 0..4095
      int cl = idx >> 10;                // uniform per i
      int rem = idx & 1023;
      int oy = rem >> 5, ox = rem & 31;
      int oc = cc * 4 + cl;
      float s = b1[oc];
#pragma unroll
      for (int ky = 0; ky < 3; ++ky) {
        int iy = 2 * oy + ky;
        if (iy < 64) {
#pragma unroll
          for (int kx = 0; kx < 3; ++kx) {
            int ix = 2 * ox + kx;
            if (ix < 64) s += w1[oc * 9 + ky * 3 + kx] * smem[iy * 64 + ix];
          }
        }
      }
      smem[4096 + cl * 1024 + rem] = fmaxf(s, 0.f);
    }
    __syncthreads();
    // conv2 partial accumulation over these 4 input channels
#pragma unroll
    for (int icl = 0; icl < 4; ++icl) {
      int ic = cc * 4 + icl;
      float in9[9];
#pragma unroll
      for (int ky = 0; ky < 3; ++ky) {
        int iy = 2 * oy2 + ky;
#pragma unroll
        for (int kx = 0; kx < 3; ++kx) {
          int ix = 2 * ox2 + kx;
          in9[ky * 3 + kx] = (iy < 32 && ix < 32) ? smem[4096 + icl * 1024 + iy * 32 + ix] : 0.f;
        }
      }
#pragma unroll
      for (int oc = 0; oc < 32; ++oc) {
        const float* wp = w2 + oc * 144 + ic * 9;
        float s = acc2[oc];
#pragma unroll
        for (int k = 0; k < 9; ++k) s += wp[k] * in9[k];
        acc2[oc] = s;
      }
    }
    __syncthreads();
  }
  // c2 = relu(acc2 + b2) -> smem [oc][256]
#pragma unroll
  for (int oc = 0; oc < 32; ++oc)
    smem[oc * 256 + tid] = fmaxf(acc2[oc] + b2[oc], 0.f);
  __syncthreads();

  // conv3: thread -> (ocg = tid>>6, pos = tid&63)
  const int ocg = tid >> 6, pos = tid & 63;
  const int oy3 = pos >> 3, ox3 = pos & 7;
  float acc3[8];
#pragma unroll
  for (int j = 0; j < 8; ++j) acc3[j] = 0.f;
  for (int ic = 0; ic < 32; ++ic) {
    float in9[9];
#pragma unroll
    for (int ky = 0; ky < 3; ++ky) {
      int iy = 2 * oy3 + ky;
#pragma unroll
      for (int kx = 0; kx < 3; ++kx) {
        int ix = 2 * ox3 + kx;
        in9[ky * 3 + kx] = (iy < 16 && ix < 16) ? smem[ic * 256 + iy * 16 + ix] : 0.f;
      }
    }
#pragma unroll
    for (int j = 0; j < 8; ++j) {
      const float* wp = w3 + (ocg * 8 + j) * 288 + ic * 9;
      float s = acc3[j];
#pragma unroll
      for (int k = 0; k < 9; ++k) s += wp[k] * in9[k];
      acc3[j] = s;
    }
  }
#pragma unroll
  for (int j = 0; j < 8; ++j)
    s_c3[(ocg * 8 + j) * 64 + pos] = fmaxf(acc3[j] + b3[ocg * 8 + j], 0.f);
  __syncthreads();

  // global avg pool -> s_z[32]
  {
    int oc = tid >> 3, l8 = tid & 7;
    float s = 0.f;
#pragma unroll
    for (int i = 0; i < 8; ++i) s += s_c3[oc * 64 + l8 * 8 + i];
    s += __shfl_xor(s, 1);
    s += __shfl_xor(s, 2);
    s += __shfl_xor(s, 4);
    if (l8 == 0) s_z[oc] = s * (1.f / 64.f);
  }
  __syncthreads();

  // fc: 32 -> 256
  float acc = fcb[tid];
#pragma unroll
  for (int k = 0; k < 32; ++k) acc += fcw[tid * 32 + k] * s_z[k];
  hout[(size_t)f * 256 + tid] = acc;
}

// ======================= RMSNorm =======================
__global__ __launch_bounds__(256) void rmsnorm_kernel(const float* __restrict__ x,
                                                      const float* __restrict__ w,
                                                      float* __restrict__ o) {
  __shared__ float red[4];
  int t = blockIdx.x, j = threadIdx.x;
  float v = x[(size_t)t * 256 + j];
  float s = v * v;
#pragma unroll
  for (int m = 32; m; m >>= 1) s += __shfl_xor(s, m);
  if ((j & 63) == 0) red[j >> 6] = s;
  __syncthreads();
  float tot = red[0] + red[1] + red[2] + red[3];
  float r = rsqrtf(tot * (1.f / 256.f) + 1e-5f);
  o[(size_t)t * 256 + j] = v * r * w[j];
}

// ======================= GEMM NT: C[m][n] = sum_k A[m*lda+k] * W[n*K+k] ===========
// ACT: 0 none, 1 bias+softplus, 2 accumulate into C, 3 bias+gelu(tanh)
template <int ACT>
__global__ __launch_bounds__(256) void gemm_nt(const float* __restrict__ A, int lda,
                                               const float* __restrict__ W,
                                               const float* __restrict__ bias,
                                               float* __restrict__ C,
                                               int M, int N, int K) {
  __shared__ __align__(16) float sA[16][68];
  __shared__ __align__(16) float sW[16][68];
  const int m0 = blockIdx.x * 64;
  const int n0 = blockIdx.y * 64;
  const int tid = threadIdx.x;
  const int lk = tid & 15, lm = tid >> 4;
  const int tx = tid & 15, ty = tid >> 4;
  float acc[4][4] = {};

  for (int k0 = 0; k0 < K; k0 += 16) {
#pragma unroll
    for (int p = 0; p < 4; ++p) {
      int m = p * 16 + lm;
      sA[lk][m] = A[(size_t)(m0 + m) * lda + k0 + lk];
    }
#pragma unroll
    for (int p = 0; p < 4; ++p) {
      int n = p * 16 + lm;
      sW[lk][n] = (n0 + n < N) ? W[(size_t)(n0 + n) * K + k0 + lk] : 0.f;
    }
    __syncthreads();
#pragma unroll
    for (int k = 0; k < 16; ++k) {
      float4 a = *(const float4*)&sA[k][ty * 4];
      float4 b = *(const float4*)&sW[k][tx * 4];
      acc[0][0] += a.x * b.x; acc[0][1] += a.x * b.y; acc[0][2] += a.x * b.z; acc[0][3] += a.x * b.w;
      acc[1][0] += a.y * b.x; acc[1][1] += a.y * b.y; acc[1][2] += a.y * b.z; acc[1][3] += a.y * b.w;
      acc[2][0] += a.z * b.x; acc[2][1] += a.z * b.y; acc[2][2] += a.z * b.z; acc[2][3] += a.z * b.w;
      acc[3][0] += a.w * b.x; acc[3][1] += a.w * b.y; acc[3][2] += a.w * b.z; acc[3][3] += a.w * b.w;
    }
    __syncthreads();
  }
#pragma unroll
  for (int i = 0; i < 4; ++i) {
    int m = m0 + ty * 4 + i;
#pragma unroll
    for (int j = 0; j < 4; ++j) {
      int n = n0 + tx * 4 + j;
      if (n < N) {
        float v = acc[i][j];
        if (ACT == 1) {
          v += bias[n];
          v = (v > 20.f) ? v : log1pf(__expf(v));
        } else if (ACT == 2) {
          v += C[(size_t)m * N + n];
        } else if (ACT == 3) {
          v += bias[n];
          float t3 = v * v * v;
          v = 0.5f * v * (1.f + tanhf(0.7978845608028654f * (v + 0.044715f * t3)));
        }
        C[(size_t)m * N + n] = v;
      }
    }
  }
}

// ======================= causal depthwise conv1d (k=4) + silu ===================
__global__ __launch_bounds__(256) void conv1d_silu_kernel(const float* __restrict__ xz,
                                                          const float* __restrict__ cw,
                                                          const float* __restrict__ cb,
                                                          float* __restrict__ u) {
  int idx = blockIdx.x * 256 + threadIdx.x;   // over B*T*DI
  int e = idx & (DI - 1);
  int bt = idx >> 9;
  int t = bt & (Tt - 1);
  int b = bt >> 8;
  float s = cb[e];
#pragma unroll
  for (int j = 0; j < 4; ++j) {
    int tt = t - 3 + j;
    if (tt >= 0) s += cw[e * 4 + j] * xz[((size_t)(b * Tt + tt)) * (2 * DI) + e];
  }
  u[idx] = siluf(s);
}

// ======================= selective scan v2 ====================
// Block = (b, 16-e tile), 256 threads = (e_local 0..15) x (n 0..15).
// Chunked (64 t) LDS staging, reg-staged double buffer, fused silu(z) gating.
__global__ __launch_bounds__(256) void scan_kernel(const float* __restrict__ delta,
                                                   const float* __restrict__ u,
                                                   const float* __restrict__ dbc,
                                                   const float* __restrict__ xz,
                                                   const float* __restrict__ A_log,
                                                   const float* __restrict__ Dp,
                                                   float* __restrict__ y) {
  __shared__ float sD[2][64][16];
  __shared__ float sU[2][64][16];
  __shared__ float sB[2][64][16];
  __shared__ float sC[2][64][16];
  __shared__ float sY[64][16];
  const int tid = threadIdx.x;
  const int b = blockIdx.x >> 5;
  const int e0 = (blockIdx.x & 31) << 4;
  const int n = tid & 15;
  const int el = tid >> 4;
  const int e = e0 + el;
  const float An = -__expf(A_log[e * 16 + n]);
  const float Dv = Dp[e];

  // staging: thread loads column j = tid&15, rows (tid>>4) + 16r
  const int j = tid & 15;
  const int tr = tid >> 4;
  const size_t baseDU = ((size_t)b * Tt) * DI + e0 + j;   // + t*DI
  const size_t baseBC = ((size_t)b * Tt) * 48;            // + t*48 + {16,32} + j
  const size_t baseZ  = ((size_t)b * Tt) * (2 * DI) + DI + e0 + j;  // + t*2*DI

  float rd[4], ru[4], rb[4], rc[4];

  // prologue: chunk 0 -> buf 0
#pragma unroll
  for (int r = 0; r < 4; ++r) {
    int t = tr + r * 16;
    rd[r] = delta[baseDU + (size_t)t * DI];
    ru[r] = u[baseDU + (size_t)t * DI];
    rb[r] = dbc[baseBC + (size_t)t * 48 + 16 + j];
    rc[r] = dbc[baseBC + (size_t)t * 48 + 32 + j];
  }
#pragma unroll
  for (int r = 0; r < 4; ++r) {
    int tt = tr + r * 16;
    sD[0][tt][j] = rd[r]; sU[0][tt][j] = ru[r];
    sB[0][tt][j] = rb[r]; sC[0][tt][j] = rc[r];
  }
  __syncthreads();

  float h = 0.f;
  for (int c = 0; c < 4; ++c) {
    // issue next chunk's global loads (latency hides under the scan below)
    if (c < 3) {
#pragma unroll
      for (int r = 0; r < 4; ++r) {
        int t = (c + 1) * 64 + tr + r * 16;
        rd[r] = delta[baseDU + (size_t)t * DI];
        ru[r] = u[baseDU + (size_t)t * DI];
        rb[r] = dbc[baseBC + (size_t)t * 48 + 16 + j];
        rc[r] = dbc[baseBC + (size_t)t * 48 + 32 + j];
      }
    }
    const int cb_ = c & 1;
#pragma unroll 4
    for (int t = 0; t < 64; ++t) {
      float dv = sD[cb_][t][el];     // broadcast within 16-lane group
      float uv = sU[cb_][t][el];
      float Bv = sB[cb_][t][n];
      float Cv = sC[cb_][t][n];
      float dA = __expf(dv * An);
      h = dA * h + dv * Bv * uv;     // the only serial dependence
      float p = h * Cv;
      p += __shfl_xor(p, 1);
      p += __shfl_xor(p, 2);
      p += __shfl_xor(p, 4);
      p += __shfl_xor(p, 8);
      if (n == 0) sY[t][el] = p + uv * Dv;
    }
    __syncthreads();
    if (c < 3) {
#pragma unroll
      for (int r = 0; r < 4; ++r) {
        int tt = tr + r * 16;
        int nb = (c + 1) & 1;
        sD[nb][tt][j] = rd[r]; sU[nb][tt][j] = ru[r];
        sB[nb][tt][j] = rb[r]; sC[nb][tt][j] = rc[r];
      }
    }
    // gated coalesced write-out for chunk c
#pragma unroll
    for (int r = 0; r < 4; ++r) {
      int tt = tr + r * 16;
      int t = c * 64 + tt;
      float zv = xz[baseZ + (size_t)t * (2 * DI)];
      y[baseDU + (size_t)t * DI] = sY[tt][j] * siluf(zv);
    }
    __syncthreads();
  }
}

// ======================= head: logits and softmax ==============================
__global__ __launch_bounds__(256) void logits_kernel(const float* __restrict__ hh,
                                                     const float* __restrict__ w2,
                                                     const float* __restrict__ b2,
                                                     float* __restrict__ logit) {
  int t = blockIdx.x * 256 + threadIdx.x;  // 2048 tokens
  float s = b2[0];
#pragma unroll
  for (int k = 0; k < 64; ++k) s += hh[(size_t)t * 64 + k] * w2[k];
  logit[t] = s;
}

__global__ __launch_bounds__(256) void softmax_kernel(const float* __restrict__ logit,
                                                      float* __restrict__ out) {
  __shared__ float redm[4], reds[4];
  int b = blockIdx.x, t = threadIdx.x;
  float v = logit[b * 256 + t];
  float m = v;
#pragma unroll
  for (int k = 32; k; k >>= 1) m = fmaxf(m, __shfl_xor(m, k));
  if ((t & 63) == 0) redm[t >> 6] = m;
  __syncthreads();
  m = fmaxf(fmaxf(redm[0], redm[1]), fmaxf(redm[2], redm[3]));
  float e = __expf(v - m);
  float s = e;
#pragma unroll
  for (int k = 32; k; k >>= 1) s += __shfl_xor(s, k);
  if ((t & 63) == 0) reds[t >> 6] = s;
  __syncthreads();
  s = reds[0] + reds[1] + reds[2] + reds[3];
  out[b * 256 + t] = (t == 0) ? 0.f : e / s;
}

// ======================= launch ===============================================
extern "C" void kernel_launch(void* const* d_in, const int* in_sizes, int n_in,
                              void* d_out, int out_size, void* d_ws, size_t ws_size,
                              hipStream_t stream) {
  const float* x      = (const float*)d_in[0];
  const float* cnn_w1 = (const float*)d_in[1];
  const float* cnn_b1 = (const float*)d_in[2];
  const float* cnn_w2 = (const float*)d_in[3];
  const float* cnn_b2 = (const float*)d_in[4];
  const float* cnn_w3 = (const float*)d_in[5];
  const float* cnn_b3 = (const float*)d_in[6];
  const float* fc_w   = (const float*)d_in[7];
  const float* fc_b   = (const float*)d_in[8];
  const float* norm_w = (const float*)d_in[9];
  const float* ipw    = (const float*)d_in[10];
  const float* cw     = (const float*)d_in[11];
  const float* cb     = (const float*)d_in[12];
  const float* xpw    = (const float*)d_in[13];
  const float* dpw    = (const float*)d_in[14];
  const float* dpb    = (const float*)d_in[15];
  const float* A_log  = (const float*)d_in[16];
  const float* Dp     = (const float*)d_in[17];
  const float* opw    = (const float*)d_in[18];
  const float* nfw    = (const float*)d_in[19];
  const float* hw1    = (const float*)d_in[20];
  const float* hb1    = (const float*)d_in[21];
  const float* hw2    = (const float*)d_in[22];
  const float* hb2    = (const float*)d_in[23];

  float* ws    = (float*)d_ws;
  float* h     = ws + OFF_H;
  float* xn    = ws + OFF_XN;
  float* xz    = ws + OFF_XZ;
  float* u     = ws + OFF_U;
  float* dbc   = ws + OFF_DBC;
  float* delta = ws + OFF_DELTA;
  float* yb    = ws + OFF_Y;
  float* hh    = ws + OFF_HH;
  float* logit = ws + OFF_LOGIT;

  cnn_fc_kernel<<<Bb * Tt, 256, 0, stream>>>(x, cnn_w1, cnn_b1, cnn_w2, cnn_b2,
                                             cnn_w3, cnn_b3, fc_w, fc_b, h);

  for (int l = 0; l < NL; ++l) {
    rmsnorm_kernel<<<Bb * Tt, 256, 0, stream>>>(h, norm_w + l * DM, xn);
    {
      dim3 g(32, 16);
      gemm_nt<0><<<g, 256, 0, stream>>>(xn, DM, ipw + (size_t)l * 2 * DI * DM, nullptr,
                                        xz, Bb * Tt, 2 * DI, DM);
    }
    conv1d_silu_kernel<<<(Bb * Tt * DI) / 256, 256, 0, stream>>>(
        xz, cw + l * DI * 4, cb + l * DI, u);
    {
      dim3 g(32, 1);
      gemm_nt<0><<<g, 256, 0, stream>>>(u, DI, xpw + (size_t)l * 48 * DI, nullptr,
                                        dbc, Bb * Tt, 48, DI);
    }
    {
      dim3 g(32, 8);
      gemm_nt<1><<<g, 256, 0, stream>>>(dbc, 48, dpw + (size_t)l * DI * DTR,
                                        dpb + l * DI, delta, Bb * Tt, DI, DTR);
    }
    scan_kernel<<<Bb * 32, 256, 0, stream>>>(
        delta, u, dbc, xz, A_log + (size_t)l * DI * DS, Dp + l * DI, yb);
    {
      dim3 g(32, 4);
      gemm_nt<2><<<g, 256, 0, stream>>>(yb, DI, opw + (size_t)l * DM * DI, nullptr,
                                        h, Bb * Tt, DM, DI);
    }
  }

  rmsnorm_kernel<<<Bb * Tt, 256, 0, stream>>>(h, nfw, xn);
  {
    dim3 g(32, 1);
    gemm_nt<3><<<g, 256, 0, stream>>>(xn, DM, hw1, hb1, hh, Bb * Tt, 64, DM);
  }
  logits_kernel<<<Bb * Tt / 256, 256, 0, stream>>>(hh, hw2, hb2, logit);
  softmax_kernel<<<Bb, 256, 0, stream>>>(logit, (float*)d_out);
}

// Round 3
// 1188.871 us; speedup vs baseline: 2.1633x; 1.5310x over previous
//
#include <hip/hip_runtime.h>
#include <hip/hip_bf16.h>
#include <math.h>

// Problem dims
#define Bb 8
#define Tt 256
#define DM 256       // d_model
#define DI 512       // d_inner
#define NL 6
#define DS 16        // d_state
#define DTR 16       // dt_rank

// ---------------- workspace layout (floats) ----------------
#define OFF_H     0u
#define SZ_H      (Bb*Tt*DM)            // 524288
#define OFF_XN    (OFF_H + SZ_H)
#define SZ_XN     (Bb*Tt*DM)
#define OFF_XZ    (OFF_XN + SZ_XN)
#define SZ_XZ     (Bb*Tt*2*DI)          // 2097152
#define OFF_U     (OFF_XZ + SZ_XZ)
#define SZ_U      (Bb*Tt*DI)
#define OFF_DBC   (OFF_U + SZ_U)
#define SZ_DBC    (Bb*Tt*48)
#define OFF_DELTA (OFF_DBC + SZ_DBC)
#define SZ_DELTA  (Bb*Tt*DI)
#define OFF_Y     (OFF_DELTA + SZ_DELTA)
#define SZ_Y      (Bb*Tt*DI)
#define OFF_HH    (OFF_Y + SZ_Y)
#define SZ_HH     (Bb*Tt*64)
#define OFF_LOGIT (OFF_HH + SZ_HH)
#define SZ_LOGIT  (Bb*Tt)
// total ~6.66M floats = ~26.6 MB

__device__ __forceinline__ float siluf(float x) { return x / (1.f + __expf(-x)); }

typedef __attribute__((ext_vector_type(8))) short bf16x8;
typedef __attribute__((ext_vector_type(4))) float f32x4;

__device__ __forceinline__ unsigned short f2bf(float x) {
  unsigned u = __float_as_uint(x);
  u += 0x7FFFu + ((u >> 16) & 1u);   // RNE
  return (unsigned short)(u >> 16);
}

// ======================= CNN + fc, one block per frame =======================
__global__ __launch_bounds__(256) void cnn_fc_kernel(
    const float* __restrict__ x,
    const float* __restrict__ w1, const float* __restrict__ b1,
    const float* __restrict__ w2, const float* __restrict__ b2,
    const float* __restrict__ w3, const float* __restrict__ b3,
    const float* __restrict__ fcw, const float* __restrict__ fcb,
    float* __restrict__ hout) {
  // smem: [0,4096) input frame; [4096,8192) c1 chunk (4 ch); reused as c2 [32][256]
  __shared__ float smem[8192];
  __shared__ float s_c3[2048];   // [32][64]
  __shared__ float s_z[32];
  const int f = blockIdx.x;
  const int tid = threadIdx.x;
  const float* xin = x + (size_t)f * 4096;

  for (int i = tid; i < 1024; i += 256)
    ((float4*)smem)[i] = ((const float4*)xin)[i];

  float acc2[32];
#pragma unroll
  for (int i = 0; i < 32; ++i) acc2[i] = 0.f;
  const int oy2 = tid >> 4, ox2 = tid & 15;
  __syncthreads();

  for (int cc = 0; cc < 4; ++cc) {
    // conv1 for output channels cc*4..cc*4+3 (stride 2, SAME: pad_lo=0, pad_hi=1)
    for (int i = 0; i < 16; ++i) {
      int idx = i * 256 + tid;           // 0..4095
      int cl = idx >> 10;                // uniform per i
      int rem = idx & 1023;
      int oy = rem >> 5, ox = rem & 31;
      int oc = cc * 4 + cl;
      float s = b1[oc];
#pragma unroll
      for (int ky = 0; ky < 3; ++ky) {
        int iy = 2 * oy + ky;
        if (iy < 64) {
#pragma unroll
          for (int kx = 0; kx < 3; ++kx) {
            int ix = 2 * ox + kx;
            if (ix < 64) s += w1[oc * 9 + ky * 3 + kx] * smem[iy * 64 + ix];
          }
        }
      }
      smem[4096 + cl * 1024 + rem] = fmaxf(s, 0.f);
    }
    __syncthreads();
    // conv2 partial accumulation over these 4 input channels
#pragma unroll
    for (int icl = 0; icl < 4; ++icl) {
      int ic = cc * 4 + icl;
      float in9[9];
#pragma unroll
      for (int ky = 0; ky < 3; ++ky) {
        int iy = 2 * oy2 + ky;
#pragma unroll
        for (int kx = 0; kx < 3; ++kx) {
          int ix = 2 * ox2 + kx;
          in9[ky * 3 + kx] = (iy < 32 && ix < 32) ? smem[4096 + icl * 1024 + iy * 32 + ix] : 0.f;
        }
      }
#pragma unroll
      for (int oc = 0; oc < 32; ++oc) {
        const float* wp = w2 + oc * 144 + ic * 9;
        float s = acc2[oc];
#pragma unroll
        for (int k = 0; k < 9; ++k) s += wp[k] * in9[k];
        acc2[oc] = s;
      }
    }
    __syncthreads();
  }
  // c2 = relu(acc2 + b2) -> smem [oc][256]
#pragma unroll
  for (int oc = 0; oc < 32; ++oc)
    smem[oc * 256 + tid] = fmaxf(acc2[oc] + b2[oc], 0.f);
  __syncthreads();

  // conv3: thread -> (ocg = tid>>6, pos = tid&63)
  const int ocg = tid >> 6, pos = tid & 63;
  const int oy3 = pos >> 3, ox3 = pos & 7;
  float acc3[8];
#pragma unroll
  for (int j = 0; j < 8; ++j) acc3[j] = 0.f;
  for (int ic = 0; ic < 32; ++ic) {
    float in9[9];
#pragma unroll
    for (int ky = 0; ky < 3; ++ky) {
      int iy = 2 * oy3 + ky;
#pragma unroll
      for (int kx = 0; kx < 3; ++kx) {
        int ix = 2 * ox3 + kx;
        in9[ky * 3 + kx] = (iy < 16 && ix < 16) ? smem[ic * 256 + iy * 16 + ix] : 0.f;
      }
    }
#pragma unroll
    for (int j = 0; j < 8; ++j) {
      const float* wp = w3 + (ocg * 8 + j) * 288 + ic * 9;
      float s = acc3[j];
#pragma unroll
      for (int k = 0; k < 9; ++k) s += wp[k] * in9[k];
      acc3[j] = s;
    }
  }
#pragma unroll
  for (int j = 0; j < 8; ++j)
    s_c3[(ocg * 8 + j) * 64 + pos] = fmaxf(acc3[j] + b3[ocg * 8 + j], 0.f);
  __syncthreads();

  // global avg pool -> s_z[32]
  {
    int oc = tid >> 3, l8 = tid & 7;
    float s = 0.f;
#pragma unroll
    for (int i = 0; i < 8; ++i) s += s_c3[oc * 64 + l8 * 8 + i];
    s += __shfl_xor(s, 1);
    s += __shfl_xor(s, 2);
    s += __shfl_xor(s, 4);
    if (l8 == 0) s_z[oc] = s * (1.f / 64.f);
  }
  __syncthreads();

  // fc: 32 -> 256
  float acc = fcb[tid];
#pragma unroll
  for (int k = 0; k < 32; ++k) acc += fcw[tid * 32 + k] * s_z[k];
  hout[(size_t)f * 256 + tid] = acc;
}

// ======================= RMSNorm =======================
__global__ __launch_bounds__(256) void rmsnorm_kernel(const float* __restrict__ x,
                                                      const float* __restrict__ w,
                                                      float* __restrict__ o) {
  __shared__ float red[4];
  int t = blockIdx.x, j = threadIdx.x;
  float v = x[(size_t)t * 256 + j];
  float s = v * v;
#pragma unroll
  for (int m = 32; m; m >>= 1) s += __shfl_xor(s, m);
  if ((j & 63) == 0) red[j >> 6] = s;
  __syncthreads();
  float tot = red[0] + red[1] + red[2] + red[3];
  float r = rsqrtf(tot * (1.f / 256.f) + 1e-5f);
  o[(size_t)t * 256 + j] = v * r * w[j];
}

// ============== bf16 MFMA GEMM NT: C[m][n] = sum_k A[m][k] * W[n][k] ==========
// fp32 in/out; converts to bf16 during LDS staging. 64x64 tile, BK=64,
// 4 waves of 2x2 16x16x32 frags. ACT: 0 write, 2 accumulate into C.
// LDS rows padded to 72 bf16 (144B) -> <=2-way bank aliasing on ds_read_b128.
template <int ACT>
__global__ __launch_bounds__(256) void gemm_bf16(const float* __restrict__ A,
                                                 const float* __restrict__ W,
                                                 float* __restrict__ C,
                                                 int M, int N, int K) {
  __shared__ __align__(16) unsigned short sA[64 * 72];
  __shared__ __align__(16) unsigned short sW[64 * 72];
  const int tid = threadIdx.x;
  const int m0 = blockIdx.x * 64, n0 = blockIdx.y * 64;
  // staging coords: thread -> (row, 16-float segment)
  const int srow = tid >> 2, sseg = tid & 3;
  int wrow = n0 + srow; if (wrow >= N) wrow = 0;   // clamp (x_proj N=48); garbage cols discarded
  const float* gA = A + (size_t)(m0 + srow) * K + sseg * 16;
  const float* gW = W + (size_t)wrow * K + sseg * 16;
  // compute coords
  const int wv = tid >> 6, wm = wv >> 1, wn = wv & 1;
  const int fr = tid & 15;            // frag row (A) / col (B)
  const int fq = (tid >> 4) & 3;      // k-chunk
  f32x4 acc[2][2] = {};

  const int NT = K >> 6;
  float4 ra[4], rw[4];
#pragma unroll
  for (int q = 0; q < 4; ++q) {
    ra[q] = ((const float4*)gA)[q];
    rw[q] = ((const float4*)gW)[q];
  }
  // convert + write LDS
  {
    unsigned short* pa = &sA[srow * 72 + sseg * 16];
    unsigned short* pw = &sW[srow * 72 + sseg * 16];
#pragma unroll
    for (int q = 0; q < 4; ++q) {
      const float* f = (const float*)&ra[q];
      pa[q * 4 + 0] = f2bf(f[0]); pa[q * 4 + 1] = f2bf(f[1]);
      pa[q * 4 + 2] = f2bf(f[2]); pa[q * 4 + 3] = f2bf(f[3]);
      const float* g = (const float*)&rw[q];
      pw[q * 4 + 0] = f2bf(g[0]); pw[q * 4 + 1] = f2bf(g[1]);
      pw[q * 4 + 2] = f2bf(g[2]); pw[q * 4 + 3] = f2bf(g[3]);
    }
  }
  __syncthreads();

  for (int kt = 0; kt < NT; ++kt) {
    // issue next tile's global loads early (latency hides under MFMA)
    if (kt + 1 < NT) {
#pragma unroll
      for (int q = 0; q < 4; ++q) {
        ra[q] = ((const float4*)(gA + (kt + 1) * 64))[q];
        rw[q] = ((const float4*)(gW + (kt + 1) * 64))[q];
      }
    }
    // compute current tile
#pragma unroll
    for (int ks = 0; ks < 2; ++ks) {
      bf16x8 a0 = *(const bf16x8*)&sA[(wm * 32 + fr) * 72 + ks * 32 + fq * 8];
      bf16x8 a1 = *(const bf16x8*)&sA[(wm * 32 + 16 + fr) * 72 + ks * 32 + fq * 8];
      bf16x8 b0 = *(const bf16x8*)&sW[(wn * 32 + fr) * 72 + ks * 32 + fq * 8];
      bf16x8 b1 = *(const bf16x8*)&sW[(wn * 32 + 16 + fr) * 72 + ks * 32 + fq * 8];
      acc[0][0] = __builtin_amdgcn_mfma_f32_16x16x32_bf16(a0, b0, acc[0][0], 0, 0, 0);
      acc[0][1] = __builtin_amdgcn_mfma_f32_16x16x32_bf16(a0, b1, acc[0][1], 0, 0, 0);
      acc[1][0] = __builtin_amdgcn_mfma_f32_16x16x32_bf16(a1, b0, acc[1][0], 0, 0, 0);
      acc[1][1] = __builtin_amdgcn_mfma_f32_16x16x32_bf16(a1, b1, acc[1][1], 0, 0, 0);
    }
    __syncthreads();
    if (kt + 1 < NT) {
      unsigned short* pa = &sA[srow * 72 + sseg * 16];
      unsigned short* pw = &sW[srow * 72 + sseg * 16];
#pragma unroll
      for (int q = 0; q < 4; ++q) {
        const float* f = (const float*)&ra[q];
        pa[q * 4 + 0] = f2bf(f[0]); pa[q * 4 + 1] = f2bf(f[1]);
        pa[q * 4 + 2] = f2bf(f[2]); pa[q * 4 + 3] = f2bf(f[3]);
        const float* g = (const float*)&rw[q];
        pw[q * 4 + 0] = f2bf(g[0]); pw[q * 4 + 1] = f2bf(g[1]);
        pw[q * 4 + 2] = f2bf(g[2]); pw[q * 4 + 3] = f2bf(g[3]);
      }
      __syncthreads();
    }
  }

  // epilogue: C/D layout col=lane&15, row=(lane>>4)*4+j  (m89-verified)
#pragma unroll
  for (int mr = 0; mr < 2; ++mr) {
#pragma unroll
    for (int nr = 0; nr < 2; ++nr) {
      int n = n0 + wn * 32 + nr * 16 + fr;
      if (n < N) {
#pragma unroll
        for (int j = 0; j < 4; ++j) {
          int m = m0 + wm * 32 + mr * 16 + fq * 4 + j;
          size_t idx = (size_t)m * N + n;
          if (ACT == 2) C[idx] += acc[mr][nr][j];
          else C[idx] = acc[mr][nr][j];
        }
      }
    }
  }
}

// ======================= GEMM NT fp32 (small): C = A*W^T ======================
// ACT: 1 bias+softplus, 3 bias+gelu(tanh)
template <int ACT>
__global__ __launch_bounds__(256) void gemm_nt(const float* __restrict__ A, int lda,
                                               const float* __restrict__ W,
                                               const float* __restrict__ bias,
                                               float* __restrict__ C,
                                               int M, int N, int K) {
  __shared__ __align__(16) float sA[16][68];
  __shared__ __align__(16) float sW[16][68];
  const int m0 = blockIdx.x * 64;
  const int n0 = blockIdx.y * 64;
  const int tid = threadIdx.x;
  const int lk = tid & 15, lm = tid >> 4;
  const int tx = tid & 15, ty = tid >> 4;
  float acc[4][4] = {};

  for (int k0 = 0; k0 < K; k0 += 16) {
#pragma unroll
    for (int p = 0; p < 4; ++p) {
      int m = p * 16 + lm;
      sA[lk][m] = A[(size_t)(m0 + m) * lda + k0 + lk];
    }
#pragma unroll
    for (int p = 0; p < 4; ++p) {
      int n = p * 16 + lm;
      sW[lk][n] = (n0 + n < N) ? W[(size_t)(n0 + n) * K + k0 + lk] : 0.f;
    }
    __syncthreads();
#pragma unroll
    for (int k = 0; k < 16; ++k) {
      float4 a = *(const float4*)&sA[k][ty * 4];
      float4 b = *(const float4*)&sW[k][tx * 4];
      acc[0][0] += a.x * b.x; acc[0][1] += a.x * b.y; acc[0][2] += a.x * b.z; acc[0][3] += a.x * b.w;
      acc[1][0] += a.y * b.x; acc[1][1] += a.y * b.y; acc[1][2] += a.y * b.z; acc[1][3] += a.y * b.w;
      acc[2][0] += a.z * b.x; acc[2][1] += a.z * b.y; acc[2][2] += a.z * b.z; acc[2][3] += a.z * b.w;
      acc[3][0] += a.w * b.x; acc[3][1] += a.w * b.y; acc[3][2] += a.w * b.z; acc[3][3] += a.w * b.w;
    }
    __syncthreads();
  }
#pragma unroll
  for (int i = 0; i < 4; ++i) {
    int m = m0 + ty * 4 + i;
#pragma unroll
    for (int j = 0; j < 4; ++j) {
      int n = n0 + tx * 4 + j;
      if (n < N) {
        float v = acc[i][j];
        if (ACT == 1) {
          v += bias[n];
          v = (v > 20.f) ? v : log1pf(__expf(v));
        } else if (ACT == 3) {
          v += bias[n];
          float t3 = v * v * v;
          v = 0.5f * v * (1.f + tanhf(0.7978845608028654f * (v + 0.044715f * t3)));
        }
        C[(size_t)m * N + n] = v;
      }
    }
  }
}

// ======================= causal depthwise conv1d (k=4) + silu ===================
__global__ __launch_bounds__(256) void conv1d_silu_kernel(const float* __restrict__ xz,
                                                          const float* __restrict__ cw,
                                                          const float* __restrict__ cb,
                                                          float* __restrict__ u) {
  int idx = blockIdx.x * 256 + threadIdx.x;   // over B*T*DI
  int e = idx & (DI - 1);
  int bt = idx >> 9;
  int t = bt & (Tt - 1);
  int b = bt >> 8;
  float s = cb[e];
#pragma unroll
  for (int j = 0; j < 4; ++j) {
    int tt = t - 3 + j;
    if (tt >= 0) s += cw[e * 4 + j] * xz[((size_t)(b * Tt + tt)) * (2 * DI) + e];
  }
  u[idx] = siluf(s);
}

// ======================= selective scan v2 ====================
__global__ __launch_bounds__(256) void scan_kernel(const float* __restrict__ delta,
                                                   const float* __restrict__ u,
                                                   const float* __restrict__ dbc,
                                                   const float* __restrict__ xz,
                                                   const float* __restrict__ A_log,
                                                   const float* __restrict__ Dp,
                                                   float* __restrict__ y) {
  __shared__ float sD[2][64][16];
  __shared__ float sU[2][64][16];
  __shared__ float sB[2][64][16];
  __shared__ float sC[2][64][16];
  __shared__ float sY[64][16];
  const int tid = threadIdx.x;
  const int b = blockIdx.x >> 5;
  const int e0 = (blockIdx.x & 31) << 4;
  const int n = tid & 15;
  const int el = tid >> 4;
  const int e = e0 + el;
  const float An = -__expf(A_log[e * 16 + n]);
  const float Dv = Dp[e];

  const int j = tid & 15;
  const int tr = tid >> 4;
  const size_t baseDU = ((size_t)b * Tt) * DI + e0 + j;   // + t*DI
  const size_t baseBC = ((size_t)b * Tt) * 48;            // + t*48 + {16,32} + j
  const size_t baseZ  = ((size_t)b * Tt) * (2 * DI) + DI + e0 + j;  // + t*2*DI

  float rd[4], ru[4], rb[4], rc[4];

#pragma unroll
  for (int r = 0; r < 4; ++r) {
    int t = tr + r * 16;
    rd[r] = delta[baseDU + (size_t)t * DI];
    ru[r] = u[baseDU + (size_t)t * DI];
    rb[r] = dbc[baseBC + (size_t)t * 48 + 16 + j];
    rc[r] = dbc[baseBC + (size_t)t * 48 + 32 + j];
  }
#pragma unroll
  for (int r = 0; r < 4; ++r) {
    int tt = tr + r * 16;
    sD[0][tt][j] = rd[r]; sU[0][tt][j] = ru[r];
    sB[0][tt][j] = rb[r]; sC[0][tt][j] = rc[r];
  }
  __syncthreads();

  float h = 0.f;
  for (int c = 0; c < 4; ++c) {
    if (c < 3) {
#pragma unroll
      for (int r = 0; r < 4; ++r) {
        int t = (c + 1) * 64 + tr + r * 16;
        rd[r] = delta[baseDU + (size_t)t * DI];
        ru[r] = u[baseDU + (size_t)t * DI];
        rb[r] = dbc[baseBC + (size_t)t * 48 + 16 + j];
        rc[r] = dbc[baseBC + (size_t)t * 48 + 32 + j];
      }
    }
    const int cb_ = c & 1;
#pragma unroll 4
    for (int t = 0; t < 64; ++t) {
      float dv = sD[cb_][t][el];
      float uv = sU[cb_][t][el];
      float Bv = sB[cb_][t][n];
      float Cv = sC[cb_][t][n];
      float dA = __expf(dv * An);
      h = dA * h + dv * Bv * uv;
      float p = h * Cv;
      p += __shfl_xor(p, 1);
      p += __shfl_xor(p, 2);
      p += __shfl_xor(p, 4);
      p += __shfl_xor(p, 8);
      if (n == 0) sY[t][el] = p + uv * Dv;
    }
    __syncthreads();
    if (c < 3) {
#pragma unroll
      for (int r = 0; r < 4; ++r) {
        int tt = tr + r * 16;
        int nb = (c + 1) & 1;
        sD[nb][tt][j] = rd[r]; sU[nb][tt][j] = ru[r];
        sB[nb][tt][j] = rb[r]; sC[nb][tt][j] = rc[r];
      }
    }
#pragma unroll
    for (int r = 0; r < 4; ++r) {
      int tt = tr + r * 16;
      int t = c * 64 + tt;
      float zv = xz[baseZ + (size_t)t * (2 * DI)];
      y[baseDU + (size_t)t * DI] = sY[tt][j] * siluf(zv);
    }
    __syncthreads();
  }
}

// ======================= head: logits and softmax ==============================
__global__ __launch_bounds__(256) void logits_kernel(const float* __restrict__ hh,
                                                     const float* __restrict__ w2,
                                                     const float* __restrict__ b2,
                                                     float* __restrict__ logit) {
  int t = blockIdx.x * 256 + threadIdx.x;  // 2048 tokens
  float s = b2[0];
#pragma unroll
  for (int k = 0; k < 64; ++k) s += hh[(size_t)t * 64 + k] * w2[k];
  logit[t] = s;
}

__global__ __launch_bounds__(256) void softmax_kernel(const float* __restrict__ logit,
                                                      float* __restrict__ out) {
  __shared__ float redm[4], reds[4];
  int b = blockIdx.x, t = threadIdx.x;
  float v = logit[b * 256 + t];
  float m = v;
#pragma unroll
  for (int k = 32; k; k >>= 1) m = fmaxf(m, __shfl_xor(m, k));
  if ((t & 63) == 0) redm[t >> 6] = m;
  __syncthreads();
  m = fmaxf(fmaxf(redm[0], redm[1]), fmaxf(redm[2], redm[3]));
  float e = __expf(v - m);
  float s = e;
#pragma unroll
  for (int k = 32; k; k >>= 1) s += __shfl_xor(s, k);
  if ((t & 63) == 0) reds[t >> 6] = s;
  __syncthreads();
  s = reds[0] + reds[1] + reds[2] + reds[3];
  out[b * 256 + t] = (t == 0) ? 0.f : e / s;
}

// ======================= launch ===============================================
extern "C" void kernel_launch(void* const* d_in, const int* in_sizes, int n_in,
                              void* d_out, int out_size, void* d_ws, size_t ws_size,
                              hipStream_t stream) {
  const float* x      = (const float*)d_in[0];
  const float* cnn_w1 = (const float*)d_in[1];
  const float* cnn_b1 = (const float*)d_in[2];
  const float* cnn_w2 = (const float*)d_in[3];
  const float* cnn_b2 = (const float*)d_in[4];
  const float* cnn_w3 = (const float*)d_in[5];
  const float* cnn_b3 = (const float*)d_in[6];
  const float* fc_w   = (const float*)d_in[7];
  const float* fc_b   = (const float*)d_in[8];
  const float* norm_w = (const float*)d_in[9];
  const float* ipw    = (const float*)d_in[10];
  const float* cw     = (const float*)d_in[11];
  const float* cb     = (const float*)d_in[12];
  const float* xpw    = (const float*)d_in[13];
  const float* dpw    = (const float*)d_in[14];
  const float* dpb    = (const float*)d_in[15];
  const float* A_log  = (const float*)d_in[16];
  const float* Dp     = (const float*)d_in[17];
  const float* opw    = (const float*)d_in[18];
  const float* nfw    = (const float*)d_in[19];
  const float* hw1    = (const float*)d_in[20];
  const float* hb1    = (const float*)d_in[21];
  const float* hw2    = (const float*)d_in[22];
  const float* hb2    = (const float*)d_in[23];

  float* ws    = (float*)d_ws;
  float* h     = ws + OFF_H;
  float* xn    = ws + OFF_XN;
  float* xz    = ws + OFF_XZ;
  float* u     = ws + OFF_U;
  float* dbc   = ws + OFF_DBC;
  float* delta = ws + OFF_DELTA;
  float* yb    = ws + OFF_Y;
  float* hh    = ws + OFF_HH;
  float* logit = ws + OFF_LOGIT;

  cnn_fc_kernel<<<Bb * Tt, 256, 0, stream>>>(x, cnn_w1, cnn_b1, cnn_w2, cnn_b2,
                                             cnn_w3, cnn_b3, fc_w, fc_b, h);

  for (int l = 0; l < NL; ++l) {
    rmsnorm_kernel<<<Bb * Tt, 256, 0, stream>>>(h, norm_w + l * DM, xn);
    {
      dim3 g(32, 16);   // M=2048, N=1024, K=256
      gemm_bf16<0><<<g, 256, 0, stream>>>(xn, ipw + (size_t)l * 2 * DI * DM, xz,
                                          Bb * Tt, 2 * DI, DM);
    }
    conv1d_silu_kernel<<<(Bb * Tt * DI) / 256, 256, 0, stream>>>(
        xz, cw + l * DI * 4, cb + l * DI, u);
    {
      dim3 g(32, 1);    // M=2048, N=48, K=512
      gemm_bf16<0><<<g, 256, 0, stream>>>(u, xpw + (size_t)l * 48 * DI, dbc,
                                          Bb * Tt, 48, DI);
    }
    {
      dim3 g(32, 8);    // delta: K=16, stays fp32 vector
      gemm_nt<1><<<g, 256, 0, stream>>>(dbc, 48, dpw + (size_t)l * DI * DTR,
                                        dpb + l * DI, delta, Bb * Tt, DI, DTR);
    }
    scan_kernel<<<Bb * 32, 256, 0, stream>>>(
        delta, u, dbc, xz, A_log + (size_t)l * DI * DS, Dp + l * DI, yb);
    {
      dim3 g(32, 4);    // M=2048, N=256, K=512, accumulate into h
      gemm_bf16<2><<<g, 256, 0, stream>>>(yb, opw + (size_t)l * DM * DI, h,
                                          Bb * Tt, DM, DI);
    }
  }

  rmsnorm_kernel<<<Bb * Tt, 256, 0, stream>>>(h, nfw, xn);
  {
    dim3 g(32, 1);
    gemm_nt<3><<<g, 256, 0, stream>>>(xn, DM, hw1, hb1, hh, Bb * Tt, 64, DM);
  }
  logits_kernel<<<Bb * Tt / 256, 256, 0, stream>>>(hh, hw2, hb2, logit);
  softmax_kernel<<<Bb, 256, 0, stream>>>(logit, (float*)d_out);
}

// Round 4
// 858.993 us; speedup vs baseline: 2.9941x; 1.3840x over previous
//
#include <hip/hip_runtime.h>
#include <hip/hip_bf16.h>
#include <math.h>

// Problem dims
#define Bb 8
#define Tt 256
#define DM 256       // d_model
#define DI 512       // d_inner
#define NL 6
#define DS 16        // d_state
#define DTR 16       // dt_rank

// ---------------- workspace layout (floats) ----------------
#define OFF_H     0u
#define SZ_H      (Bb*Tt*DM)
#define OFF_XN    (OFF_H + SZ_H)
#define SZ_XN     (Bb*Tt*DM)
#define OFF_XZ    (OFF_XN + SZ_XN)
#define SZ_XZ     (Bb*Tt*2*DI)
#define OFF_U     (OFF_XZ + SZ_XZ)
#define SZ_U      (Bb*Tt*DI)
#define OFF_DBC   (OFF_U + SZ_U)
#define SZ_DBC    (Bb*Tt*48)
#define OFF_DELTA (OFF_DBC + SZ_DBC)
#define SZ_DELTA  (Bb*Tt*DI)
#define OFF_Y     (OFF_DELTA + SZ_DELTA)
#define SZ_Y      (Bb*Tt*DI)
#define OFF_HH    (OFF_Y + SZ_Y)
#define SZ_HH     (Bb*Tt*64)
#define OFF_LOGIT (OFF_HH + SZ_HH)
#define SZ_LOGIT  (Bb*Tt)

__device__ __forceinline__ float siluf(float x) { return x / (1.f + __expf(-x)); }

typedef __attribute__((ext_vector_type(8))) short bf16x8;
typedef __attribute__((ext_vector_type(4))) short bf16x4;
typedef __attribute__((ext_vector_type(4))) float f32x4;

__device__ __forceinline__ unsigned short f2bf(float x) {
  unsigned u = __float_as_uint(x);
  u += 0x7FFFu + ((u >> 16) & 1u);   // RNE
  return (unsigned short)(u >> 16);
}
__device__ __forceinline__ float bf2f(unsigned short u) {
  return __uint_as_float((unsigned)u << 16);
}

// ================== CNN (implicit-GEMM MFMA) + fc, one block per frame =========
// LDS (ushort units, 62048 B total):
//   frameb [0,4096)           bf16 [64][64]       (phase 1-2)
//   w2t    [0,6400)           [5][32][40]         (phase 3-4; overlaps frameb)
//   c1t    [6400,22800)       [1025][16]          (rows 32B; row 1024 = zeros)
//   c2t    [22800,31024)      [257][32] swizzled  (rows 64B; row 256 = zeros)
//   w3t    [0,11520)          [9][32][40]         (phase 5-6; overlaps w2t+c1t head)
__global__ __launch_bounds__(256) void cnn_fc_mfma(
    const float* __restrict__ x,
    const float* __restrict__ w1, const float* __restrict__ b1,
    const float* __restrict__ w2, const float* __restrict__ b2,
    const float* __restrict__ w3, const float* __restrict__ b3,
    const float* __restrict__ fcw, const float* __restrict__ fcb,
    float* __restrict__ hout) {
  __shared__ __align__(16) unsigned short ldsu[31024];
  __shared__ float s_pool[32];
  const int tid = threadIdx.x;
  const int f = blockIdx.x;
  const int lane = tid & 63;
  const int lc = lane & 15;          // MFMA col/row-within-tile
  const int fq = lane >> 4;          // k-chunk (0..3)
  const int wv = tid >> 6;           // wave id (0..3)

  const int FR = 0;
  const int W2 = 0;
  const int C1 = 6400;
  const int C2 = 22800;
  const int W3 = 0;

  // ---- P1: frame -> bf16 LDS; zero rows; zero pool
  {
    const float* xin = x + (size_t)f * 4096;
#pragma unroll
    for (int r = 0; r < 4; ++r) {
      float4 v = ((const float4*)xin)[r * 256 + tid];
      bf16x4 o;
      o[0] = (short)f2bf(v.x); o[1] = (short)f2bf(v.y);
      o[2] = (short)f2bf(v.z); o[3] = (short)f2bf(v.w);
      *(bf16x4*)&ldsu[FR + (r * 256 + tid) * 4] = o;
    }
    if (tid < 8)  ((unsigned*)&ldsu[C1 + 1024 * 16])[tid] = 0u;
    if (tid < 16) ((unsigned*)&ldsu[C2 + 256 * 32])[tid] = 0u;
    if (tid < 32) s_pool[tid] = 0.f;
  }
  __syncthreads();

  // ---- P2: conv1 (VALU, 1->16ch, 64x64 -> 32x32), write c1t[pos][ic] bf16
#pragma unroll
  for (int r = 0; r < 4; ++r) {
    int p = r * 256 + tid;           // 0..1023
    int oy = p >> 5, ox = p & 31;
    float in9[9];
#pragma unroll
    for (int ky = 0; ky < 3; ++ky) {
      int iy = 2 * oy + ky;
#pragma unroll
      for (int kx = 0; kx < 3; ++kx) {
        int ix = 2 * ox + kx;
        in9[ky * 3 + kx] = (iy < 64 && ix < 64) ? bf2f(ldsu[FR + iy * 64 + ix]) : 0.f;
      }
    }
    bf16x8 o0, o1;
#pragma unroll
    for (int oc = 0; oc < 8; ++oc) {
      float s = b1[oc];
#pragma unroll
      for (int k = 0; k < 9; ++k) s += w1[oc * 9 + k] * in9[k];
      o0[oc] = (short)f2bf(fmaxf(s, 0.f));
    }
#pragma unroll
    for (int oc = 0; oc < 8; ++oc) {
      float s = b1[8 + oc];
#pragma unroll
      for (int k = 0; k < 9; ++k) s += w1[(8 + oc) * 9 + k] * in9[k];
      o1[oc] = (short)f2bf(fmaxf(s, 0.f));
    }
    *(bf16x8*)&ldsu[C1 + p * 16] = o0;
    *(bf16x8*)&ldsu[C1 + p * 16 + 8] = o1;
  }
  __syncthreads();

  // ---- P3: stage w2t [kt(5)][oc(32)][k(32) pad40]; k = tappair-half*16 + ic
  for (int r = 0; r < 20; ++r) {
    int i = r * 256 + tid;           // 0..5119
    int kt = i >> 10, rem = i & 1023;
    int oc = rem >> 5, k = rem & 31;
    int tap = 2 * kt + (k >> 4), ic = k & 15;
    float v = (tap < 9) ? w2[oc * 144 + ic * 9 + tap] : 0.f;
    ldsu[W2 + (kt * 32 + oc) * 40 + k] = f2bf(v);
  }
  __syncthreads();

  // ---- P4: conv2 MFMA (16->32ch, 32x32 -> 16x16). A=w2t, B=c1 positions.
  {
    f32x4 acc[2][4] = {};
    for (int kt = 0; kt < 5; ++kt) {
      bf16x8 a0 = *(const bf16x8*)&ldsu[W2 + (kt * 32 + lc) * 40 + fq * 8];
      bf16x8 a1 = *(const bf16x8*)&ldsu[W2 + (kt * 32 + 16 + lc) * 40 + fq * 8];
      int tap = 2 * kt + (fq >> 1);
      int t9 = (tap < 9) ? tap : 0;
      int ky = (t9 * 11) >> 5;
      int kx = t9 - ky * 3;
      int ix = 2 * lc + kx;
#pragma unroll
      for (int ni = 0; ni < 4; ++ni) {
        int nt = wv * 4 + ni;        // = output row py
        int iy = 2 * nt + ky;
        int ipos = (tap < 9 && iy < 32 && ix < 32) ? iy * 32 + ix : 1024;
        bf16x8 b = *(const bf16x8*)&ldsu[C1 + ipos * 16 + (fq & 1) * 8];
        acc[0][ni] = __builtin_amdgcn_mfma_f32_16x16x32_bf16(a0, b, acc[0][ni], 0, 0, 0);
        acc[1][ni] = __builtin_amdgcn_mfma_f32_16x16x32_bf16(a1, b, acc[1][ni], 0, 0, 0);
      }
    }
    // epilogue: bias+relu -> c2t[pos][oc] bf16, 8B-granule XOR swizzle
#pragma unroll
    for (int mi = 0; mi < 2; ++mi) {
      int oc0 = mi * 16 + fq * 4;
#pragma unroll
      for (int ni = 0; ni < 4; ++ni) {
        int pos = (wv * 4 + ni) * 16 + lc;
        bf16x4 o;
#pragma unroll
        for (int j = 0; j < 4; ++j)
          o[j] = (short)f2bf(fmaxf(acc[mi][ni][j] + b2[oc0 + j], 0.f));
        int g = mi * 4 + fq;
        int gp = ((((g >> 1) ^ ((pos >> 1) & 3)) << 1) | (g & 1));
        *(bf16x4*)&ldsu[C2 + pos * 32 + gp * 4] = o;
      }
    }
  }
  __syncthreads();

  // ---- P5: stage w3t [tap(9)][oc(32)][ic(32) pad40]
  for (int r = 0; r < 36; ++r) {
    int i = r * 256 + tid;           // 0..9215
    int tap = i >> 10, rem = i & 1023;
    int oc = rem >> 5, ic = rem & 31;
    ldsu[W3 + (tap * 32 + oc) * 40 + ic] = f2bf(w3[oc * 288 + ic * 9 + tap]);
  }
  __syncthreads();

  // ---- P6: conv3 MFMA (32->32ch, 16x16 -> 8x8) + bias+relu+pool
  {
    const int mh = wv >> 1, nb = wv & 1;
    f32x4 acc[2] = {};
#pragma unroll
    for (int tap = 0; tap < 9; ++tap) {
      const int ky = tap / 3, kx = tap % 3;
      bf16x8 a = *(const bf16x8*)&ldsu[W3 + (tap * 32 + mh * 16 + lc) * 40 + fq * 8];
#pragma unroll
      for (int ni = 0; ni < 2; ++ni) {
        int pos = (nb * 2 + ni) * 16 + lc;    // 0..63
        int py = pos >> 3, px = pos & 7;
        int iy = 2 * py + ky, ix = 2 * px + kx;
        int ipos = (iy < 16 && ix < 16) ? iy * 16 + ix : 256;
        int sp = fq ^ ((ipos >> 1) & 3);
        bf16x8 b = *(const bf16x8*)&ldsu[C2 + ipos * 32 + sp * 8];
        acc[ni] = __builtin_amdgcn_mfma_f32_16x16x32_bf16(a, b, acc[ni], 0, 0, 0);
      }
    }
    int oc0 = mh * 16 + fq * 4;
#pragma unroll
    for (int j = 0; j < 4; ++j) {
      float v = fmaxf(acc[0][j] + b3[oc0 + j], 0.f) +
                fmaxf(acc[1][j] + b3[oc0 + j], 0.f);
      v += __shfl_xor(v, 1);
      v += __shfl_xor(v, 2);
      v += __shfl_xor(v, 4);
      v += __shfl_xor(v, 8);
      if (lc == 0) atomicAdd(&s_pool[oc0 + j], v);
    }
  }
  __syncthreads();

  // ---- P7: fc 32 -> 256
  {
    float dot = 0.f;
#pragma unroll
    for (int k = 0; k < 32; ++k) dot += fcw[tid * 32 + k] * s_pool[k];
    hout[(size_t)f * 256 + tid] = fcb[tid] + dot * (1.f / 64.f);
  }
}

// ======================= RMSNorm =======================
__global__ __launch_bounds__(256) void rmsnorm_kernel(const float* __restrict__ x,
                                                      const float* __restrict__ w,
                                                      float* __restrict__ o) {
  __shared__ float red[4];
  int t = blockIdx.x, j = threadIdx.x;
  float v = x[(size_t)t * 256 + j];
  float s = v * v;
#pragma unroll
  for (int m = 32; m; m >>= 1) s += __shfl_xor(s, m);
  if ((j & 63) == 0) red[j >> 6] = s;
  __syncthreads();
  float tot = red[0] + red[1] + red[2] + red[3];
  float r = rsqrtf(tot * (1.f / 256.f) + 1e-5f);
  o[(size_t)t * 256 + j] = v * r * w[j];
}

// ============== bf16 MFMA GEMM NT: C[m][n] = sum_k A[m][k] * W[n][k] ==========
template <int ACT>
__global__ __launch_bounds__(256) void gemm_bf16(const float* __restrict__ A,
                                                 const float* __restrict__ W,
                                                 float* __restrict__ C,
                                                 int M, int N, int K) {
  __shared__ __align__(16) unsigned short sA[64 * 72];
  __shared__ __align__(16) unsigned short sW[64 * 72];
  const int tid = threadIdx.x;
  const int m0 = blockIdx.x * 64, n0 = blockIdx.y * 64;
  const int srow = tid >> 2, sseg = tid & 3;
  int wrow = n0 + srow; if (wrow >= N) wrow = 0;
  const float* gA = A + (size_t)(m0 + srow) * K + sseg * 16;
  const float* gW = W + (size_t)wrow * K + sseg * 16;
  const int wv = tid >> 6, wm = wv >> 1, wn = wv & 1;
  const int fr = tid & 15;
  const int fq = (tid >> 4) & 3;
  f32x4 acc[2][2] = {};

  const int NT = K >> 6;
  float4 ra[4], rw[4];
#pragma unroll
  for (int q = 0; q < 4; ++q) {
    ra[q] = ((const float4*)gA)[q];
    rw[q] = ((const float4*)gW)[q];
  }
  {
    unsigned short* pa = &sA[srow * 72 + sseg * 16];
    unsigned short* pw = &sW[srow * 72 + sseg * 16];
#pragma unroll
    for (int q = 0; q < 4; ++q) {
      const float* fp = (const float*)&ra[q];
      pa[q * 4 + 0] = f2bf(fp[0]); pa[q * 4 + 1] = f2bf(fp[1]);
      pa[q * 4 + 2] = f2bf(fp[2]); pa[q * 4 + 3] = f2bf(fp[3]);
      const float* gp = (const float*)&rw[q];
      pw[q * 4 + 0] = f2bf(gp[0]); pw[q * 4 + 1] = f2bf(gp[1]);
      pw[q * 4 + 2] = f2bf(gp[2]); pw[q * 4 + 3] = f2bf(gp[3]);
    }
  }
  __syncthreads();

  for (int kt = 0; kt < NT; ++kt) {
    if (kt + 1 < NT) {
#pragma unroll
      for (int q = 0; q < 4; ++q) {
        ra[q] = ((const float4*)(gA + (kt + 1) * 64))[q];
        rw[q] = ((const float4*)(gW + (kt + 1) * 64))[q];
      }
    }
#pragma unroll
    for (int ks = 0; ks < 2; ++ks) {
      bf16x8 a0 = *(const bf16x8*)&sA[(wm * 32 + fr) * 72 + ks * 32 + fq * 8];
      bf16x8 a1 = *(const bf16x8*)&sA[(wm * 32 + 16 + fr) * 72 + ks * 32 + fq * 8];
      bf16x8 b0 = *(const bf16x8*)&sW[(wn * 32 + fr) * 72 + ks * 32 + fq * 8];
      bf16x8 b1 = *(const bf16x8*)&sW[(wn * 32 + 16 + fr) * 72 + ks * 32 + fq * 8];
      acc[0][0] = __builtin_amdgcn_mfma_f32_16x16x32_bf16(a0, b0, acc[0][0], 0, 0, 0);
      acc[0][1] = __builtin_amdgcn_mfma_f32_16x16x32_bf16(a0, b1, acc[0][1], 0, 0, 0);
      acc[1][0] = __builtin_amdgcn_mfma_f32_16x16x32_bf16(a1, b0, acc[1][0], 0, 0, 0);
      acc[1][1] = __builtin_amdgcn_mfma_f32_16x16x32_bf16(a1, b1, acc[1][1], 0, 0, 0);
    }
    __syncthreads();
    if (kt + 1 < NT) {
      unsigned short* pa = &sA[srow * 72 + sseg * 16];
      unsigned short* pw = &sW[srow * 72 + sseg * 16];
#pragma unroll
      for (int q = 0; q < 4; ++q) {
        const float* fp = (const float*)&ra[q];
        pa[q * 4 + 0] = f2bf(fp[0]); pa[q * 4 + 1] = f2bf(fp[1]);
        pa[q * 4 + 2] = f2bf(fp[2]); pa[q * 4 + 3] = f2bf(fp[3]);
        const float* gp = (const float*)&rw[q];
        pw[q * 4 + 0] = f2bf(gp[0]); pw[q * 4 + 1] = f2bf(gp[1]);
        pw[q * 4 + 2] = f2bf(gp[2]); pw[q * 4 + 3] = f2bf(gp[3]);
      }
      __syncthreads();
    }
  }

#pragma unroll
  for (int mr = 0; mr < 2; ++mr) {
#pragma unroll
    for (int nr = 0; nr < 2; ++nr) {
      int n = n0 + wn * 32 + nr * 16 + fr;
      if (n < N) {
#pragma unroll
        for (int j = 0; j < 4; ++j) {
          int m = m0 + wm * 32 + mr * 16 + fq * 4 + j;
          size_t idx = (size_t)m * N + n;
          if (ACT == 2) C[idx] += acc[mr][nr][j];
          else C[idx] = acc[mr][nr][j];
        }
      }
    }
  }
}

// ======================= GEMM NT fp32 (small): C = A*W^T ======================
// ACT: 1 bias+softplus, 3 bias+gelu(tanh)
template <int ACT>
__global__ __launch_bounds__(256) void gemm_nt(const float* __restrict__ A, int lda,
                                               const float* __restrict__ W,
                                               const float* __restrict__ bias,
                                               float* __restrict__ C,
                                               int M, int N, int K) {
  __shared__ __align__(16) float sA[16][68];
  __shared__ __align__(16) float sW[16][68];
  const int m0 = blockIdx.x * 64;
  const int n0 = blockIdx.y * 64;
  const int tid = threadIdx.x;
  const int lk = tid & 15, lm = tid >> 4;
  const int tx = tid & 15, ty = tid >> 4;
  float acc[4][4] = {};

  for (int k0 = 0; k0 < K; k0 += 16) {
#pragma unroll
    for (int p = 0; p < 4; ++p) {
      int m = p * 16 + lm;
      sA[lk][m] = A[(size_t)(m0 + m) * lda + k0 + lk];
    }
#pragma unroll
    for (int p = 0; p < 4; ++p) {
      int n = p * 16 + lm;
      sW[lk][n] = (n0 + n < N) ? W[(size_t)(n0 + n) * K + k0 + lk] : 0.f;
    }
    __syncthreads();
#pragma unroll
    for (int k = 0; k < 16; ++k) {
      float4 a = *(const float4*)&sA[k][ty * 4];
      float4 b = *(const float4*)&sW[k][tx * 4];
      acc[0][0] += a.x * b.x; acc[0][1] += a.x * b.y; acc[0][2] += a.x * b.z; acc[0][3] += a.x * b.w;
      acc[1][0] += a.y * b.x; acc[1][1] += a.y * b.y; acc[1][2] += a.y * b.z; acc[1][3] += a.y * b.w;
      acc[2][0] += a.z * b.x; acc[2][1] += a.z * b.y; acc[2][2] += a.z * b.z; acc[2][3] += a.z * b.w;
      acc[3][0] += a.w * b.x; acc[3][1] += a.w * b.y; acc[3][2] += a.w * b.z; acc[3][3] += a.w * b.w;
    }
    __syncthreads();
  }
#pragma unroll
  for (int i = 0; i < 4; ++i) {
    int m = m0 + ty * 4 + i;
#pragma unroll
    for (int j = 0; j < 4; ++j) {
      int n = n0 + tx * 4 + j;
      if (n < N) {
        float v = acc[i][j];
        if (ACT == 1) {
          v += bias[n];
          v = (v > 20.f) ? v : log1pf(__expf(v));
        } else if (ACT == 3) {
          v += bias[n];
          float t3 = v * v * v;
          v = 0.5f * v * (1.f + tanhf(0.7978845608028654f * (v + 0.044715f * t3)));
        }
        C[(size_t)m * N + n] = v;
      }
    }
  }
}

// ======================= causal depthwise conv1d (k=4) + silu ===================
__global__ __launch_bounds__(256) void conv1d_silu_kernel(const float* __restrict__ xz,
                                                          const float* __restrict__ cw,
                                                          const float* __restrict__ cb,
                                                          float* __restrict__ u) {
  int idx = blockIdx.x * 256 + threadIdx.x;   // over B*T*DI
  int e = idx & (DI - 1);
  int bt = idx >> 9;
  int t = bt & (Tt - 1);
  int b = bt >> 8;
  float s = cb[e];
#pragma unroll
  for (int j = 0; j < 4; ++j) {
    int tt = t - 3 + j;
    if (tt >= 0) s += cw[e * 4 + j] * xz[((size_t)(b * Tt + tt)) * (2 * DI) + e];
  }
  u[idx] = siluf(s);
}

// ======================= selective scan v2 ====================
__global__ __launch_bounds__(256) void scan_kernel(const float* __restrict__ delta,
                                                   const float* __restrict__ u,
                                                   const float* __restrict__ dbc,
                                                   const float* __restrict__ xz,
                                                   const float* __restrict__ A_log,
                                                   const float* __restrict__ Dp,
                                                   float* __restrict__ y) {
  __shared__ float sD[2][64][16];
  __shared__ float sU[2][64][16];
  __shared__ float sB[2][64][16];
  __shared__ float sC[2][64][16];
  __shared__ float sY[64][16];
  const int tid = threadIdx.x;
  const int b = blockIdx.x >> 5;
  const int e0 = (blockIdx.x & 31) << 4;
  const int n = tid & 15;
  const int el = tid >> 4;
  const int e = e0 + el;
  const float An = -__expf(A_log[e * 16 + n]);
  const float Dv = Dp[e];

  const int j = tid & 15;
  const int tr = tid >> 4;
  const size_t baseDU = ((size_t)b * Tt) * DI + e0 + j;
  const size_t baseBC = ((size_t)b * Tt) * 48;
  const size_t baseZ  = ((size_t)b * Tt) * (2 * DI) + DI + e0 + j;

  float rd[4], ru[4], rb[4], rc[4];

#pragma unroll
  for (int r = 0; r < 4; ++r) {
    int t = tr + r * 16;
    rd[r] = delta[baseDU + (size_t)t * DI];
    ru[r] = u[baseDU + (size_t)t * DI];
    rb[r] = dbc[baseBC + (size_t)t * 48 + 16 + j];
    rc[r] = dbc[baseBC + (size_t)t * 48 + 32 + j];
  }
#pragma unroll
  for (int r = 0; r < 4; ++r) {
    int tt = tr + r * 16;
    sD[0][tt][j] = rd[r]; sU[0][tt][j] = ru[r];
    sB[0][tt][j] = rb[r]; sC[0][tt][j] = rc[r];
  }
  __syncthreads();

  float h = 0.f;
  for (int c = 0; c < 4; ++c) {
    if (c < 3) {
#pragma unroll
      for (int r = 0; r < 4; ++r) {
        int t = (c + 1) * 64 + tr + r * 16;
        rd[r] = delta[baseDU + (size_t)t * DI];
        ru[r] = u[baseDU + (size_t)t * DI];
        rb[r] = dbc[baseBC + (size_t)t * 48 + 16 + j];
        rc[r] = dbc[baseBC + (size_t)t * 48 + 32 + j];
      }
    }
    const int cb_ = c & 1;
#pragma unroll 4
    for (int t = 0; t < 64; ++t) {
      float dv = sD[cb_][t][el];
      float uv = sU[cb_][t][el];
      float Bv = sB[cb_][t][n];
      float Cv = sC[cb_][t][n];
      float dA = __expf(dv * An);
      h = dA * h + dv * Bv * uv;
      float p = h * Cv;
      p += __shfl_xor(p, 1);
      p += __shfl_xor(p, 2);
      p += __shfl_xor(p, 4);
      p += __shfl_xor(p, 8);
      if (n == 0) sY[t][el] = p + uv * Dv;
    }
    __syncthreads();
    if (c < 3) {
#pragma unroll
      for (int r = 0; r < 4; ++r) {
        int tt = tr + r * 16;
        int nb = (c + 1) & 1;
        sD[nb][tt][j] = rd[r]; sU[nb][tt][j] = ru[r];
        sB[nb][tt][j] = rb[r]; sC[nb][tt][j] = rc[r];
      }
    }
#pragma unroll
    for (int r = 0; r < 4; ++r) {
      int tt = tr + r * 16;
      int t = c * 64 + tt;
      float zv = xz[baseZ + (size_t)t * (2 * DI)];
      y[baseDU + (size_t)t * DI] = sY[tt][j] * siluf(zv);
    }
    __syncthreads();
  }
}

// ======================= head: logits and softmax ==============================
__global__ __launch_bounds__(256) void logits_kernel(const float* __restrict__ hh,
                                                     const float* __restrict__ w2,
                                                     const float* __restrict__ b2,
                                                     float* __restrict__ logit) {
  int t = blockIdx.x * 256 + threadIdx.x;
  float s = b2[0];
#pragma unroll
  for (int k = 0; k < 64; ++k) s += hh[(size_t)t * 64 + k] * w2[k];
  logit[t] = s;
}

__global__ __launch_bounds__(256) void softmax_kernel(const float* __restrict__ logit,
                                                      float* __restrict__ out) {
  __shared__ float redm[4], reds[4];
  int b = blockIdx.x, t = threadIdx.x;
  float v = logit[b * 256 + t];
  float m = v;
#pragma unroll
  for (int k = 32; k; k >>= 1) m = fmaxf(m, __shfl_xor(m, k));
  if ((t & 63) == 0) redm[t >> 6] = m;
  __syncthreads();
  m = fmaxf(fmaxf(redm[0], redm[1]), fmaxf(redm[2], redm[3]));
  float e = __expf(v - m);
  float s = e;
#pragma unroll
  for (int k = 32; k; k >>= 1) s += __shfl_xor(s, k);
  if ((t & 63) == 0) reds[t >> 6] = s;
  __syncthreads();
  s = reds[0] + reds[1] + reds[2] + reds[3];
  out[b * 256 + t] = (t == 0) ? 0.f : e / s;
}

// ======================= launch ===============================================
extern "C" void kernel_launch(void* const* d_in, const int* in_sizes, int n_in,
                              void* d_out, int out_size, void* d_ws, size_t ws_size,
                              hipStream_t stream) {
  const float* x      = (const float*)d_in[0];
  const float* cnn_w1 = (const float*)d_in[1];
  const float* cnn_b1 = (const float*)d_in[2];
  const float* cnn_w2 = (const float*)d_in[3];
  const float* cnn_b2 = (const float*)d_in[4];
  const float* cnn_w3 = (const float*)d_in[5];
  const float* cnn_b3 = (const float*)d_in[6];
  const float* fc_w   = (const float*)d_in[7];
  const float* fc_b   = (const float*)d_in[8];
  const float* norm_w = (const float*)d_in[9];
  const float* ipw    = (const float*)d_in[10];
  const float* cw     = (const float*)d_in[11];
  const float* cb     = (const float*)d_in[12];
  const float* xpw    = (const float*)d_in[13];
  const float* dpw    = (const float*)d_in[14];
  const float* dpb    = (const float*)d_in[15];
  const float* A_log  = (const float*)d_in[16];
  const float* Dp     = (const float*)d_in[17];
  const float* opw    = (const float*)d_in[18];
  const float* nfw    = (const float*)d_in[19];
  const float* hw1    = (const float*)d_in[20];
  const float* hb1    = (const float*)d_in[21];
  const float* hw2    = (const float*)d_in[22];
  const float* hb2    = (const float*)d_in[23];

  float* ws    = (float*)d_ws;
  float* h     = ws + OFF_H;
  float* xn    = ws + OFF_XN;
  float* xz    = ws + OFF_XZ;
  float* u     = ws + OFF_U;
  float* dbc   = ws + OFF_DBC;
  float* delta = ws + OFF_DELTA;
  float* yb    = ws + OFF_Y;
  float* hh    = ws + OFF_HH;
  float* logit = ws + OFF_LOGIT;

  cnn_fc_mfma<<<Bb * Tt, 256, 0, stream>>>(x, cnn_w1, cnn_b1, cnn_w2, cnn_b2,
                                           cnn_w3, cnn_b3, fc_w, fc_b, h);

  for (int l = 0; l < NL; ++l) {
    rmsnorm_kernel<<<Bb * Tt, 256, 0, stream>>>(h, norm_w + l * DM, xn);
    {
      dim3 g(32, 16);   // M=2048, N=1024, K=256
      gemm_bf16<0><<<g, 256, 0, stream>>>(xn, ipw + (size_t)l * 2 * DI * DM, xz,
                                          Bb * Tt, 2 * DI, DM);
    }
    conv1d_silu_kernel<<<(Bb * Tt * DI) / 256, 256, 0, stream>>>(
        xz, cw + l * DI * 4, cb + l * DI, u);
    {
      dim3 g(32, 1);    // M=2048, N=48, K=512
      gemm_bf16<0><<<g, 256, 0, stream>>>(u, xpw + (size_t)l * 48 * DI, dbc,
                                          Bb * Tt, 48, DI);
    }
    {
      dim3 g(32, 8);    // delta: K=16, stays fp32 vector
      gemm_nt<1><<<g, 256, 0, stream>>>(dbc, 48, dpw + (size_t)l * DI * DTR,
                                        dpb + l * DI, delta, Bb * Tt, DI, DTR);
    }
    scan_kernel<<<Bb * 32, 256, 0, stream>>>(
        delta, u, dbc, xz, A_log + (size_t)l * DI * DS, Dp + l * DI, yb);
    {
      dim3 g(32, 4);    // M=2048, N=256, K=512, accumulate into h
      gemm_bf16<2><<<g, 256, 0, stream>>>(yb, opw + (size_t)l * DM * DI, h,
                                          Bb * Tt, DM, DI);
    }
  }

  rmsnorm_kernel<<<Bb * Tt, 256, 0, stream>>>(h, nfw, xn);
  {
    dim3 g(32, 1);
    gemm_nt<3><<<g, 256, 0, stream>>>(xn, DM, hw1, hb1, hh, Bb * Tt, 64, DM);
  }
  logits_kernel<<<Bb * Tt / 256, 256, 0, stream>>>(hh, hw2, hb2, logit);
  softmax_kernel<<<Bb, 256, 0, stream>>>(logit, (float*)d_out);
}

// Round 5
// 639.575 us; speedup vs baseline: 4.0212x; 1.3431x over previous
//
#include <hip/hip_runtime.h>
#include <hip/hip_bf16.h>
#include <math.h>

// Problem dims
#define Bb 8
#define Tt 256
#define DM 256       // d_model
#define DI 512       // d_inner
#define NL 6
#define DS 16        // d_state
#define DTR 16       // dt_rank

// ---------------- workspace layout (float units) ----------------
#define OFF_H     0u          // f32 [2048][256]
#define OFF_XZ    524288u     // f32 [2048][1024]
#define OFF_U     2621440u    // f32 [2048][512]
#define OFF_DBC   3670016u    // f32 [2048][48]
#define OFF_DELTA 3768320u    // f32 [2048][512]
#define OFF_HH    4816896u    // f32 [2048][64]
#define OFF_LOGIT 4947968u    // f32 [2048]
#define OFF_XNB   4950016u    // bf16 [2048][256]   (262144 floats)
#define OFF_UB    5212160u    // bf16 [2048][512]   (524288 floats)
#define OFF_YBF   5736448u    // bf16 [2048][512]   (524288 floats)
#define OFF_WIP   6260736u    // bf16 ipw 6*1024*256 (786432 floats)
#define OFF_WXP   7047168u    // bf16 xpw 6*48*512   (73728 floats)
#define OFF_WOP   7120896u    // bf16 opw 6*256*512  (393216 floats)
// total 7514112 floats = 30.1 MB

__device__ __forceinline__ float siluf(float x) { return x / (1.f + __expf(-x)); }

typedef __attribute__((ext_vector_type(8))) short bf16x8;
typedef __attribute__((ext_vector_type(4))) short bf16x4;
typedef __attribute__((ext_vector_type(4))) float f32x4;
typedef __attribute__((ext_vector_type(4))) unsigned int u32x4;

__device__ __forceinline__ unsigned short f2bf(float x) {
  unsigned u = __float_as_uint(x);
  u += 0x7FFFu + ((u >> 16) & 1u);   // RNE
  return (unsigned short)(u >> 16);
}
__device__ __forceinline__ float bf2f(unsigned short u) {
  return __uint_as_float((unsigned)u << 16);
}
__device__ __forceinline__ float ldf(const float* p) { return *p; }
__device__ __forceinline__ float ldf(const unsigned short* p) { return bf2f(*p); }

// ======================= fp32 -> bf16 convert (weights) =======================
__global__ __launch_bounds__(256) void cvt_bf16_kernel(const float* __restrict__ src,
                                                       unsigned short* __restrict__ dst,
                                                       int nvec) {
  int i = blockIdx.x * 256 + threadIdx.x;
  if (i < nvec) {
    float4 v = ((const float4*)src)[i];
    bf16x4 o;
    o[0] = (short)f2bf(v.x); o[1] = (short)f2bf(v.y);
    o[2] = (short)f2bf(v.z); o[3] = (short)f2bf(v.w);
    ((bf16x4*)dst)[i] = o;
  }
}

// ================== CNN (implicit-GEMM MFMA) + fc, one block per frame =========
__global__ __launch_bounds__(256) void cnn_fc_mfma(
    const float* __restrict__ x,
    const float* __restrict__ w1, const float* __restrict__ b1,
    const float* __restrict__ w2, const float* __restrict__ b2,
    const float* __restrict__ w3, const float* __restrict__ b3,
    const float* __restrict__ fcw, const float* __restrict__ fcb,
    float* __restrict__ hout) {
  __shared__ __align__(16) unsigned short ldsu[31024];
  __shared__ float s_pool[32];
  const int tid = threadIdx.x;
  const int f = blockIdx.x;
  const int lane = tid & 63;
  const int lc = lane & 15;
  const int fq = lane >> 4;
  const int wv = tid >> 6;

  const int FR = 0;
  const int W2 = 0;
  const int C1 = 6400;
  const int C2 = 22800;
  const int W3 = 0;

  // ---- P1: frame -> bf16 LDS; zero rows; zero pool
  {
    const float* xin = x + (size_t)f * 4096;
#pragma unroll
    for (int r = 0; r < 4; ++r) {
      float4 v = ((const float4*)xin)[r * 256 + tid];
      bf16x4 o;
      o[0] = (short)f2bf(v.x); o[1] = (short)f2bf(v.y);
      o[2] = (short)f2bf(v.z); o[3] = (short)f2bf(v.w);
      *(bf16x4*)&ldsu[FR + (r * 256 + tid) * 4] = o;
    }
    if (tid < 8)  ((unsigned*)&ldsu[C1 + 1024 * 16])[tid] = 0u;
    if (tid < 16) ((unsigned*)&ldsu[C2 + 256 * 32])[tid] = 0u;
    if (tid < 32) s_pool[tid] = 0.f;
  }
  __syncthreads();

  // ---- P2: conv1 (VALU)
#pragma unroll
  for (int r = 0; r < 4; ++r) {
    int p = r * 256 + tid;
    int oy = p >> 5, ox = p & 31;
    float in9[9];
#pragma unroll
    for (int ky = 0; ky < 3; ++ky) {
      int iy = 2 * oy + ky;
#pragma unroll
      for (int kx = 0; kx < 3; ++kx) {
        int ix = 2 * ox + kx;
        in9[ky * 3 + kx] = (iy < 64 && ix < 64) ? bf2f(ldsu[FR + iy * 64 + ix]) : 0.f;
      }
    }
    bf16x8 o0, o1;
#pragma unroll
    for (int oc = 0; oc < 8; ++oc) {
      float s = b1[oc];
#pragma unroll
      for (int k = 0; k < 9; ++k) s += w1[oc * 9 + k] * in9[k];
      o0[oc] = (short)f2bf(fmaxf(s, 0.f));
    }
#pragma unroll
    for (int oc = 0; oc < 8; ++oc) {
      float s = b1[8 + oc];
#pragma unroll
      for (int k = 0; k < 9; ++k) s += w1[(8 + oc) * 9 + k] * in9[k];
      o1[oc] = (short)f2bf(fmaxf(s, 0.f));
    }
    *(bf16x8*)&ldsu[C1 + p * 16] = o0;
    *(bf16x8*)&ldsu[C1 + p * 16 + 8] = o1;
  }
  __syncthreads();

  // ---- P3: stage w2t
  for (int r = 0; r < 20; ++r) {
    int i = r * 256 + tid;
    int kt = i >> 10, rem = i & 1023;
    int oc = rem >> 5, k = rem & 31;
    int tap = 2 * kt + (k >> 4), ic = k & 15;
    float v = (tap < 9) ? w2[oc * 144 + ic * 9 + tap] : 0.f;
    ldsu[W2 + (kt * 32 + oc) * 40 + k] = f2bf(v);
  }
  __syncthreads();

  // ---- P4: conv2 MFMA
  {
    f32x4 acc[2][4] = {};
    for (int kt = 0; kt < 5; ++kt) {
      bf16x8 a0 = *(const bf16x8*)&ldsu[W2 + (kt * 32 + lc) * 40 + fq * 8];
      bf16x8 a1 = *(const bf16x8*)&ldsu[W2 + (kt * 32 + 16 + lc) * 40 + fq * 8];
      int tap = 2 * kt + (fq >> 1);
      int t9 = (tap < 9) ? tap : 0;
      int ky = (t9 * 11) >> 5;
      int kx = t9 - ky * 3;
      int ix = 2 * lc + kx;
#pragma unroll
      for (int ni = 0; ni < 4; ++ni) {
        int nt = wv * 4 + ni;
        int iy = 2 * nt + ky;
        int ipos = (tap < 9 && iy < 32 && ix < 32) ? iy * 32 + ix : 1024;
        bf16x8 b = *(const bf16x8*)&ldsu[C1 + ipos * 16 + (fq & 1) * 8];
        acc[0][ni] = __builtin_amdgcn_mfma_f32_16x16x32_bf16(a0, b, acc[0][ni], 0, 0, 0);
        acc[1][ni] = __builtin_amdgcn_mfma_f32_16x16x32_bf16(a1, b, acc[1][ni], 0, 0, 0);
      }
    }
#pragma unroll
    for (int mi = 0; mi < 2; ++mi) {
      int oc0 = mi * 16 + fq * 4;
#pragma unroll
      for (int ni = 0; ni < 4; ++ni) {
        int pos = (wv * 4 + ni) * 16 + lc;
        bf16x4 o;
#pragma unroll
        for (int j = 0; j < 4; ++j)
          o[j] = (short)f2bf(fmaxf(acc[mi][ni][j] + b2[oc0 + j], 0.f));
        int g = mi * 4 + fq;
        int gp = ((((g >> 1) ^ ((pos >> 1) & 3)) << 1) | (g & 1));
        *(bf16x4*)&ldsu[C2 + pos * 32 + gp * 4] = o;
      }
    }
  }
  __syncthreads();

  // ---- P5: stage w3t
  for (int r = 0; r < 36; ++r) {
    int i = r * 256 + tid;
    int tap = i >> 10, rem = i & 1023;
    int oc = rem >> 5, ic = rem & 31;
    ldsu[W3 + (tap * 32 + oc) * 40 + ic] = f2bf(w3[oc * 288 + ic * 9 + tap]);
  }
  __syncthreads();

  // ---- P6: conv3 MFMA + pool
  {
    const int mh = wv >> 1, nb = wv & 1;
    f32x4 acc[2] = {};
#pragma unroll
    for (int tap = 0; tap < 9; ++tap) {
      const int ky = tap / 3, kx = tap % 3;
      bf16x8 a = *(const bf16x8*)&ldsu[W3 + (tap * 32 + mh * 16 + lc) * 40 + fq * 8];
#pragma unroll
      for (int ni = 0; ni < 2; ++ni) {
        int pos = (nb * 2 + ni) * 16 + lc;
        int py = pos >> 3, px = pos & 7;
        int iy = 2 * py + ky, ix = 2 * px + kx;
        int ipos = (iy < 16 && ix < 16) ? iy * 16 + ix : 256;
        int sp = fq ^ ((ipos >> 1) & 3);
        bf16x8 b = *(const bf16x8*)&ldsu[C2 + ipos * 32 + sp * 8];
        acc[ni] = __builtin_amdgcn_mfma_f32_16x16x32_bf16(a, b, acc[ni], 0, 0, 0);
      }
    }
    int oc0 = mh * 16 + fq * 4;
#pragma unroll
    for (int j = 0; j < 4; ++j) {
      float v = fmaxf(acc[0][j] + b3[oc0 + j], 0.f) +
                fmaxf(acc[1][j] + b3[oc0 + j], 0.f);
      v += __shfl_xor(v, 1);
      v += __shfl_xor(v, 2);
      v += __shfl_xor(v, 4);
      v += __shfl_xor(v, 8);
      if (lc == 0) atomicAdd(&s_pool[oc0 + j], v);
    }
  }
  __syncthreads();

  // ---- P7: fc 32 -> 256
  {
    float dot = 0.f;
#pragma unroll
    for (int k = 0; k < 32; ++k) dot += fcw[tid * 32 + k] * s_pool[k];
    hout[(size_t)f * 256 + tid] = fcb[tid] + dot * (1.f / 64.f);
  }
}

// ======================= RMSNorm -> bf16 =======================
__global__ __launch_bounds__(256) void rmsnorm_kernel(const float* __restrict__ x,
                                                      const float* __restrict__ w,
                                                      unsigned short* __restrict__ ob) {
  __shared__ float red[4];
  int t = blockIdx.x, j = threadIdx.x;
  float v = x[(size_t)t * 256 + j];
  float s = v * v;
#pragma unroll
  for (int m = 32; m; m >>= 1) s += __shfl_xor(s, m);
  if ((j & 63) == 0) red[j >> 6] = s;
  __syncthreads();
  float tot = red[0] + red[1] + red[2] + red[3];
  float r = rsqrtf(tot * (1.f / 256.f) + 1e-5f);
  ob[(size_t)t * 256 + j] = f2bf(v * r * w[j]);
}

// ============== bf16 MFMA GEMM NT (bf16 A, bf16 W, f32 C) =====================
// ACT: 0 write, 2 accumulate into C
template <int ACT>
__global__ __launch_bounds__(256) void gemm_bb(const unsigned short* __restrict__ A,
                                               const unsigned short* __restrict__ W,
                                               float* __restrict__ C,
                                               int M, int N, int K) {
  __shared__ __align__(16) unsigned short sA[64 * 72];
  __shared__ __align__(16) unsigned short sW[64 * 72];
  const int tid = threadIdx.x;
  const int m0 = blockIdx.x * 64, n0 = blockIdx.y * 64;
  const int srow = tid >> 2, sseg = tid & 3;
  int wrow = n0 + srow; if (wrow >= N) wrow = 0;
  const unsigned short* gA = A + (size_t)(m0 + srow) * K + sseg * 16;
  const unsigned short* gW = W + (size_t)wrow * K + sseg * 16;
  const int wv = tid >> 6, wm = wv >> 1, wn = wv & 1;
  const int fr = tid & 15;
  const int fq = (tid >> 4) & 3;
  f32x4 acc[2][2] = {};

  const int NT = K >> 6;
  u32x4 ra0, ra1, rw0, rw1;
  ra0 = ((const u32x4*)gA)[0]; ra1 = ((const u32x4*)gA)[1];
  rw0 = ((const u32x4*)gW)[0]; rw1 = ((const u32x4*)gW)[1];
  *(u32x4*)&sA[srow * 72 + sseg * 16] = ra0;
  *(u32x4*)&sA[srow * 72 + sseg * 16 + 8] = ra1;
  *(u32x4*)&sW[srow * 72 + sseg * 16] = rw0;
  *(u32x4*)&sW[srow * 72 + sseg * 16 + 8] = rw1;
  __syncthreads();

  for (int kt = 0; kt < NT; ++kt) {
    if (kt + 1 < NT) {
      ra0 = ((const u32x4*)(gA + (kt + 1) * 64))[0];
      ra1 = ((const u32x4*)(gA + (kt + 1) * 64))[1];
      rw0 = ((const u32x4*)(gW + (kt + 1) * 64))[0];
      rw1 = ((const u32x4*)(gW + (kt + 1) * 64))[1];
    }
#pragma unroll
    for (int ks = 0; ks < 2; ++ks) {
      bf16x8 a0 = *(const bf16x8*)&sA[(wm * 32 + fr) * 72 + ks * 32 + fq * 8];
      bf16x8 a1 = *(const bf16x8*)&sA[(wm * 32 + 16 + fr) * 72 + ks * 32 + fq * 8];
      bf16x8 b0 = *(const bf16x8*)&sW[(wn * 32 + fr) * 72 + ks * 32 + fq * 8];
      bf16x8 b1 = *(const bf16x8*)&sW[(wn * 32 + 16 + fr) * 72 + ks * 32 + fq * 8];
      acc[0][0] = __builtin_amdgcn_mfma_f32_16x16x32_bf16(a0, b0, acc[0][0], 0, 0, 0);
      acc[0][1] = __builtin_amdgcn_mfma_f32_16x16x32_bf16(a0, b1, acc[0][1], 0, 0, 0);
      acc[1][0] = __builtin_amdgcn_mfma_f32_16x16x32_bf16(a1, b0, acc[1][0], 0, 0, 0);
      acc[1][1] = __builtin_amdgcn_mfma_f32_16x16x32_bf16(a1, b1, acc[1][1], 0, 0, 0);
    }
    __syncthreads();
    if (kt + 1 < NT) {
      *(u32x4*)&sA[srow * 72 + sseg * 16] = ra0;
      *(u32x4*)&sA[srow * 72 + sseg * 16 + 8] = ra1;
      *(u32x4*)&sW[srow * 72 + sseg * 16] = rw0;
      *(u32x4*)&sW[srow * 72 + sseg * 16 + 8] = rw1;
      __syncthreads();
    }
  }

#pragma unroll
  for (int mr = 0; mr < 2; ++mr) {
#pragma unroll
    for (int nr = 0; nr < 2; ++nr) {
      int n = n0 + wn * 32 + nr * 16 + fr;
      if (n < N) {
#pragma unroll
        for (int j = 0; j < 4; ++j) {
          int m = m0 + wm * 32 + mr * 16 + fq * 4 + j;
          size_t idx = (size_t)m * N + n;
          if (ACT == 2) C[idx] += acc[mr][nr][j];
          else C[idx] = acc[mr][nr][j];
        }
      }
    }
  }
}

// ======================= GEMM NT fp32 vector (small K) ========================
// ACT: 1 bias+softplus, 3 bias+gelu(tanh); AT = float or bf16(ushort)
template <int ACT, typename AT>
__global__ __launch_bounds__(256) void gemm_nt(const AT* __restrict__ A, int lda,
                                               const float* __restrict__ W,
                                               const float* __restrict__ bias,
                                               float* __restrict__ C,
                                               int M, int N, int K) {
  __shared__ __align__(16) float sA[16][68];
  __shared__ __align__(16) float sW[16][68];
  const int m0 = blockIdx.x * 64;
  const int n0 = blockIdx.y * 64;
  const int tid = threadIdx.x;
  const int lk = tid & 15, lm = tid >> 4;
  const int tx = tid & 15, ty = tid >> 4;
  float acc[4][4] = {};

  for (int k0 = 0; k0 < K; k0 += 16) {
#pragma unroll
    for (int p = 0; p < 4; ++p) {
      int m = p * 16 + lm;
      sA[lk][m] = ldf(&A[(size_t)(m0 + m) * lda + k0 + lk]);
    }
#pragma unroll
    for (int p = 0; p < 4; ++p) {
      int n = p * 16 + lm;
      sW[lk][n] = (n0 + n < N) ? W[(size_t)(n0 + n) * K + k0 + lk] : 0.f;
    }
    __syncthreads();
#pragma unroll
    for (int k = 0; k < 16; ++k) {
      float4 a = *(const float4*)&sA[k][ty * 4];
      float4 b = *(const float4*)&sW[k][tx * 4];
      acc[0][0] += a.x * b.x; acc[0][1] += a.x * b.y; acc[0][2] += a.x * b.z; acc[0][3] += a.x * b.w;
      acc[1][0] += a.y * b.x; acc[1][1] += a.y * b.y; acc[1][2] += a.y * b.z; acc[1][3] += a.y * b.w;
      acc[2][0] += a.z * b.x; acc[2][1] += a.z * b.y; acc[2][2] += a.z * b.z; acc[2][3] += a.z * b.w;
      acc[3][0] += a.w * b.x; acc[3][1] += a.w * b.y; acc[3][2] += a.w * b.z; acc[3][3] += a.w * b.w;
    }
    __syncthreads();
  }
#pragma unroll
  for (int i = 0; i < 4; ++i) {
    int m = m0 + ty * 4 + i;
#pragma unroll
    for (int j = 0; j < 4; ++j) {
      int n = n0 + tx * 4 + j;
      if (n < N) {
        float v = acc[i][j];
        if (ACT == 1) {
          v += bias[n];
          v = (v > 20.f) ? v : log1pf(__expf(v));
        } else if (ACT == 3) {
          v += bias[n];
          float t3 = v * v * v;
          v = 0.5f * v * (1.f + tanhf(0.7978845608028654f * (v + 0.044715f * t3)));
        }
        C[(size_t)m * N + n] = v;
      }
    }
  }
}

// ======================= causal depthwise conv1d (k=4) + silu ===================
__global__ __launch_bounds__(256) void conv1d_silu_kernel(const float* __restrict__ xz,
                                                          const float* __restrict__ cw,
                                                          const float* __restrict__ cb,
                                                          float* __restrict__ u,
                                                          unsigned short* __restrict__ ub) {
  int idx = blockIdx.x * 256 + threadIdx.x;
  int e = idx & (DI - 1);
  int bt = idx >> 9;
  int t = bt & (Tt - 1);
  int b = bt >> 8;
  float s = cb[e];
#pragma unroll
  for (int j = 0; j < 4; ++j) {
    int tt = t - 3 + j;
    if (tt >= 0) s += cw[e * 4 + j] * xz[((size_t)(b * Tt + tt)) * (2 * DI) + e];
  }
  float v = siluf(s);
  u[idx] = v;
  ub[idx] = f2bf(v);
}

// ======================= selective scan v3: chunk-parallel two-pass ============
// Block = 1024 threads = (chunk 0..3) x (el 0..15) x (n 0..15); 256 blocks.
// LDS: full (b, 16-e tile) slab; pass1 local scans, serial combine, pass2 + y.
__global__ __launch_bounds__(1024) void scan_kernel(const float* __restrict__ delta,
                                                    const float* __restrict__ u,
                                                    const float* __restrict__ dbc,
                                                    const float* __restrict__ xz,
                                                    const float* __restrict__ A_log,
                                                    const float* __restrict__ Dp,
                                                    unsigned short* __restrict__ ybf) {
  __shared__ float sD[256][16];
  __shared__ float sU[256][16];
  __shared__ float sB[256][16];
  __shared__ float sC[256][16];
  __shared__ float sY[256][16];   // rows 0-63: hloc, 64-127: aprod, 128-191: startH (pass1)
  const int tid = threadIdx.x;
  const int b = blockIdx.x >> 5;
  const int e0 = (blockIdx.x & 31) << 4;
  const int chunk = tid >> 8;
  const int el = (tid >> 4) & 15;
  const int n = tid & 15;
  const int e = e0 + el;
  const float An = -__expf(A_log[e * 16 + n]);
  const float Dv = Dp[e];
  const size_t rowbase = (size_t)b * Tt;

  // staging (coalesced, 16-float segments)
#pragma unroll
  for (int k = 0; k < 4; ++k) {
    int idx = k * 1024 + tid;
    int row = idx >> 4, col = idx & 15;
    size_t g = (rowbase + row) * DI + e0 + col;
    size_t gb = (rowbase + row) * 48;
    sD[row][col] = delta[g];
    sU[row][col] = u[g];
    sB[row][col] = dbc[gb + 16 + col];
    sC[row][col] = dbc[gb + 32 + col];
  }
  __syncthreads();

  // pass 1: local scan of own 64-step chunk (h0 = 0), track prod(dA)
  float h = 0.f, ap = 1.f;
  const int t0 = chunk * 64;
#pragma unroll 4
  for (int t = t0; t < t0 + 64; ++t) {
    float dv = sD[t][el];
    float dA = __expf(dv * An);
    h = dA * h + dv * sB[t][n] * sU[t][el];
    ap *= dA;
  }
  float* hloc   = &sY[0][0];
  float* aprod  = &sY[64][0];
  float* startH = &sY[128][0];
  const int sidx = el * 16 + n;
  hloc[chunk * 256 + sidx] = h;
  aprod[chunk * 256 + sidx] = ap;
  __syncthreads();

  // serial combine (chunk-0 threads): startH[c] = state entering chunk c
  if (chunk == 0) {
    float H = 0.f;
    startH[sidx] = 0.f;
#pragma unroll
    for (int c = 0; c < 3; ++c) {
      H = aprod[c * 256 + sidx] * H + hloc[c * 256 + sidx];
      startH[(c + 1) * 256 + sidx] = H;
    }
  }
  __syncthreads();
  float h2 = startH[chunk * 256 + sidx];
  __syncthreads();   // all reads done before sY reuse below

  // pass 2: corrected scan + y
#pragma unroll 4
  for (int t = t0; t < t0 + 64; ++t) {
    float dv = sD[t][el];
    float uv = sU[t][el];
    float dA = __expf(dv * An);
    h2 = dA * h2 + dv * sB[t][n] * uv;
    float p = h2 * sC[t][n];
    p += __shfl_xor(p, 1);
    p += __shfl_xor(p, 2);
    p += __shfl_xor(p, 4);
    p += __shfl_xor(p, 8);
    if (n == 0) sY[t][el] = p + uv * Dv;
  }
  __syncthreads();

  // gated bf16 writeout
#pragma unroll
  for (int k = 0; k < 4; ++k) {
    int idx = k * 1024 + tid;
    int t = idx >> 4, col = idx & 15;
    float zv = xz[(rowbase + t) * (2 * DI) + DI + e0 + col];
    ybf[(rowbase + t) * DI + e0 + col] = f2bf(sY[t][col] * siluf(zv));
  }
}

// ======================= head: logits and softmax ==============================
__global__ __launch_bounds__(256) void logits_kernel(const float* __restrict__ hh,
                                                     const float* __restrict__ w2,
                                                     const float* __restrict__ b2,
                                                     float* __restrict__ logit) {
  int t = blockIdx.x * 256 + threadIdx.x;
  float s = b2[0];
#pragma unroll
  for (int k = 0; k < 64; ++k) s += hh[(size_t)t * 64 + k] * w2[k];
  logit[t] = s;
}

__global__ __launch_bounds__(256) void softmax_kernel(const float* __restrict__ logit,
                                                      float* __restrict__ out) {
  __shared__ float redm[4], reds[4];
  int b = blockIdx.x, t = threadIdx.x;
  float v = logit[b * 256 + t];
  float m = v;
#pragma unroll
  for (int k = 32; k; k >>= 1) m = fmaxf(m, __shfl_xor(m, k));
  if ((t & 63) == 0) redm[t >> 6] = m;
  __syncthreads();
  m = fmaxf(fmaxf(redm[0], redm[1]), fmaxf(redm[2], redm[3]));
  float e = __expf(v - m);
  float s = e;
#pragma unroll
  for (int k = 32; k; k >>= 1) s += __shfl_xor(s, k);
  if ((t & 63) == 0) reds[t >> 6] = s;
  __syncthreads();
  s = reds[0] + reds[1] + reds[2] + reds[3];
  out[b * 256 + t] = (t == 0) ? 0.f : e / s;
}

// ======================= launch ===============================================
extern "C" void kernel_launch(void* const* d_in, const int* in_sizes, int n_in,
                              void* d_out, int out_size, void* d_ws, size_t ws_size,
                              hipStream_t stream) {
  const float* x      = (const float*)d_in[0];
  const float* cnn_w1 = (const float*)d_in[1];
  const float* cnn_b1 = (const float*)d_in[2];
  const float* cnn_w2 = (const float*)d_in[3];
  const float* cnn_b2 = (const float*)d_in[4];
  const float* cnn_w3 = (const float*)d_in[5];
  const float* cnn_b3 = (const float*)d_in[6];
  const float* fc_w   = (const float*)d_in[7];
  const float* fc_b   = (const float*)d_in[8];
  const float* norm_w = (const float*)d_in[9];
  const float* ipw    = (const float*)d_in[10];
  const float* cw     = (const float*)d_in[11];
  const float* cb     = (const float*)d_in[12];
  const float* xpw    = (const float*)d_in[13];
  const float* dpw    = (const float*)d_in[14];
  const float* dpb    = (const float*)d_in[15];
  const float* A_log  = (const float*)d_in[16];
  const float* Dp     = (const float*)d_in[17];
  const float* opw    = (const float*)d_in[18];
  const float* nfw    = (const float*)d_in[19];
  const float* hw1    = (const float*)d_in[20];
  const float* hb1    = (const float*)d_in[21];
  const float* hw2    = (const float*)d_in[22];
  const float* hb2    = (const float*)d_in[23];

  float* ws    = (float*)d_ws;
  float* h     = ws + OFF_H;
  float* xz    = ws + OFF_XZ;
  float* u     = ws + OFF_U;
  float* dbc   = ws + OFF_DBC;
  float* delta = ws + OFF_DELTA;
  float* hh    = ws + OFF_HH;
  float* logit = ws + OFF_LOGIT;
  unsigned short* xnb = (unsigned short*)(ws + OFF_XNB);
  unsigned short* ub  = (unsigned short*)(ws + OFF_UB);
  unsigned short* ybf = (unsigned short*)(ws + OFF_YBF);
  unsigned short* wip = (unsigned short*)(ws + OFF_WIP);
  unsigned short* wxp = (unsigned short*)(ws + OFF_WXP);
  unsigned short* wop = (unsigned short*)(ws + OFF_WOP);

  // weight conversions (re-done every launch; ws is re-poisoned by harness)
  cvt_bf16_kernel<<<1536, 256, 0, stream>>>(ipw, wip, NL * 2 * DI * DM / 4);
  cvt_bf16_kernel<<<144, 256, 0, stream>>>(xpw, wxp, NL * 48 * DI / 4);
  cvt_bf16_kernel<<<768, 256, 0, stream>>>(opw, wop, NL * DM * DI / 4);

  cnn_fc_mfma<<<Bb * Tt, 256, 0, stream>>>(x, cnn_w1, cnn_b1, cnn_w2, cnn_b2,
                                           cnn_w3, cnn_b3, fc_w, fc_b, h);

  for (int l = 0; l < NL; ++l) {
    rmsnorm_kernel<<<Bb * Tt, 256, 0, stream>>>(h, norm_w + l * DM, xnb);
    {
      dim3 g(32, 16);   // M=2048, N=1024, K=256
      gemm_bb<0><<<g, 256, 0, stream>>>(xnb, wip + (size_t)l * 2 * DI * DM, xz,
                                        Bb * Tt, 2 * DI, DM);
    }
    conv1d_silu_kernel<<<(Bb * Tt * DI) / 256, 256, 0, stream>>>(
        xz, cw + l * DI * 4, cb + l * DI, u, ub);
    {
      dim3 g(32, 1);    // M=2048, N=48, K=512
      gemm_bb<0><<<g, 256, 0, stream>>>(ub, wxp + (size_t)l * 48 * DI, dbc,
                                        Bb * Tt, 48, DI);
    }
    {
      dim3 g(32, 8);    // delta: K=16, fp32 vector
      gemm_nt<1, float><<<g, 256, 0, stream>>>(dbc, 48, dpw + (size_t)l * DI * DTR,
                                               dpb + l * DI, delta, Bb * Tt, DI, DTR);
    }
    scan_kernel<<<Bb * 32, 1024, 0, stream>>>(
        delta, u, dbc, xz, A_log + (size_t)l * DI * DS, Dp + l * DI, ybf);
    {
      dim3 g(32, 4);    // M=2048, N=256, K=512, accumulate into h
      gemm_bb<2><<<g, 256, 0, stream>>>(ybf, wop + (size_t)l * DM * DI, h,
                                        Bb * Tt, DM, DI);
    }
  }

  rmsnorm_kernel<<<Bb * Tt, 256, 0, stream>>>(h, nfw, xnb);
  {
    dim3 g(32, 1);
    gemm_nt<3, unsigned short><<<g, 256, 0, stream>>>(xnb, DM, hw1, hb1, hh,
                                                      Bb * Tt, 64, DM);
  }
  logits_kernel<<<Bb * Tt / 256, 256, 0, stream>>>(hh, hw2, hb2, logit);
  softmax_kernel<<<Bb, 256, 0, stream>>>(logit, (float*)d_out);
}

// Round 8
// 589.227 us; speedup vs baseline: 4.3648x; 1.0854x over previous
//
#include <hip/hip_runtime.h>
#include <hip/hip_bf16.h>
#include <math.h>

// Problem dims
#define Bb 8
#define Tt 256
#define DM 256       // d_model
#define DI 512       // d_inner
#define NL 6
#define DS 16        // d_state
#define DTR 16       // dt_rank

// ---------------- workspace layout (float units) ----------------
#define OFF_H     0u          // f32 [2048][256]
#define OFF_XZ    524288u     // f32 [2048][1024]
#define OFF_DBCP  2621440u    // f32 [4][2048][48] split-K partials
#define OFF_HH    3014656u    // f32 [2048][64]
#define OFF_LOGIT 3145728u    // f32 [2048]
#define OFF_XNB   3147776u    // bf16 [2048][256]
#define OFF_UB    3278848u    // bf16 [2048][512]
#define OFF_YBF   3540992u    // bf16 [2048][512]
#define OFF_WIP   3803136u    // bf16 ipw 6*1024*256
#define OFF_WXP   4589568u    // bf16 xpw 6*48*512
#define OFF_WOP   4663296u    // bf16 opw 6*256*512
// total 5056512 floats = 20.2 MB

__device__ __forceinline__ float siluf(float x) { return x / (1.f + __expf(-x)); }

typedef __attribute__((ext_vector_type(8))) short bf16x8;
typedef __attribute__((ext_vector_type(4))) short bf16x4;
typedef __attribute__((ext_vector_type(4))) float f32x4;
typedef __attribute__((ext_vector_type(4))) unsigned int u32x4;

__device__ __forceinline__ unsigned short f2bf(float x) {
  unsigned u = __float_as_uint(x);
  u += 0x7FFFu + ((u >> 16) & 1u);   // RNE
  return (unsigned short)(u >> 16);
}
__device__ __forceinline__ float bf2f(unsigned short u) {
  return __uint_as_float((unsigned)u << 16);
}
__device__ __forceinline__ float ldf(const float* p) { return *p; }
__device__ __forceinline__ float ldf(const unsigned short* p) { return bf2f(*p); }

// ======================= fp32 -> bf16 convert (all 3 weight sets) =============
__global__ __launch_bounds__(256) void cvt_all_kernel(
    const float* __restrict__ s0, unsigned short* __restrict__ d0, int n0,
    const float* __restrict__ s1, unsigned short* __restrict__ d1, int n1,
    const float* __restrict__ s2, unsigned short* __restrict__ d2, int n2) {
  int i = blockIdx.x * 256 + threadIdx.x;
  const float* s; unsigned short* d; int j = i;
  if (j < n0) { s = s0; d = d0; }
  else { j -= n0; if (j < n1) { s = s1; d = d1; }
         else { j -= n1; if (j >= n2) return; s = s2; d = d2; } }
  float4 v = ((const float4*)s)[j];
  bf16x4 o;
  o[0] = (short)f2bf(v.x); o[1] = (short)f2bf(v.y);
  o[2] = (short)f2bf(v.z); o[3] = (short)f2bf(v.w);
  ((bf16x4*)d)[j] = o;
}

// ================== CNN (implicit-GEMM MFMA) + fc, one block per frame =========
__global__ __launch_bounds__(256) void cnn_fc_mfma(
    const float* __restrict__ x,
    const float* __restrict__ w1, const float* __restrict__ b1,
    const float* __restrict__ w2, const float* __restrict__ b2,
    const float* __restrict__ w3, const float* __restrict__ b3,
    const float* __restrict__ fcw, const float* __restrict__ fcb,
    float* __restrict__ hout) {
  __shared__ __align__(16) unsigned short ldsu[31024];
  __shared__ float s_pool[32];
  const int tid = threadIdx.x;
  const int f = blockIdx.x;
  const int lane = tid & 63;
  const int lc = lane & 15;
  const int fq = lane >> 4;
  const int wv = tid >> 6;

  const int FR = 0;
  const int W2 = 0;
  const int C1 = 6400;
  const int C2 = 22800;
  const int W3 = 0;

  // ---- P1
  {
    const float* xin = x + (size_t)f * 4096;
#pragma unroll
    for (int r = 0; r < 4; ++r) {
      float4 v = ((const float4*)xin)[r * 256 + tid];
      bf16x4 o;
      o[0] = (short)f2bf(v.x); o[1] = (short)f2bf(v.y);
      o[2] = (short)f2bf(v.z); o[3] = (short)f2bf(v.w);
      *(bf16x4*)&ldsu[FR + (r * 256 + tid) * 4] = o;
    }
    if (tid < 8)  ((unsigned*)&ldsu[C1 + 1024 * 16])[tid] = 0u;
    if (tid < 16) ((unsigned*)&ldsu[C2 + 256 * 32])[tid] = 0u;
    if (tid < 32) s_pool[tid] = 0.f;
  }
  __syncthreads();

  // ---- P2: conv1 (VALU)
#pragma unroll
  for (int r = 0; r < 4; ++r) {
    int p = r * 256 + tid;
    int oy = p >> 5, ox = p & 31;
    float in9[9];
#pragma unroll
    for (int ky = 0; ky < 3; ++ky) {
      int iy = 2 * oy + ky;
#pragma unroll
      for (int kx = 0; kx < 3; ++kx) {
        int ix = 2 * ox + kx;
        in9[ky * 3 + kx] = (iy < 64 && ix < 64) ? bf2f(ldsu[FR + iy * 64 + ix]) : 0.f;
      }
    }
    bf16x8 o0, o1;
#pragma unroll
    for (int oc = 0; oc < 8; ++oc) {
      float s = b1[oc];
#pragma unroll
      for (int k = 0; k < 9; ++k) s += w1[oc * 9 + k] * in9[k];
      o0[oc] = (short)f2bf(fmaxf(s, 0.f));
    }
#pragma unroll
    for (int oc = 0; oc < 8; ++oc) {
      float s = b1[8 + oc];
#pragma unroll
      for (int k = 0; k < 9; ++k) s += w1[(8 + oc) * 9 + k] * in9[k];
      o1[oc] = (short)f2bf(fmaxf(s, 0.f));
    }
    *(bf16x8*)&ldsu[C1 + p * 16] = o0;
    *(bf16x8*)&ldsu[C1 + p * 16 + 8] = o1;
  }
  __syncthreads();

  // ---- P3: stage w2t
  for (int r = 0; r < 20; ++r) {
    int i = r * 256 + tid;
    int kt = i >> 10, rem = i & 1023;
    int oc = rem >> 5, k = rem & 31;
    int tap = 2 * kt + (k >> 4), ic = k & 15;
    float v = (tap < 9) ? w2[oc * 144 + ic * 9 + tap] : 0.f;
    ldsu[W2 + (kt * 32 + oc) * 40 + k] = f2bf(v);
  }
  __syncthreads();

  // ---- P4: conv2 MFMA
  {
    f32x4 acc[2][4] = {};
    for (int kt = 0; kt < 5; ++kt) {
      bf16x8 a0 = *(const bf16x8*)&ldsu[W2 + (kt * 32 + lc) * 40 + fq * 8];
      bf16x8 a1 = *(const bf16x8*)&ldsu[W2 + (kt * 32 + 16 + lc) * 40 + fq * 8];
      int tap = 2 * kt + (fq >> 1);
      int t9 = (tap < 9) ? tap : 0;
      int ky = (t9 * 11) >> 5;
      int kx = t9 - ky * 3;
      int ix = 2 * lc + kx;
#pragma unroll
      for (int ni = 0; ni < 4; ++ni) {
        int nt = wv * 4 + ni;
        int iy = 2 * nt + ky;
        int ipos = (tap < 9 && iy < 32 && ix < 32) ? iy * 32 + ix : 1024;
        bf16x8 b = *(const bf16x8*)&ldsu[C1 + ipos * 16 + (fq & 1) * 8];
        acc[0][ni] = __builtin_amdgcn_mfma_f32_16x16x32_bf16(a0, b, acc[0][ni], 0, 0, 0);
        acc[1][ni] = __builtin_amdgcn_mfma_f32_16x16x32_bf16(a1, b, acc[1][ni], 0, 0, 0);
      }
    }
#pragma unroll
    for (int mi = 0; mi < 2; ++mi) {
      int oc0 = mi * 16 + fq * 4;
#pragma unroll
      for (int ni = 0; ni < 4; ++ni) {
        int pos = (wv * 4 + ni) * 16 + lc;
        bf16x4 o;
#pragma unroll
        for (int j = 0; j < 4; ++j)
          o[j] = (short)f2bf(fmaxf(acc[mi][ni][j] + b2[oc0 + j], 0.f));
        int g = mi * 4 + fq;
        int gp = ((((g >> 1) ^ ((pos >> 1) & 3)) << 1) | (g & 1));
        *(bf16x4*)&ldsu[C2 + pos * 32 + gp * 4] = o;
      }
    }
  }
  __syncthreads();

  // ---- P5: stage w3t
  for (int r = 0; r < 36; ++r) {
    int i = r * 256 + tid;
    int tap = i >> 10, rem = i & 1023;
    int oc = rem >> 5, ic = rem & 31;
    ldsu[W3 + (tap * 32 + oc) * 40 + ic] = f2bf(w3[oc * 288 + ic * 9 + tap]);
  }
  __syncthreads();

  // ---- P6: conv3 MFMA + pool
  {
    const int mh = wv >> 1, nb = wv & 1;
    f32x4 acc[2] = {};
#pragma unroll
    for (int tap = 0; tap < 9; ++tap) {
      const int ky = tap / 3, kx = tap % 3;
      bf16x8 a = *(const bf16x8*)&ldsu[W3 + (tap * 32 + mh * 16 + lc) * 40 + fq * 8];
#pragma unroll
      for (int ni = 0; ni < 2; ++ni) {
        int pos = (nb * 2 + ni) * 16 + lc;
        int py = pos >> 3, px = pos & 7;
        int iy = 2 * py + ky, ix = 2 * px + kx;
        int ipos = (iy < 16 && ix < 16) ? iy * 16 + ix : 256;
        int sp = fq ^ ((ipos >> 1) & 3);
        bf16x8 b = *(const bf16x8*)&ldsu[C2 + ipos * 32 + sp * 8];
        acc[ni] = __builtin_amdgcn_mfma_f32_16x16x32_bf16(a, b, acc[ni], 0, 0, 0);
      }
    }
    int oc0 = mh * 16 + fq * 4;
#pragma unroll
    for (int j = 0; j < 4; ++j) {
      float v = fmaxf(acc[0][j] + b3[oc0 + j], 0.f) +
                fmaxf(acc[1][j] + b3[oc0 + j], 0.f);
      v += __shfl_xor(v, 1);
      v += __shfl_xor(v, 2);
      v += __shfl_xor(v, 4);
      v += __shfl_xor(v, 8);
      if (lc == 0) atomicAdd(&s_pool[oc0 + j], v);
    }
  }
  __syncthreads();

  // ---- P7: fc 32 -> 256
  {
    float dot = 0.f;
#pragma unroll
    for (int k = 0; k < 32; ++k) dot += fcw[tid * 32 + k] * s_pool[k];
    hout[(size_t)f * 256 + tid] = fcb[tid] + dot * (1.f / 64.f);
  }
}

// ======================= RMSNorm -> bf16 (final only) =======================
__global__ __launch_bounds__(256) void rmsnorm_kernel(const float* __restrict__ x,
                                                      const float* __restrict__ w,
                                                      unsigned short* __restrict__ ob) {
  __shared__ float red[4];
  int t = blockIdx.x, j = threadIdx.x;
  float v = x[(size_t)t * 256 + j];
  float s = v * v;
#pragma unroll
  for (int m = 32; m; m >>= 1) s += __shfl_xor(s, m);
  if ((j & 63) == 0) red[j >> 6] = s;
  __syncthreads();
  float tot = red[0] + red[1] + red[2] + red[3];
  float r = rsqrtf(tot * (1.f / 256.f) + 1e-5f);
  ob[(size_t)t * 256 + j] = f2bf(v * r * w[j]);
}

// ====== fused RMSNorm + in_proj GEMM: C[m][n] = r[m]*sum_k (h*w)[m][k]*W[n][k]
// M=2048, N=1024, K=256. A staged fully (64x256 bf16), r folded into epilogue.
__global__ __launch_bounds__(256) void gemm_rn(const float* __restrict__ H,
                                               const float* __restrict__ nw,
                                               const unsigned short* __restrict__ W,
                                               float* __restrict__ C) {
  __shared__ __align__(16) unsigned short sA[64 * 260];
  __shared__ __align__(16) unsigned short sW[64 * 72];
  __shared__ float s_r[64];
  const int tid = threadIdx.x;
  const int m0 = blockIdx.x * 64, n0 = blockIdx.y * 64;
  const int srow = tid >> 2, sseg = tid & 3;
  // --- A staging: one full row-strip, sumsq on the fly
  {
    const float4* gA4 = (const float4*)(H + (size_t)(m0 + srow) * 256 + sseg * 64);
    const float4* nw4 = (const float4*)(nw + sseg * 64);
    float ss = 0.f;
#pragma unroll
    for (int q = 0; q < 16; ++q) {
      float4 v = gA4[q];
      float4 wv = nw4[q];
      ss += v.x * v.x + v.y * v.y + v.z * v.z + v.w * v.w;
      bf16x4 o;
      o[0] = (short)f2bf(v.x * wv.x); o[1] = (short)f2bf(v.y * wv.y);
      o[2] = (short)f2bf(v.z * wv.z); o[3] = (short)f2bf(v.w * wv.w);
      *(bf16x4*)&sA[srow * 260 + sseg * 64 + q * 4] = o;
    }
    ss += __shfl_xor(ss, 1);
    ss += __shfl_xor(ss, 2);
    if ((tid & 3) == 0) s_r[srow] = rsqrtf(ss * (1.f / 256.f) + 1e-5f);
  }
  // --- W staging tile 0
  const unsigned short* gW = W + (size_t)(n0 + srow) * 256 + sseg * 16;
  u32x4 rw0 = ((const u32x4*)gW)[0];
  u32x4 rw1 = ((const u32x4*)gW)[1];
  *(u32x4*)&sW[srow * 72 + sseg * 16] = rw0;
  *(u32x4*)&sW[srow * 72 + sseg * 16 + 8] = rw1;
  __syncthreads();

  const int wv = tid >> 6, wm = wv >> 1, wn = wv & 1;
  const int fr = tid & 15;
  const int fq = (tid >> 4) & 3;
  f32x4 acc[2][2] = {};

  for (int kt = 0; kt < 4; ++kt) {
    if (kt < 3) {
      rw0 = ((const u32x4*)(gW + (kt + 1) * 64))[0];
      rw1 = ((const u32x4*)(gW + (kt + 1) * 64))[1];
    }
#pragma unroll
    for (int ks = 0; ks < 2; ++ks) {
      bf16x8 a0 = *(const bf16x8*)&sA[(wm * 32 + fr) * 260 + kt * 64 + ks * 32 + fq * 8];
      bf16x8 a1 = *(const bf16x8*)&sA[(wm * 32 + 16 + fr) * 260 + kt * 64 + ks * 32 + fq * 8];
      bf16x8 b0 = *(const bf16x8*)&sW[(wn * 32 + fr) * 72 + ks * 32 + fq * 8];
      bf16x8 b1 = *(const bf16x8*)&sW[(wn * 32 + 16 + fr) * 72 + ks * 32 + fq * 8];
      acc[0][0] = __builtin_amdgcn_mfma_f32_16x16x32_bf16(a0, b0, acc[0][0], 0, 0, 0);
      acc[0][1] = __builtin_amdgcn_mfma_f32_16x16x32_bf16(a0, b1, acc[0][1], 0, 0, 0);
      acc[1][0] = __builtin_amdgcn_mfma_f32_16x16x32_bf16(a1, b0, acc[1][0], 0, 0, 0);
      acc[1][1] = __builtin_amdgcn_mfma_f32_16x16x32_bf16(a1, b1, acc[1][1], 0, 0, 0);
    }
    if (kt < 3) {
      __syncthreads();
      *(u32x4*)&sW[srow * 72 + sseg * 16] = rw0;
      *(u32x4*)&sW[srow * 72 + sseg * 16 + 8] = rw1;
      __syncthreads();
    }
  }

#pragma unroll
  for (int mr = 0; mr < 2; ++mr) {
#pragma unroll
    for (int nr = 0; nr < 2; ++nr) {
      int n = n0 + wn * 32 + nr * 16 + fr;
#pragma unroll
      for (int j = 0; j < 4; ++j) {
        int ml = wm * 32 + mr * 16 + fq * 4 + j;
        C[(size_t)(m0 + ml) * 1024 + n] = acc[mr][nr][j] * s_r[ml];
      }
    }
  }
}

// ============== bf16 MFMA GEMM NT, split-K via gridDim.z, atomic accumulate ===
// Used for out_proj (accumulate into residual h).
__global__ __launch_bounds__(256) void gemm_bb_acc(const unsigned short* __restrict__ A,
                                                   const unsigned short* __restrict__ W,
                                                   float* __restrict__ C,
                                                   int M, int N, int K) {
  __shared__ __align__(16) unsigned short sA[64 * 72];
  __shared__ __align__(16) unsigned short sW[64 * 72];
  const int tid = threadIdx.x;
  const int m0 = blockIdx.x * 64, n0 = blockIdx.y * 64;
  const int ksz = K / (int)gridDim.z;
  const int koff = blockIdx.z * ksz;
  const int srow = tid >> 2, sseg = tid & 3;
  const unsigned short* gA = A + (size_t)(m0 + srow) * K + koff + sseg * 16;
  const unsigned short* gW = W + (size_t)(n0 + srow) * K + koff + sseg * 16;
  const int wv = tid >> 6, wm = wv >> 1, wn = wv & 1;
  const int fr = tid & 15;
  const int fq = (tid >> 4) & 3;
  f32x4 acc[2][2] = {};

  const int NT = ksz >> 6;
  u32x4 ra0, ra1, rw0, rw1;
  ra0 = ((const u32x4*)gA)[0]; ra1 = ((const u32x4*)gA)[1];
  rw0 = ((const u32x4*)gW)[0]; rw1 = ((const u32x4*)gW)[1];
  *(u32x4*)&sA[srow * 72 + sseg * 16] = ra0;
  *(u32x4*)&sA[srow * 72 + sseg * 16 + 8] = ra1;
  *(u32x4*)&sW[srow * 72 + sseg * 16] = rw0;
  *(u32x4*)&sW[srow * 72 + sseg * 16 + 8] = rw1;
  __syncthreads();

  for (int kt = 0; kt < NT; ++kt) {
    if (kt + 1 < NT) {
      ra0 = ((const u32x4*)(gA + (kt + 1) * 64))[0];
      ra1 = ((const u32x4*)(gA + (kt + 1) * 64))[1];
      rw0 = ((const u32x4*)(gW + (kt + 1) * 64))[0];
      rw1 = ((const u32x4*)(gW + (kt + 1) * 64))[1];
    }
#pragma unroll
    for (int ks = 0; ks < 2; ++ks) {
      bf16x8 a0 = *(const bf16x8*)&sA[(wm * 32 + fr) * 72 + ks * 32 + fq * 8];
      bf16x8 a1 = *(const bf16x8*)&sA[(wm * 32 + 16 + fr) * 72 + ks * 32 + fq * 8];
      bf16x8 b0 = *(const bf16x8*)&sW[(wn * 32 + fr) * 72 + ks * 32 + fq * 8];
      bf16x8 b1 = *(const bf16x8*)&sW[(wn * 32 + 16 + fr) * 72 + ks * 32 + fq * 8];
      acc[0][0] = __builtin_amdgcn_mfma_f32_16x16x32_bf16(a0, b0, acc[0][0], 0, 0, 0);
      acc[0][1] = __builtin_amdgcn_mfma_f32_16x16x32_bf16(a0, b1, acc[0][1], 0, 0, 0);
      acc[1][0] = __builtin_amdgcn_mfma_f32_16x16x32_bf16(a1, b0, acc[1][0], 0, 0, 0);
      acc[1][1] = __builtin_amdgcn_mfma_f32_16x16x32_bf16(a1, b1, acc[1][1], 0, 0, 0);
    }
    __syncthreads();
    if (kt + 1 < NT) {
      *(u32x4*)&sA[srow * 72 + sseg * 16] = ra0;
      *(u32x4*)&sA[srow * 72 + sseg * 16 + 8] = ra1;
      *(u32x4*)&sW[srow * 72 + sseg * 16] = rw0;
      *(u32x4*)&sW[srow * 72 + sseg * 16 + 8] = rw1;
      __syncthreads();
    }
  }

#pragma unroll
  for (int mr = 0; mr < 2; ++mr) {
#pragma unroll
    for (int nr = 0; nr < 2; ++nr) {
      int n = n0 + wn * 32 + nr * 16 + fr;
#pragma unroll
      for (int j = 0; j < 4; ++j) {
        int m = m0 + wm * 32 + mr * 16 + fq * 4 + j;
        atomicAdd(&C[(size_t)m * N + n], acc[mr][nr][j]);
      }
    }
  }
}

// ============== x_proj split-K GEMM: partials [kz][2048][48] ==================
// A=ub [2048][512] bf16, W=wxp [48][512] bf16. grid (32, 4): m-tile, kz.
__global__ __launch_bounds__(256) void gemm_xp(const unsigned short* __restrict__ A,
                                               const unsigned short* __restrict__ W,
                                               float* __restrict__ Cp) {
  __shared__ __align__(16) unsigned short sA[64 * 72];
  __shared__ __align__(16) unsigned short sW[64 * 72];
  const int tid = threadIdx.x;
  const int m0 = blockIdx.x * 64;
  const int koff = blockIdx.y * 128;
  const int srow = tid >> 2, sseg = tid & 3;
  int wrow = (srow < 48) ? srow : 0;
  const unsigned short* gA = A + (size_t)(m0 + srow) * 512 + koff + sseg * 16;
  const unsigned short* gW = W + (size_t)wrow * 512 + koff + sseg * 16;
  const int wv = tid >> 6, wm = wv >> 1, wn = wv & 1;
  const int fr = tid & 15;
  const int fq = (tid >> 4) & 3;
  f32x4 acc[2][2] = {};

  u32x4 ra0, ra1, rw0, rw1;
  ra0 = ((const u32x4*)gA)[0]; ra1 = ((const u32x4*)gA)[1];
  rw0 = ((const u32x4*)gW)[0]; rw1 = ((const u32x4*)gW)[1];
  *(u32x4*)&sA[srow * 72 + sseg * 16] = ra0;
  *(u32x4*)&sA[srow * 72 + sseg * 16 + 8] = ra1;
  *(u32x4*)&sW[srow * 72 + sseg * 16] = rw0;
  *(u32x4*)&sW[srow * 72 + sseg * 16 + 8] = rw1;
  __syncthreads();

  for (int kt = 0; kt < 2; ++kt) {
    if (kt == 0) {
      ra0 = ((const u32x4*)(gA + 64))[0];
      ra1 = ((const u32x4*)(gA + 64))[1];
      rw0 = ((const u32x4*)(gW + 64))[0];
      rw1 = ((const u32x4*)(gW + 64))[1];
    }
#pragma unroll
    for (int ks = 0; ks < 2; ++ks) {
      bf16x8 a0 = *(const bf16x8*)&sA[(wm * 32 + fr) * 72 + ks * 32 + fq * 8];
      bf16x8 a1 = *(const bf16x8*)&sA[(wm * 32 + 16 + fr) * 72 + ks * 32 + fq * 8];
      bf16x8 b0 = *(const bf16x8*)&sW[(wn * 32 + fr) * 72 + ks * 32 + fq * 8];
      bf16x8 b1 = *(const bf16x8*)&sW[(wn * 32 + 16 + fr) * 72 + ks * 32 + fq * 8];
      acc[0][0] = __builtin_amdgcn_mfma_f32_16x16x32_bf16(a0, b0, acc[0][0], 0, 0, 0);
      acc[0][1] = __builtin_amdgcn_mfma_f32_16x16x32_bf16(a0, b1, acc[0][1], 0, 0, 0);
      acc[1][0] = __builtin_amdgcn_mfma_f32_16x16x32_bf16(a1, b0, acc[1][0], 0, 0, 0);
      acc[1][1] = __builtin_amdgcn_mfma_f32_16x16x32_bf16(a1, b1, acc[1][1], 0, 0, 0);
    }
    if (kt == 0) {
      __syncthreads();
      *(u32x4*)&sA[srow * 72 + sseg * 16] = ra0;
      *(u32x4*)&sA[srow * 72 + sseg * 16 + 8] = ra1;
      *(u32x4*)&sW[srow * 72 + sseg * 16] = rw0;
      *(u32x4*)&sW[srow * 72 + sseg * 16 + 8] = rw1;
      __syncthreads();
    }
  }

  float* Co = Cp + (size_t)blockIdx.y * 2048 * 48;
#pragma unroll
  for (int mr = 0; mr < 2; ++mr) {
#pragma unroll
    for (int nr = 0; nr < 2; ++nr) {
      int n = wn * 32 + nr * 16 + fr;
      if (n < 48) {
#pragma unroll
        for (int j = 0; j < 4; ++j) {
          int m = m0 + wm * 32 + mr * 16 + fq * 4 + j;
          Co[(size_t)m * 48 + n] = acc[mr][nr][j];
        }
      }
    }
  }
}

// ======================= causal depthwise conv1d (k=4) + silu -> bf16 =========
__global__ __launch_bounds__(256) void conv1d_silu_kernel(const float* __restrict__ xz,
                                                          const float* __restrict__ cw,
                                                          const float* __restrict__ cb,
                                                          unsigned short* __restrict__ ub) {
  int idx = blockIdx.x * 256 + threadIdx.x;
  int e = idx & (DI - 1);
  int bt = idx >> 9;
  int t = bt & (Tt - 1);
  int b = bt >> 8;
  float s = cb[e];
#pragma unroll
  for (int j = 0; j < 4; ++j) {
    int tt = t - 3 + j;
    if (tt >= 0) s += cw[e * 4 + j] * xz[((size_t)(b * Tt + tt)) * (2 * DI) + e];
  }
  ub[idx] = f2bf(siluf(s));
}

// ======= selective scan v4: fused delta-proj + split-K reduce + two-pass ======
// Block = 1024 threads = (chunk 0..3) x (el 0..15) x (n 0..15); 256 blocks.
__global__ __launch_bounds__(1024) void scan_kernel(const float* __restrict__ dbcp,
                                                    const unsigned short* __restrict__ ub,
                                                    const float* __restrict__ xz,
                                                    const float* __restrict__ A_log,
                                                    const float* __restrict__ Dp,
                                                    const float* __restrict__ dpw,
                                                    const float* __restrict__ dpb,
                                                    unsigned short* __restrict__ ybf) {
  __shared__ float sD[256][16];
  __shared__ float sU[256][16];
  __shared__ float sB[256][16];
  __shared__ float sC[256][16];
  __shared__ float sY[256][16];    // staging: dt sums; pass1: hloc/aprod/startH; pass2: y
  __shared__ float s_dpwT[16][17];
  __shared__ float s_dpb[16];
  const int tid = threadIdx.x;
  const int b = blockIdx.x >> 5;
  const int e0 = (blockIdx.x & 31) << 4;
  const int chunk = tid >> 8;
  const int el = (tid >> 4) & 15;
  const int n = tid & 15;
  const int e = e0 + el;
  const float An = -__expf(A_log[e * 16 + n]);
  const float Dv = Dp[e];
  const size_t rowbase = (size_t)b * Tt;

  if (tid < 256) s_dpwT[tid & 15][tid >> 4] = dpw[(size_t)(e0 + (tid >> 4)) * DTR + (tid & 15)];
  if (tid >= 256 && tid < 272) s_dpb[tid - 256] = dpb[e0 + tid - 256];

  // staging: sum split-K partials for dt/B/C; u from bf16
#pragma unroll
  for (int k = 0; k < 4; ++k) {
    int idx = k * 1024 + tid;
    int row = idx >> 4, col = idx & 15;
    size_t gb = (rowbase + row) * 48;
    float dt = 0.f, Bv = 0.f, Cv = 0.f;
#pragma unroll
    for (int kz = 0; kz < 4; ++kz) {
      const float* p = dbcp + (size_t)kz * 2048 * 48 + gb;
      dt += p[col]; Bv += p[16 + col]; Cv += p[32 + col];
    }
    sY[row][col] = dt;
    sB[row][col] = Bv;
    sC[row][col] = Cv;
    sU[row][col] = bf2f(ub[(rowbase + row) * DI + e0 + col]);
  }
  __syncthreads();

  // fused delta projection + softplus: sD[t][el]
#pragma unroll
  for (int k = 0; k < 4; ++k) {
    int idx = k * 1024 + tid;
    int t = idx >> 4, l = idx & 15;
    float a = s_dpb[l];
#pragma unroll
    for (int kk = 0; kk < 16; ++kk) a += sY[t][kk] * s_dpwT[kk][l];
    sD[t][l] = (a > 20.f) ? a : log1pf(__expf(a));
  }
  __syncthreads();

  // pass 1: local scan of own 64-step chunk (h0 = 0), track prod(dA)
  float h = 0.f, ap = 1.f;
  const int t0 = chunk * 64;
#pragma unroll 4
  for (int t = t0; t < t0 + 64; ++t) {
    float dv = sD[t][el];
    float dA = __expf(dv * An);
    h = dA * h + dv * sB[t][n] * sU[t][el];
    ap *= dA;
  }
  float* hloc   = &sY[0][0];
  float* aprod  = &sY[64][0];
  float* startH = &sY[128][0];
  const int sidx = el * 16 + n;
  hloc[chunk * 256 + sidx] = h;
  aprod[chunk * 256 + sidx] = ap;
  __syncthreads();

  if (chunk == 0) {
    float H = 0.f;
    startH[sidx] = 0.f;
#pragma unroll
    for (int c = 0; c < 3; ++c) {
      H = aprod[c * 256 + sidx] * H + hloc[c * 256 + sidx];
      startH[(c + 1) * 256 + sidx] = H;
    }
  }
  __syncthreads();
  float h2 = startH[chunk * 256 + sidx];
  __syncthreads();

  // pass 2: corrected scan + y
#pragma unroll 4
  for (int t = t0; t < t0 + 64; ++t) {
    float dv = sD[t][el];
    float uv = sU[t][el];
    float dA = __expf(dv * An);
    h2 = dA * h2 + dv * sB[t][n] * uv;
    float p = h2 * sC[t][n];
    p += __shfl_xor(p, 1);
    p += __shfl_xor(p, 2);
    p += __shfl_xor(p, 4);
    p += __shfl_xor(p, 8);
    if (n == 0) sY[t][el] = p + uv * Dv;
  }
  __syncthreads();

  // gated bf16 writeout
#pragma unroll
  for (int k = 0; k < 4; ++k) {
    int idx = k * 1024 + tid;
    int t = idx >> 4, col = idx & 15;
    float zv = xz[(rowbase + t) * (2 * DI) + DI + e0 + col];
    ybf[(rowbase + t) * DI + e0 + col] = f2bf(sY[t][col] * siluf(zv));
  }
}

// ======================= GEMM NT fp32 vector (head) ===========================
template <int ACT, typename AT>
__global__ __launch_bounds__(256) void gemm_nt(const AT* __restrict__ A, int lda,
                                               const float* __restrict__ W,
                                               const float* __restrict__ bias,
                                               float* __restrict__ C,
                                               int M, int N, int K) {
  __shared__ __align__(16) float sA[16][68];
  __shared__ __align__(16) float sW[16][68];
  const int m0 = blockIdx.x * 64;
  const int n0 = blockIdx.y * 64;
  const int tid = threadIdx.x;
  const int lk = tid & 15, lm = tid >> 4;
  const int tx = tid & 15, ty = tid >> 4;
  float acc[4][4] = {};

  for (int k0 = 0; k0 < K; k0 += 16) {
#pragma unroll
    for (int p = 0; p < 4; ++p) {
      int m = p * 16 + lm;
      sA[lk][m] = ldf(&A[(size_t)(m0 + m) * lda + k0 + lk]);
    }
#pragma unroll
    for (int p = 0; p < 4; ++p) {
      int n = p * 16 + lm;
      sW[lk][n] = (n0 + n < N) ? W[(size_t)(n0 + n) * K + k0 + lk] : 0.f;
    }
    __syncthreads();
#pragma unroll
    for (int k = 0; k < 16; ++k) {
      float4 a = *(const float4*)&sA[k][ty * 4];
      float4 b = *(const float4*)&sW[k][tx * 4];
      acc[0][0] += a.x * b.x; acc[0][1] += a.x * b.y; acc[0][2] += a.x * b.z; acc[0][3] += a.x * b.w;
      acc[1][0] += a.y * b.x; acc[1][1] += a.y * b.y; acc[1][2] += a.y * b.z; acc[1][3] += a.y * b.w;
      acc[2][0] += a.z * b.x; acc[2][1] += a.z * b.y; acc[2][2] += a.z * b.z; acc[2][3] += a.z * b.w;
      acc[3][0] += a.w * b.x; acc[3][1] += a.w * b.y; acc[3][2] += a.w * b.z; acc[3][3] += a.w * b.w;
    }
    __syncthreads();
  }
#pragma unroll
  for (int i = 0; i < 4; ++i) {
    int m = m0 + ty * 4 + i;
#pragma unroll
    for (int j = 0; j < 4; ++j) {
      int n = n0 + tx * 4 + j;
      if (n < N) {
        float v = acc[i][j];
        if (ACT == 3) {
          v += bias[n];
          float t3 = v * v * v;
          v = 0.5f * v * (1.f + tanhf(0.7978845608028654f * (v + 0.044715f * t3)));
        }
        C[(size_t)m * N + n] = v;
      }
    }
  }
}

// ======================= head: fused logits + softmax =========================
__global__ __launch_bounds__(256) void head_kernel(const float* __restrict__ hh,
                                                   const float* __restrict__ w2,
                                                   const float* __restrict__ b2,
                                                   float* __restrict__ out) {
  __shared__ float redm[4], reds[4];
  int b = blockIdx.x, t = threadIdx.x;
  const float4* row = (const float4*)(hh + ((size_t)b * 256 + t) * 64);
  float v = b2[0];
#pragma unroll
  for (int q = 0; q < 16; ++q) {
    float4 a = row[q];
    float4 w = ((const float4*)w2)[q];
    v += a.x * w.x + a.y * w.y + a.z * w.z + a.w * w.w;
  }
  float m = v;
#pragma unroll
  for (int k = 32; k; k >>= 1) m = fmaxf(m, __shfl_xor(m, k));
  if ((t & 63) == 0) redm[t >> 6] = m;
  __syncthreads();
  m = fmaxf(fmaxf(redm[0], redm[1]), fmaxf(redm[2], redm[3]));
  float e = __expf(v - m);
  float s = e;
#pragma unroll
  for (int k = 32; k; k >>= 1) s += __shfl_xor(s, k);
  if ((t & 63) == 0) reds[t >> 6] = s;
  __syncthreads();
  s = reds[0] + reds[1] + reds[2] + reds[3];
  out[b * 256 + t] = (t == 0) ? 0.f : e / s;
}

// ======================= launch ===============================================
extern "C" void kernel_launch(void* const* d_in, const int* in_sizes, int n_in,
                              void* d_out, int out_size, void* d_ws, size_t ws_size,
                              hipStream_t stream) {
  const float* x      = (const float*)d_in[0];
  const float* cnn_w1 = (const float*)d_in[1];
  const float* cnn_b1 = (const float*)d_in[2];
  const float* cnn_w2 = (const float*)d_in[3];
  const float* cnn_b2 = (const float*)d_in[4];
  const float* cnn_w3 = (const float*)d_in[5];
  const float* cnn_b3 = (const float*)d_in[6];
  const float* fc_w   = (const float*)d_in[7];
  const float* fc_b   = (const float*)d_in[8];
  const float* norm_w = (const float*)d_in[9];
  const float* ipw    = (const float*)d_in[10];
  const float* cw     = (const float*)d_in[11];
  const float* cb     = (const float*)d_in[12];
  const float* xpw    = (const float*)d_in[13];
  const float* dpw    = (const float*)d_in[14];
  const float* dpb    = (const float*)d_in[15];
  const float* A_log  = (const float*)d_in[16];
  const float* Dp     = (const float*)d_in[17];
  const float* opw    = (const float*)d_in[18];
  const float* nfw    = (const float*)d_in[19];
  const float* hw1    = (const float*)d_in[20];
  const float* hb1    = (const float*)d_in[21];
  const float* hw2    = (const float*)d_in[22];
  const float* hb2    = (const float*)d_in[23];

  float* ws    = (float*)d_ws;
  float* h     = ws + OFF_H;
  float* xz    = ws + OFF_XZ;
  float* dbcp  = ws + OFF_DBCP;
  float* hh    = ws + OFF_HH;
  float* logit = ws + OFF_LOGIT;  (void)logit;
  unsigned short* xnb = (unsigned short*)(ws + OFF_XNB);
  unsigned short* ub  = (unsigned short*)(ws + OFF_UB);
  unsigned short* ybf = (unsigned short*)(ws + OFF_YBF);
  unsigned short* wip = (unsigned short*)(ws + OFF_WIP);
  unsigned short* wxp = (unsigned short*)(ws + OFF_WXP);
  unsigned short* wop = (unsigned short*)(ws + OFF_WOP);

  const int nv0 = NL * 2 * DI * DM / 4, nv1 = NL * 48 * DI / 4, nv2 = NL * DM * DI / 4;
  cvt_all_kernel<<<(nv0 + nv1 + nv2 + 255) / 256, 256, 0, stream>>>(
      ipw, wip, nv0, xpw, wxp, nv1, opw, wop, nv2);

  cnn_fc_mfma<<<Bb * Tt, 256, 0, stream>>>(x, cnn_w1, cnn_b1, cnn_w2, cnn_b2,
                                           cnn_w3, cnn_b3, fc_w, fc_b, h);

  for (int l = 0; l < NL; ++l) {
    {
      dim3 g(32, 16);   // fused rmsnorm + in_proj
      gemm_rn<<<g, 256, 0, stream>>>(h, norm_w + l * DM,
                                     wip + (size_t)l * 2 * DI * DM, xz);
    }
    conv1d_silu_kernel<<<(Bb * Tt * DI) / 256, 256, 0, stream>>>(
        xz, cw + l * DI * 4, cb + l * DI, ub);
    {
      dim3 g(32, 4);    // x_proj split-K x4 -> partials
      gemm_xp<<<g, 256, 0, stream>>>(ub, wxp + (size_t)l * 48 * DI, dbcp);
    }
    scan_kernel<<<Bb * 32, 1024, 0, stream>>>(
        dbcp, ub, xz, A_log + (size_t)l * DI * DS, Dp + l * DI,
        dpw + (size_t)l * DI * DTR, dpb + l * DI, ybf);
    {
      dim3 g(32, 4, 2); // out_proj split-K x2, atomic accumulate into h
      gemm_bb_acc<<<g, 256, 0, stream>>>(ybf, wop + (size_t)l * DM * DI, h,
                                         Bb * Tt, DM, DI);
    }
  }

  rmsnorm_kernel<<<Bb * Tt, 256, 0, stream>>>(h, nfw, xnb);
  {
    dim3 g(32, 1);
    gemm_nt<3, unsigned short><<<g, 256, 0, stream>>>(xnb, DM, hw1, hb1, hh,
                                                      Bb * Tt, 64, DM);
  }
  head_kernel<<<Bb, 256, 0, stream>>>(hh, hw2, hb2, (float*)d_out);
}

// Round 9
// 578.377 us; speedup vs baseline: 4.4467x; 1.0188x over previous
//
#include <hip/hip_runtime.h>
#include <hip/hip_bf16.h>
#include <math.h>

// Problem dims
#define Bb 8
#define Tt 256
#define DM 256       // d_model
#define DI 512       // d_inner
#define NL 6
#define DS 16        // d_state
#define DTR 16       // dt_rank

// ---------------- workspace layout (float units) ----------------
#define OFF_H     0u          // f32 [2048][256]
#define OFF_XZ    524288u     // f32 [2048][1024]
#define OFF_DBCP  2621440u    // f32 [4][2048][48] split-K partials
#define OFF_HH    3014656u    // f32 [2048][64]
#define OFF_LOGIT 3145728u    // f32 [2048]
#define OFF_XNB   3147776u    // bf16 [2048][256]
#define OFF_W2T   3278848u    // bf16 [5][32][32] cnn w2 transposed (2560 floats)
#define OFF_W3T   3281408u    // bf16 [9][32][32] cnn w3 transposed (4608 floats)
#define OFF_YBF   3540992u    // bf16 [2048][512]
#define OFF_WIP   3803136u    // bf16 ipw 6*1024*256
#define OFF_WXP   4589568u    // bf16 xpw 6*48*512
#define OFF_WOP   4663296u    // bf16 opw 6*256*512
// total 5056512 floats = 20.2 MB

__device__ __forceinline__ float siluf(float x) { return x / (1.f + __expf(-x)); }

typedef __attribute__((ext_vector_type(8))) short bf16x8;
typedef __attribute__((ext_vector_type(4))) short bf16x4;
typedef __attribute__((ext_vector_type(4))) float f32x4;
typedef __attribute__((ext_vector_type(4))) unsigned int u32x4;

__device__ __forceinline__ unsigned short f2bf(float x) {
  unsigned u = __float_as_uint(x);
  u += 0x7FFFu + ((u >> 16) & 1u);   // RNE
  return (unsigned short)(u >> 16);
}
__device__ __forceinline__ float bf2f(unsigned short u) {
  return __uint_as_float((unsigned)u << 16);
}
__device__ __forceinline__ float ldf(const float* p) { return *p; }
__device__ __forceinline__ float ldf(const unsigned short* p) { return bf2f(*p); }

// ======================= fp32 -> bf16 convert (all 3 weight sets) =============
__global__ __launch_bounds__(256) void cvt_all_kernel(
    const float* __restrict__ s0, unsigned short* __restrict__ d0, int n0,
    const float* __restrict__ s1, unsigned short* __restrict__ d1, int n1,
    const float* __restrict__ s2, unsigned short* __restrict__ d2, int n2) {
  int i = blockIdx.x * 256 + threadIdx.x;
  const float* s; unsigned short* d; int j = i;
  if (j < n0) { s = s0; d = d0; }
  else { j -= n0; if (j < n1) { s = s1; d = d1; }
         else { j -= n1; if (j >= n2) return; s = s2; d = d2; } }
  float4 v = ((const float4*)s)[j];
  bf16x4 o;
  o[0] = (short)f2bf(v.x); o[1] = (short)f2bf(v.y);
  o[2] = (short)f2bf(v.z); o[3] = (short)f2bf(v.w);
  ((bf16x4*)d)[j] = o;
}

// ====== CNN weight pre-transpose to MFMA A-layout (bf16, global, L2-hot) ======
// w2t: [kt(5)][oc(32)][k(32)] with k = tappair-half*16 + ic, tap=2kt+(k>>4)
// w3t: [tap(9)][oc(32)][ic(32)]
__global__ __launch_bounds__(256) void cvt_cnnw_kernel(const float* __restrict__ w2,
                                                       const float* __restrict__ w3,
                                                       unsigned short* __restrict__ w2t,
                                                       unsigned short* __restrict__ w3t) {
  int i = blockIdx.x * 256 + threadIdx.x;
  if (i < 5120) {
    int kt = i >> 10, rem = i & 1023;
    int oc = rem >> 5, k = rem & 31;
    int tap = 2 * kt + (k >> 4), ic = k & 15;
    w2t[i] = f2bf((tap < 9) ? w2[oc * 144 + ic * 9 + tap] : 0.f);
  } else if (i < 5120 + 9216) {
    int j = i - 5120;
    int tap = j >> 10, rem = j & 1023;
    int oc = rem >> 5, ic = rem & 31;
    w3t[j] = f2bf(w3[oc * 288 + ic * 9 + tap]);
  }
}

// ================== CNN (implicit-GEMM MFMA) + fc, one block per frame =========
// LDS 49.3KB -> 3 blocks/CU. Weights read from global (L2-resident w2t/w3t).
// C1 [1025][16] at 0; C2 [257][32] at 16400; frame FR aliases C2 (dead by P4).
__global__ __launch_bounds__(256) void cnn_fc_mfma(
    const float* __restrict__ x,
    const float* __restrict__ w1, const float* __restrict__ b1,
    const unsigned short* __restrict__ w2t, const float* __restrict__ b2,
    const unsigned short* __restrict__ w3t, const float* __restrict__ b3,
    const float* __restrict__ fcw, const float* __restrict__ fcb,
    float* __restrict__ hout) {
  __shared__ __align__(16) unsigned short ldsu[24624];
  __shared__ float s_pool[32];
  const int tid = threadIdx.x;
  const int f = blockIdx.x;
  const int lane = tid & 63;
  const int lc = lane & 15;
  const int fq = lane >> 4;
  const int wv = tid >> 6;

  const int C1 = 0;       // [1025][16], row 1024 = zeros
  const int C2 = 16400;   // [257][32] swizzled, row 256 = zeros
  const int FR = 16400;   // frame bf16 [64][64], aliases C2 (dead before C2 writes)

  // ---- P1: frame -> FR; zero rows; zero pool
  {
    const float* xin = x + (size_t)f * 4096;
#pragma unroll
    for (int r = 0; r < 4; ++r) {
      float4 v = ((const float4*)xin)[r * 256 + tid];
      bf16x4 o;
      o[0] = (short)f2bf(v.x); o[1] = (short)f2bf(v.y);
      o[2] = (short)f2bf(v.z); o[3] = (short)f2bf(v.w);
      *(bf16x4*)&ldsu[FR + (r * 256 + tid) * 4] = o;
    }
    if (tid < 8)  ((unsigned*)&ldsu[C1 + 1024 * 16])[tid] = 0u;   // C1 zero row
    if (tid < 16) ((unsigned*)&ldsu[C2 + 256 * 32])[tid] = 0u;    // C2 zero row (beyond FR)
    if (tid < 32) s_pool[tid] = 0.f;
  }
  __syncthreads();

  // ---- P2: conv1 (VALU, 1->16ch), write c1t[pos][ic]
#pragma unroll
  for (int r = 0; r < 4; ++r) {
    int p = r * 256 + tid;
    int oy = p >> 5, ox = p & 31;
    float in9[9];
#pragma unroll
    for (int ky = 0; ky < 3; ++ky) {
      int iy = 2 * oy + ky;
#pragma unroll
      for (int kx = 0; kx < 3; ++kx) {
        int ix = 2 * ox + kx;
        in9[ky * 3 + kx] = (iy < 64 && ix < 64) ? bf2f(ldsu[FR + iy * 64 + ix]) : 0.f;
      }
    }
    bf16x8 o0, o1;
#pragma unroll
    for (int oc = 0; oc < 8; ++oc) {
      float s = b1[oc];
#pragma unroll
      for (int k = 0; k < 9; ++k) s += w1[oc * 9 + k] * in9[k];
      o0[oc] = (short)f2bf(fmaxf(s, 0.f));
    }
#pragma unroll
    for (int oc = 0; oc < 8; ++oc) {
      float s = b1[8 + oc];
#pragma unroll
      for (int k = 0; k < 9; ++k) s += w1[(8 + oc) * 9 + k] * in9[k];
      o1[oc] = (short)f2bf(fmaxf(s, 0.f));
    }
    *(bf16x8*)&ldsu[C1 + p * 16] = o0;
    *(bf16x8*)&ldsu[C1 + p * 16 + 8] = o1;
  }
  __syncthreads();

  // ---- P4: conv2 MFMA (A from global w2t; B from C1); epilogue -> C2 (over FR)
  {
    f32x4 acc[2][4] = {};
    for (int kt = 0; kt < 5; ++kt) {
      bf16x8 a0 = *(const bf16x8*)&w2t[(kt * 32 + lc) * 32 + fq * 8];
      bf16x8 a1 = *(const bf16x8*)&w2t[(kt * 32 + 16 + lc) * 32 + fq * 8];
      int tap = 2 * kt + (fq >> 1);
      int t9 = (tap < 9) ? tap : 0;
      int ky = (t9 * 11) >> 5;
      int kx = t9 - ky * 3;
      int ix = 2 * lc + kx;
#pragma unroll
      for (int ni = 0; ni < 4; ++ni) {
        int nt = wv * 4 + ni;
        int iy = 2 * nt + ky;
        int ipos = (tap < 9 && iy < 32 && ix < 32) ? iy * 32 + ix : 1024;
        bf16x8 b = *(const bf16x8*)&ldsu[C1 + ipos * 16 + (fq & 1) * 8];
        acc[0][ni] = __builtin_amdgcn_mfma_f32_16x16x32_bf16(a0, b, acc[0][ni], 0, 0, 0);
        acc[1][ni] = __builtin_amdgcn_mfma_f32_16x16x32_bf16(a1, b, acc[1][ni], 0, 0, 0);
      }
    }
#pragma unroll
    for (int mi = 0; mi < 2; ++mi) {
      int oc0 = mi * 16 + fq * 4;
#pragma unroll
      for (int ni = 0; ni < 4; ++ni) {
        int pos = (wv * 4 + ni) * 16 + lc;
        bf16x4 o;
#pragma unroll
        for (int j = 0; j < 4; ++j)
          o[j] = (short)f2bf(fmaxf(acc[mi][ni][j] + b2[oc0 + j], 0.f));
        int g = mi * 4 + fq;
        int gp = ((((g >> 1) ^ ((pos >> 1) & 3)) << 1) | (g & 1));
        *(bf16x4*)&ldsu[C2 + pos * 32 + gp * 4] = o;
      }
    }
  }
  __syncthreads();

  // ---- P6: conv3 MFMA (A from global w3t; B from C2) + bias+relu+pool
  {
    const int mh = wv >> 1, nb = wv & 1;
    f32x4 acc[2] = {};
#pragma unroll
    for (int tap = 0; tap < 9; ++tap) {
      const int ky = tap / 3, kx = tap % 3;
      bf16x8 a = *(const bf16x8*)&w3t[(tap * 32 + mh * 16 + lc) * 32 + fq * 8];
#pragma unroll
      for (int ni = 0; ni < 2; ++ni) {
        int pos = (nb * 2 + ni) * 16 + lc;
        int py = pos >> 3, px = pos & 7;
        int iy = 2 * py + ky, ix = 2 * px + kx;
        int ipos = (iy < 16 && ix < 16) ? iy * 16 + ix : 256;
        int sp = fq ^ ((ipos >> 1) & 3);
        bf16x8 b = *(const bf16x8*)&ldsu[C2 + ipos * 32 + sp * 8];
        acc[ni] = __builtin_amdgcn_mfma_f32_16x16x32_bf16(a, b, acc[ni], 0, 0, 0);
      }
    }
    int oc0 = mh * 16 + fq * 4;
#pragma unroll
    for (int j = 0; j < 4; ++j) {
      float v = fmaxf(acc[0][j] + b3[oc0 + j], 0.f) +
                fmaxf(acc[1][j] + b3[oc0 + j], 0.f);
      v += __shfl_xor(v, 1);
      v += __shfl_xor(v, 2);
      v += __shfl_xor(v, 4);
      v += __shfl_xor(v, 8);
      if (lc == 0) atomicAdd(&s_pool[oc0 + j], v);
    }
  }
  __syncthreads();

  // ---- P7: fc 32 -> 256
  {
    float dot = 0.f;
#pragma unroll
    for (int k = 0; k < 32; ++k) dot += fcw[tid * 32 + k] * s_pool[k];
    hout[(size_t)f * 256 + tid] = fcb[tid] + dot * (1.f / 64.f);
  }
}

// ======================= RMSNorm -> bf16 (final only) =======================
__global__ __launch_bounds__(256) void rmsnorm_kernel(const float* __restrict__ x,
                                                      const float* __restrict__ w,
                                                      unsigned short* __restrict__ ob) {
  __shared__ float red[4];
  int t = blockIdx.x, j = threadIdx.x;
  float v = x[(size_t)t * 256 + j];
  float s = v * v;
#pragma unroll
  for (int m = 32; m; m >>= 1) s += __shfl_xor(s, m);
  if ((j & 63) == 0) red[j >> 6] = s;
  __syncthreads();
  float tot = red[0] + red[1] + red[2] + red[3];
  float r = rsqrtf(tot * (1.f / 256.f) + 1e-5f);
  ob[(size_t)t * 256 + j] = f2bf(v * r * w[j]);
}

// ====== fused RMSNorm + in_proj GEMM: C[m][n] = r[m]*sum_k (h*w)[m][k]*W[n][k]
__global__ __launch_bounds__(256) void gemm_rn(const float* __restrict__ H,
                                               const float* __restrict__ nw,
                                               const unsigned short* __restrict__ W,
                                               float* __restrict__ C) {
  __shared__ __align__(16) unsigned short sA[64 * 260];
  __shared__ __align__(16) unsigned short sW[64 * 72];
  __shared__ float s_r[64];
  const int tid = threadIdx.x;
  const int m0 = blockIdx.x * 64, n0 = blockIdx.y * 64;
  const int srow = tid >> 2, sseg = tid & 3;
  {
    const float4* gA4 = (const float4*)(H + (size_t)(m0 + srow) * 256 + sseg * 64);
    const float4* nw4 = (const float4*)(nw + sseg * 64);
    float ss = 0.f;
#pragma unroll
    for (int q = 0; q < 16; ++q) {
      float4 v = gA4[q];
      float4 wv = nw4[q];
      ss += v.x * v.x + v.y * v.y + v.z * v.z + v.w * v.w;
      bf16x4 o;
      o[0] = (short)f2bf(v.x * wv.x); o[1] = (short)f2bf(v.y * wv.y);
      o[2] = (short)f2bf(v.z * wv.z); o[3] = (short)f2bf(v.w * wv.w);
      *(bf16x4*)&sA[srow * 260 + sseg * 64 + q * 4] = o;
    }
    ss += __shfl_xor(ss, 1);
    ss += __shfl_xor(ss, 2);
    if ((tid & 3) == 0) s_r[srow] = rsqrtf(ss * (1.f / 256.f) + 1e-5f);
  }
  const unsigned short* gW = W + (size_t)(n0 + srow) * 256 + sseg * 16;
  u32x4 rw0 = ((const u32x4*)gW)[0];
  u32x4 rw1 = ((const u32x4*)gW)[1];
  *(u32x4*)&sW[srow * 72 + sseg * 16] = rw0;
  *(u32x4*)&sW[srow * 72 + sseg * 16 + 8] = rw1;
  __syncthreads();

  const int wv = tid >> 6, wm = wv >> 1, wn = wv & 1;
  const int fr = tid & 15;
  const int fq = (tid >> 4) & 3;
  f32x4 acc[2][2] = {};

  for (int kt = 0; kt < 4; ++kt) {
    if (kt < 3) {
      rw0 = ((const u32x4*)(gW + (kt + 1) * 64))[0];
      rw1 = ((const u32x4*)(gW + (kt + 1) * 64))[1];
    }
#pragma unroll
    for (int ks = 0; ks < 2; ++ks) {
      bf16x8 a0 = *(const bf16x8*)&sA[(wm * 32 + fr) * 260 + kt * 64 + ks * 32 + fq * 8];
      bf16x8 a1 = *(const bf16x8*)&sA[(wm * 32 + 16 + fr) * 260 + kt * 64 + ks * 32 + fq * 8];
      bf16x8 b0 = *(const bf16x8*)&sW[(wn * 32 + fr) * 72 + ks * 32 + fq * 8];
      bf16x8 b1 = *(const bf16x8*)&sW[(wn * 32 + 16 + fr) * 72 + ks * 32 + fq * 8];
      acc[0][0] = __builtin_amdgcn_mfma_f32_16x16x32_bf16(a0, b0, acc[0][0], 0, 0, 0);
      acc[0][1] = __builtin_amdgcn_mfma_f32_16x16x32_bf16(a0, b1, acc[0][1], 0, 0, 0);
      acc[1][0] = __builtin_amdgcn_mfma_f32_16x16x32_bf16(a1, b0, acc[1][0], 0, 0, 0);
      acc[1][1] = __builtin_amdgcn_mfma_f32_16x16x32_bf16(a1, b1, acc[1][1], 0, 0, 0);
    }
    if (kt < 3) {
      __syncthreads();
      *(u32x4*)&sW[srow * 72 + sseg * 16] = rw0;
      *(u32x4*)&sW[srow * 72 + sseg * 16 + 8] = rw1;
      __syncthreads();
    }
  }

#pragma unroll
  for (int mr = 0; mr < 2; ++mr) {
#pragma unroll
    for (int nr = 0; nr < 2; ++nr) {
      int n = n0 + wn * 32 + nr * 16 + fr;
#pragma unroll
      for (int j = 0; j < 4; ++j) {
        int ml = wm * 32 + mr * 16 + fq * 4 + j;
        C[(size_t)(m0 + ml) * 1024 + n] = acc[mr][nr][j] * s_r[ml];
      }
    }
  }
}

// ============== bf16 MFMA GEMM NT, split-K via gridDim.z, atomic accumulate ===
__global__ __launch_bounds__(256) void gemm_bb_acc(const unsigned short* __restrict__ A,
                                                   const unsigned short* __restrict__ W,
                                                   float* __restrict__ C,
                                                   int M, int N, int K) {
  __shared__ __align__(16) unsigned short sA[64 * 72];
  __shared__ __align__(16) unsigned short sW[64 * 72];
  const int tid = threadIdx.x;
  const int m0 = blockIdx.x * 64, n0 = blockIdx.y * 64;
  const int ksz = K / (int)gridDim.z;
  const int koff = blockIdx.z * ksz;
  const int srow = tid >> 2, sseg = tid & 3;
  const unsigned short* gA = A + (size_t)(m0 + srow) * K + koff + sseg * 16;
  const unsigned short* gW = W + (size_t)(n0 + srow) * K + koff + sseg * 16;
  const int wv = tid >> 6, wm = wv >> 1, wn = wv & 1;
  const int fr = tid & 15;
  const int fq = (tid >> 4) & 3;
  f32x4 acc[2][2] = {};

  const int NT = ksz >> 6;
  u32x4 ra0, ra1, rw0, rw1;
  ra0 = ((const u32x4*)gA)[0]; ra1 = ((const u32x4*)gA)[1];
  rw0 = ((const u32x4*)gW)[0]; rw1 = ((const u32x4*)gW)[1];
  *(u32x4*)&sA[srow * 72 + sseg * 16] = ra0;
  *(u32x4*)&sA[srow * 72 + sseg * 16 + 8] = ra1;
  *(u32x4*)&sW[srow * 72 + sseg * 16] = rw0;
  *(u32x4*)&sW[srow * 72 + sseg * 16 + 8] = rw1;
  __syncthreads();

  for (int kt = 0; kt < NT; ++kt) {
    if (kt + 1 < NT) {
      ra0 = ((const u32x4*)(gA + (kt + 1) * 64))[0];
      ra1 = ((const u32x4*)(gA + (kt + 1) * 64))[1];
      rw0 = ((const u32x4*)(gW + (kt + 1) * 64))[0];
      rw1 = ((const u32x4*)(gW + (kt + 1) * 64))[1];
    }
#pragma unroll
    for (int ks = 0; ks < 2; ++ks) {
      bf16x8 a0 = *(const bf16x8*)&sA[(wm * 32 + fr) * 72 + ks * 32 + fq * 8];
      bf16x8 a1 = *(const bf16x8*)&sA[(wm * 32 + 16 + fr) * 72 + ks * 32 + fq * 8];
      bf16x8 b0 = *(const bf16x8*)&sW[(wn * 32 + fr) * 72 + ks * 32 + fq * 8];
      bf16x8 b1 = *(const bf16x8*)&sW[(wn * 32 + 16 + fr) * 72 + ks * 32 + fq * 8];
      acc[0][0] = __builtin_amdgcn_mfma_f32_16x16x32_bf16(a0, b0, acc[0][0], 0, 0, 0);
      acc[0][1] = __builtin_amdgcn_mfma_f32_16x16x32_bf16(a0, b1, acc[0][1], 0, 0, 0);
      acc[1][0] = __builtin_amdgcn_mfma_f32_16x16x32_bf16(a1, b0, acc[1][0], 0, 0, 0);
      acc[1][1] = __builtin_amdgcn_mfma_f32_16x16x32_bf16(a1, b1, acc[1][1], 0, 0, 0);
    }
    __syncthreads();
    if (kt + 1 < NT) {
      *(u32x4*)&sA[srow * 72 + sseg * 16] = ra0;
      *(u32x4*)&sA[srow * 72 + sseg * 16 + 8] = ra1;
      *(u32x4*)&sW[srow * 72 + sseg * 16] = rw0;
      *(u32x4*)&sW[srow * 72 + sseg * 16 + 8] = rw1;
      __syncthreads();
    }
  }

#pragma unroll
  for (int mr = 0; mr < 2; ++mr) {
#pragma unroll
    for (int nr = 0; nr < 2; ++nr) {
      int n = n0 + wn * 32 + nr * 16 + fr;
#pragma unroll
      for (int j = 0; j < 4; ++j) {
        int m = m0 + wm * 32 + mr * 16 + fq * 4 + j;
        atomicAdd(&C[(size_t)m * N + n], acc[mr][nr][j]);
      }
    }
  }
}

// ============== x_proj split-K GEMM with FUSED conv1d+silu A-staging ==========
// A computed on the fly from xz (x-half); W=wxp bf16. grid (32, 4): m-tile, kz.
__global__ __launch_bounds__(256) void gemm_xp(const float* __restrict__ xz,
                                               const float* __restrict__ cw,
                                               const float* __restrict__ cb,
                                               const unsigned short* __restrict__ W,
                                               float* __restrict__ Cp) {
  __shared__ __align__(16) unsigned short sA[64 * 72];
  __shared__ __align__(16) unsigned short sW[64 * 72];
  const int tid = threadIdx.x;
  const int m0 = blockIdx.x * 64;
  const int koff = blockIdx.y * 128;
  const int srow = tid >> 2, sseg = tid & 3;
  const int m = m0 + srow;
  const int t = m & (Tt - 1);
  int wrow = (srow < 48) ? srow : 0;
  const unsigned short* gW = W + (size_t)wrow * 512 + koff + sseg * 16;
  const int wv = tid >> 6, wm = wv >> 1, wn = wv & 1;
  const int fr = tid & 15;
  const int fq = (tid >> 4) & 3;
  f32x4 acc[2][2] = {};

  for (int kt = 0; kt < 2; ++kt) {
    if (kt) __syncthreads();   // previous tile's reads complete
    // --- A staging: u = silu(conv1d(xz)) computed on the fly
    {
      int ebase = koff + kt * 64 + sseg * 16;
      unsigned short* pa = &sA[srow * 72 + sseg * 16];
#pragma unroll
      for (int q = 0; q < 4; ++q) {
        int e = ebase + q * 4;
        const float* cwp = cw + e * 4;   // [4 chans][4 taps]
        float s0 = cb[e], s1 = cb[e + 1], s2 = cb[e + 2], s3 = cb[e + 3];
#pragma unroll
        for (int j = 0; j < 4; ++j) {
          int tt = t - 3 + j;
          if (tt >= 0) {
            float4 xv = *(const float4*)&xz[(size_t)(m - 3 + j) * 1024 + e];
            s0 += cwp[0 * 4 + j] * xv.x;
            s1 += cwp[1 * 4 + j] * xv.y;
            s2 += cwp[2 * 4 + j] * xv.z;
            s3 += cwp[3 * 4 + j] * xv.w;
          }
        }
        bf16x4 o;
        o[0] = (short)f2bf(siluf(s0)); o[1] = (short)f2bf(siluf(s1));
        o[2] = (short)f2bf(siluf(s2)); o[3] = (short)f2bf(siluf(s3));
        *(bf16x4*)&pa[q * 4] = o;
      }
    }
    // --- W staging
    {
      u32x4 rw0 = ((const u32x4*)(gW + kt * 64))[0];
      u32x4 rw1 = ((const u32x4*)(gW + kt * 64))[1];
      *(u32x4*)&sW[srow * 72 + sseg * 16] = rw0;
      *(u32x4*)&sW[srow * 72 + sseg * 16 + 8] = rw1;
    }
    __syncthreads();
#pragma unroll
    for (int ks = 0; ks < 2; ++ks) {
      bf16x8 a0 = *(const bf16x8*)&sA[(wm * 32 + fr) * 72 + ks * 32 + fq * 8];
      bf16x8 a1 = *(const bf16x8*)&sA[(wm * 32 + 16 + fr) * 72 + ks * 32 + fq * 8];
      bf16x8 b0 = *(const bf16x8*)&sW[(wn * 32 + fr) * 72 + ks * 32 + fq * 8];
      bf16x8 b1 = *(const bf16x8*)&sW[(wn * 32 + 16 + fr) * 72 + ks * 32 + fq * 8];
      acc[0][0] = __builtin_amdgcn_mfma_f32_16x16x32_bf16(a0, b0, acc[0][0], 0, 0, 0);
      acc[0][1] = __builtin_amdgcn_mfma_f32_16x16x32_bf16(a0, b1, acc[0][1], 0, 0, 0);
      acc[1][0] = __builtin_amdgcn_mfma_f32_16x16x32_bf16(a1, b0, acc[1][0], 0, 0, 0);
      acc[1][1] = __builtin_amdgcn_mfma_f32_16x16x32_bf16(a1, b1, acc[1][1], 0, 0, 0);
    }
  }

  float* Co = Cp + (size_t)blockIdx.y * 2048 * 48;
#pragma unroll
  for (int mr = 0; mr < 2; ++mr) {
#pragma unroll
    for (int nr = 0; nr < 2; ++nr) {
      int n = wn * 32 + nr * 16 + fr;
      if (n < 48) {
#pragma unroll
        for (int j = 0; j < 4; ++j) {
          int mm = m0 + wm * 32 + mr * 16 + fq * 4 + j;
          Co[(size_t)mm * 48 + n] = acc[mr][nr][j];
        }
      }
    }
  }
}

// ======= selective scan v5: fused conv1d+silu, delta-proj, split-K reduce =====
// Block = 1024 threads = (chunk 0..3) x (el 0..15) x (n 0..15); 256 blocks.
__global__ __launch_bounds__(1024) void scan_kernel(const float* __restrict__ dbcp,
                                                    const float* __restrict__ xz,
                                                    const float* __restrict__ cw,
                                                    const float* __restrict__ cb,
                                                    const float* __restrict__ A_log,
                                                    const float* __restrict__ Dp,
                                                    const float* __restrict__ dpw,
                                                    const float* __restrict__ dpb,
                                                    unsigned short* __restrict__ ybf) {
  __shared__ float sD[256][16];
  __shared__ float sU[256][16];
  __shared__ float sB[256][16];
  __shared__ float sC[256][16];
  __shared__ float sY[256][16];    // staging: dt sums; pass1: hloc/aprod/startH; pass2: y
  __shared__ float s_dpwT[16][17];
  __shared__ float s_dpb[16];
  const int tid = threadIdx.x;
  const int b = blockIdx.x >> 5;
  const int e0 = (blockIdx.x & 31) << 4;
  const int chunk = tid >> 8;
  const int el = (tid >> 4) & 15;
  const int n = tid & 15;
  const int e = e0 + el;
  const float An = -__expf(A_log[e * 16 + n]);
  const float Dv = Dp[e];
  const size_t rowbase = (size_t)b * Tt;

  if (tid < 256) s_dpwT[tid & 15][tid >> 4] = dpw[(size_t)(e0 + (tid >> 4)) * DTR + (tid & 15)];
  if (tid >= 256 && tid < 272) s_dpb[tid - 256] = dpb[e0 + tid - 256];

  // staging: split-K reduce for dt/B/C; u = silu(conv1d(xz)) fused
#pragma unroll
  for (int k = 0; k < 4; ++k) {
    int idx = k * 1024 + tid;
    int row = idx >> 4, col = idx & 15;
    size_t gb = (rowbase + row) * 48;
    float dt = 0.f, Bv = 0.f, Cv = 0.f;
#pragma unroll
    for (int kz = 0; kz < 4; ++kz) {
      const float* p = dbcp + (size_t)kz * 2048 * 48 + gb;
      dt += p[col]; Bv += p[16 + col]; Cv += p[32 + col];
    }
    sY[row][col] = dt;
    sB[row][col] = Bv;
    sC[row][col] = Cv;
    int ec = e0 + col;
    float uv = cb[ec];
#pragma unroll
    for (int j = 0; j < 4; ++j) {
      int tt = row - 3 + j;
      if (tt >= 0) uv += cw[ec * 4 + j] * xz[(size_t)(rowbase + tt) * 1024 + ec];
    }
    sU[row][col] = siluf(uv);
  }
  __syncthreads();

  // fused delta projection + softplus: sD[t][el]
#pragma unroll
  for (int k = 0; k < 4; ++k) {
    int idx = k * 1024 + tid;
    int t = idx >> 4, l = idx & 15;
    float a = s_dpb[l];
#pragma unroll
    for (int kk = 0; kk < 16; ++kk) a += sY[t][kk] * s_dpwT[kk][l];
    sD[t][l] = (a > 20.f) ? a : log1pf(__expf(a));
  }
  __syncthreads();

  // pass 1: local scan of own 64-step chunk (h0 = 0), track prod(dA)
  float h = 0.f, ap = 1.f;
  const int t0 = chunk * 64;
#pragma unroll 4
  for (int t = t0; t < t0 + 64; ++t) {
    float dv = sD[t][el];
    float dA = __expf(dv * An);
    h = dA * h + dv * sB[t][n] * sU[t][el];
    ap *= dA;
  }
  float* hloc   = &sY[0][0];
  float* aprod  = &sY[64][0];
  float* startH = &sY[128][0];
  const int sidx = el * 16 + n;
  hloc[chunk * 256 + sidx] = h;
  aprod[chunk * 256 + sidx] = ap;
  __syncthreads();

  if (chunk == 0) {
    float H = 0.f;
    startH[sidx] = 0.f;
#pragma unroll
    for (int c = 0; c < 3; ++c) {
      H = aprod[c * 256 + sidx] * H + hloc[c * 256 + sidx];
      startH[(c + 1) * 256 + sidx] = H;
    }
  }
  __syncthreads();
  float h2 = startH[chunk * 256 + sidx];
  __syncthreads();

  // pass 2: corrected scan + y
#pragma unroll 4
  for (int t = t0; t < t0 + 64; ++t) {
    float dv = sD[t][el];
    float uv = sU[t][el];
    float dA = __expf(dv * An);
    h2 = dA * h2 + dv * sB[t][n] * uv;
    float p = h2 * sC[t][n];
    p += __shfl_xor(p, 1);
    p += __shfl_xor(p, 2);
    p += __shfl_xor(p, 4);
    p += __shfl_xor(p, 8);
    if (n == 0) sY[t][el] = p + uv * Dv;
  }
  __syncthreads();

  // gated bf16 writeout
#pragma unroll
  for (int k = 0; k < 4; ++k) {
    int idx = k * 1024 + tid;
    int t = idx >> 4, col = idx & 15;
    float zv = xz[(rowbase + t) * (2 * DI) + DI + e0 + col];
    ybf[(rowbase + t) * DI + e0 + col] = f2bf(sY[t][col] * siluf(zv));
  }
}

// ======================= GEMM NT fp32 vector (head) ===========================
template <int ACT, typename AT>
__global__ __launch_bounds__(256) void gemm_nt(const AT* __restrict__ A, int lda,
                                               const float* __restrict__ W,
                                               const float* __restrict__ bias,
                                               float* __restrict__ C,
                                               int M, int N, int K) {
  __shared__ __align__(16) float sA[16][68];
  __shared__ __align__(16) float sW[16][68];
  const int m0 = blockIdx.x * 64;
  const int n0 = blockIdx.y * 64;
  const int tid = threadIdx.x;
  const int lk = tid & 15, lm = tid >> 4;
  const int tx = tid & 15, ty = tid >> 4;
  float acc[4][4] = {};

  for (int k0 = 0; k0 < K; k0 += 16) {
#pragma unroll
    for (int p = 0; p < 4; ++p) {
      int m = p * 16 + lm;
      sA[lk][m] = ldf(&A[(size_t)(m0 + m) * lda + k0 + lk]);
    }
#pragma unroll
    for (int p = 0; p < 4; ++p) {
      int n = p * 16 + lm;
      sW[lk][n] = (n0 + n < N) ? W[(size_t)(n0 + n) * K + k0 + lk] : 0.f;
    }
    __syncthreads();
#pragma unroll
    for (int k = 0; k < 16; ++k) {
      float4 a = *(const float4*)&sA[k][ty * 4];
      float4 b = *(const float4*)&sW[k][tx * 4];
      acc[0][0] += a.x * b.x; acc[0][1] += a.x * b.y; acc[0][2] += a.x * b.z; acc[0][3] += a.x * b.w;
      acc[1][0] += a.y * b.x; acc[1][1] += a.y * b.y; acc[1][2] += a.y * b.z; acc[1][3] += a.y * b.w;
      acc[2][0] += a.z * b.x; acc[2][1] += a.z * b.y; acc[2][2] += a.z * b.z; acc[2][3] += a.z * b.w;
      acc[3][0] += a.w * b.x; acc[3][1] += a.w * b.y; acc[3][2] += a.w * b.z; acc[3][3] += a.w * b.w;
    }
    __syncthreads();
  }
#pragma unroll
  for (int i = 0; i < 4; ++i) {
    int m = m0 + ty * 4 + i;
#pragma unroll
    for (int j = 0; j < 4; ++j) {
      int n = n0 + tx * 4 + j;
      if (n < N) {
        float v = acc[i][j];
        if (ACT == 3) {
          v += bias[n];
          float t3 = v * v * v;
          v = 0.5f * v * (1.f + tanhf(0.7978845608028654f * (v + 0.044715f * t3)));
        }
        C[(size_t)m * N + n] = v;
      }
    }
  }
}

// ======================= head: fused logits + softmax =========================
__global__ __launch_bounds__(256) void head_kernel(const float* __restrict__ hh,
                                                   const float* __restrict__ w2,
                                                   const float* __restrict__ b2,
                                                   float* __restrict__ out) {
  __shared__ float redm[4], reds[4];
  int b = blockIdx.x, t = threadIdx.x;
  const float4* row = (const float4*)(hh + ((size_t)b * 256 + t) * 64);
  float v = b2[0];
#pragma unroll
  for (int q = 0; q < 16; ++q) {
    float4 a = row[q];
    float4 w = ((const float4*)w2)[q];
    v += a.x * w.x + a.y * w.y + a.z * w.z + a.w * w.w;
  }
  float m = v;
#pragma unroll
  for (int k = 32; k; k >>= 1) m = fmaxf(m, __shfl_xor(m, k));
  if ((t & 63) == 0) redm[t >> 6] = m;
  __syncthreads();
  m = fmaxf(fmaxf(redm[0], redm[1]), fmaxf(redm[2], redm[3]));
  float e = __expf(v - m);
  float s = e;
#pragma unroll
  for (int k = 32; k; k >>= 1) s += __shfl_xor(s, k);
  if ((t & 63) == 0) reds[t >> 6] = s;
  __syncthreads();
  s = reds[0] + reds[1] + reds[2] + reds[3];
  out[b * 256 + t] = (t == 0) ? 0.f : e / s;
}

// ======================= launch ===============================================
extern "C" void kernel_launch(void* const* d_in, const int* in_sizes, int n_in,
                              void* d_out, int out_size, void* d_ws, size_t ws_size,
                              hipStream_t stream) {
  const float* x      = (const float*)d_in[0];
  const float* cnn_w1 = (const float*)d_in[1];
  const float* cnn_b1 = (const float*)d_in[2];
  const float* cnn_w2 = (const float*)d_in[3];
  const float* cnn_b2 = (const float*)d_in[4];
  const float* cnn_w3 = (const float*)d_in[5];
  const float* cnn_b3 = (const float*)d_in[6];
  const float* fc_w   = (const float*)d_in[7];
  const float* fc_b   = (const float*)d_in[8];
  const float* norm_w = (const float*)d_in[9];
  const float* ipw    = (const float*)d_in[10];
  const float* cw     = (const float*)d_in[11];
  const float* cb     = (const float*)d_in[12];
  const float* xpw    = (const float*)d_in[13];
  const float* dpw    = (const float*)d_in[14];
  const float* dpb    = (const float*)d_in[15];
  const float* A_log  = (const float*)d_in[16];
  const float* Dp     = (const float*)d_in[17];
  const float* opw    = (const float*)d_in[18];
  const float* nfw    = (const float*)d_in[19];
  const float* hw1    = (const float*)d_in[20];
  const float* hb1    = (const float*)d_in[21];
  const float* hw2    = (const float*)d_in[22];
  const float* hb2    = (const float*)d_in[23];

  float* ws    = (float*)d_ws;
  float* h     = ws + OFF_H;
  float* xz    = ws + OFF_XZ;
  float* dbcp  = ws + OFF_DBCP;
  float* hh    = ws + OFF_HH;
  unsigned short* xnb = (unsigned short*)(ws + OFF_XNB);
  unsigned short* w2t = (unsigned short*)(ws + OFF_W2T);
  unsigned short* w3t = (unsigned short*)(ws + OFF_W3T);
  unsigned short* ybf = (unsigned short*)(ws + OFF_YBF);
  unsigned short* wip = (unsigned short*)(ws + OFF_WIP);
  unsigned short* wxp = (unsigned short*)(ws + OFF_WXP);
  unsigned short* wop = (unsigned short*)(ws + OFF_WOP);

  const int nv0 = NL * 2 * DI * DM / 4, nv1 = NL * 48 * DI / 4, nv2 = NL * DM * DI / 4;
  cvt_all_kernel<<<(nv0 + nv1 + nv2 + 255) / 256, 256, 0, stream>>>(
      ipw, wip, nv0, xpw, wxp, nv1, opw, wop, nv2);
  cvt_cnnw_kernel<<<57, 256, 0, stream>>>(cnn_w2, cnn_w3, w2t, w3t);

  cnn_fc_mfma<<<Bb * Tt, 256, 0, stream>>>(x, cnn_w1, cnn_b1, w2t, cnn_b2,
                                           w3t, cnn_b3, fc_w, fc_b, h);

  for (int l = 0; l < NL; ++l) {
    {
      dim3 g(32, 16);   // fused rmsnorm + in_proj
      gemm_rn<<<g, 256, 0, stream>>>(h, norm_w + l * DM,
                                     wip + (size_t)l * 2 * DI * DM, xz);
    }
    {
      dim3 g(32, 4);    // x_proj split-K x4 with fused conv1d+silu -> partials
      gemm_xp<<<g, 256, 0, stream>>>(xz, cw + l * DI * 4, cb + l * DI,
                                     wxp + (size_t)l * 48 * DI, dbcp);
    }
    scan_kernel<<<Bb * 32, 1024, 0, stream>>>(
        dbcp, xz, cw + l * DI * 4, cb + l * DI,
        A_log + (size_t)l * DI * DS, Dp + l * DI,
        dpw + (size_t)l * DI * DTR, dpb + l * DI, ybf);
    {
      dim3 g(32, 4, 2); // out_proj split-K x2, atomic accumulate into h
      gemm_bb_acc<<<g, 256, 0, stream>>>(ybf, wop + (size_t)l * DM * DI, h,
                                         Bb * Tt, DM, DI);
    }
  }

  rmsnorm_kernel<<<Bb * Tt, 256, 0, stream>>>(h, nfw, xnb);
  {
    dim3 g(32, 1);
    gemm_nt<3, unsigned short><<<g, 256, 0, stream>>>(xnb, DM, hw1, hb1, hh,
                                                      Bb * Tt, 64, DM);
  }
  head_kernel<<<Bb, 256, 0, stream>>>(hh, hw2, hb2, (float*)d_out);
}